// Round 7
// baseline (761.747 us; speedup 1.0000x reference)
//
#include <hip/hip_runtime.h>
#include <math.h>

#define NN 50000
#define NE 800000
#define NF 512
#define NH 128
#define KF 4
#define NC 64
#define LRELU_ALPHA 0.2f
#define EPSF 1e-16f

typedef unsigned short u16;
typedef __attribute__((ext_vector_type(8))) short bf16x8;
typedef __attribute__((ext_vector_type(4))) float f32x4;

// ---------------- workspace layout (float offsets) ----------------
#define OFF_H      0LL                                  // h (NN,512)
#define OFF_HP     (OFF_H + (long long)NN * NF)         // hp (NN,512)
#define OFF_REC    (OFF_HP + (long long)NN * NF)        // rec (NE int4); ALSO Wt split before edge_pre1
#define OFF_XO0    (OFF_REC + 4LL * NE)                 // (NN,64)
#define OFF_EEO    (OFF_XO0 + (long long)NN * NC)       // (NE,) unused (kept for layout)
#define OFF_SSRC   (OFF_EEO + (long long)NE)            // (NN,4)
#define OFF_SDST   (OFF_SSRC + (long long)NN * KF)
#define OFF_S1A    (OFF_SDST + (long long)NN * KF)
#define OFF_S2A    (OFF_S1A + (long long)NN * KF)
#define OFF_ROWSUM (OFF_S2A + (long long)NN * KF)       // (NN,4)
#define OFF_S1O    (OFF_ROWSUM + (long long)NN * KF)    // (NN,)
#define OFF_S2O    (OFF_S1O + NN)
#define OFF_START  (OFF_S2O + NN)                       // (NN+1) ints, pad
// ---- zeroed-each-call region starts here ----
#define OFF_CNT    (OFF_START + NN + 4)                 // NN ints
#define OFF_CURSOR (OFF_CNT + NN)                       // NN ints
#define OFF_ATT    (OFF_CURSOR + NN)                    // double (2 floats)
#define WS_FLOATS  (OFF_ATT + 2)

__device__ __forceinline__ u16 bf16_rne(float f) {
    unsigned int u = __float_as_uint(f);
    return (u16)((u + 0x7FFFu + ((u >> 16) & 1u)) >> 16);
}
__device__ __forceinline__ float bf16_f(u16 b) {
    return __uint_as_float(((unsigned int)b) << 16);
}

// ---------------------------------------------------------------------------
// K0: transpose + split W: Wt[kf*128+n][f] = split(Wks[kf][f][n]).
__global__ void split_w(const float* __restrict__ Wks,
                        u16* __restrict__ wthi, u16* __restrict__ wtlo) {
    int b = blockIdx.x;            // 0..511 = kf*128 + n
    int kf = b >> 7, n = b & 127;
    for (int f = threadIdx.x; f < NF; f += 256) {
        float v = Wks[(size_t)kf * (NF * NH) + (size_t)f * NH + n];
        u16 hb = bf16_rne(v);
        u16 lb = bf16_rne(v - bf16_f(hb));
        wthi[(size_t)b * NF + f] = hb;
        wtlo[(size_t)b * NF + f] = lb;
    }
}

// ---------------------------------------------------------------------------
// K1: h = x @ Wcat via 3-term split-bf16 MFMA (hi*hi + hi*lo + lo*hi; the
// lo*lo term is ~2^-18 relative and dropped). A-side split from f32 x is
// fused into the staging (no xhi/xlo round trip). 128x128 tile, BK=32,
// 4 waves x 64x64 quadrant, mfma_f32_16x16x32_bf16.
// C/D layout: col = lane&15, row = (lane>>4)*4 + reg.
#define LDST 40   // shorts per LDS row (32 data + 8 pad) = 80 B, 16B-aligned
__global__ __launch_bounds__(256) void gemm_h_mfma(
        const float* __restrict__ x,
        const u16* __restrict__ wthi, const u16* __restrict__ wtlo,
        float* __restrict__ h) {
    __shared__ u16 Ah[128 * LDST], Al[128 * LDST];
    __shared__ u16 Bh[128 * LDST], Bl[128 * LDST];
    int m0 = blockIdx.y * 128, n0 = blockIdx.x * 128;
    int tid = threadIdx.x;
    int lane = tid & 63;
    int wave = tid >> 6, wm = wave >> 1, wn = wave & 1;
    f32x4 acc[4][4];
#pragma unroll
    for (int i = 0; i < 4; ++i)
#pragma unroll
        for (int j = 0; j < 4; ++j) acc[i][j] = (f32x4)(0.f);

    int srow = tid & 127;
    int kh = (tid >> 7) * 16;       // this thread stages k-cols [kh, kh+16)
    int am = m0 + srow; if (am >= NN) am = NN - 1;   // clamp; OOB rows unused
    const float* ax = x + (size_t)am * NF + kh;
    const u16* gbh = wthi + (size_t)(n0 + srow) * NF + kh;
    const u16* gbl = wtlo + (size_t)(n0 + srow) * NF + kh;
    u16* dAh = Ah + srow * LDST + kh;
    u16* dAl = Al + srow * LDST + kh;
    u16* dBh = Bh + srow * LDST + kh;
    u16* dBl = Bl + srow * LDST + kh;

    const int arow = wm * 64 + (lane & 15);
    const int brow = wn * 64 + (lane & 15);
    const int koff = (lane >> 4) * 8;

    for (int k0 = 0; k0 < NF; k0 += 32) {
        float4 f0 = *(const float4*)(ax + k0);
        float4 f1 = *(const float4*)(ax + k0 + 4);
        float4 f2 = *(const float4*)(ax + k0 + 8);
        float4 f3 = *(const float4*)(ax + k0 + 12);
        uint4 wh0 = *(const uint4*)(gbh + k0);
        uint4 wh1 = *(const uint4*)(gbh + k0 + 8);
        uint4 wl0 = *(const uint4*)(gbl + k0);
        uint4 wl1 = *(const uint4*)(gbl + k0 + 8);
        float fv[16] = {f0.x, f0.y, f0.z, f0.w, f1.x, f1.y, f1.z, f1.w,
                        f2.x, f2.y, f2.z, f2.w, f3.x, f3.y, f3.z, f3.w};
        unsigned int hi[8], lo[8];
#pragma unroll
        for (int i = 0; i < 8; ++i) {
            u16 ha = bf16_rne(fv[2 * i]);
            u16 hb = bf16_rne(fv[2 * i + 1]);
            u16 la = bf16_rne(fv[2 * i] - bf16_f(ha));
            u16 lb = bf16_rne(fv[2 * i + 1] - bf16_f(hb));
            hi[i] = (unsigned int)ha | ((unsigned int)hb << 16);
            lo[i] = (unsigned int)la | ((unsigned int)lb << 16);
        }
        __syncthreads();   // previous step's frag reads complete
        *(uint4*)(dAh)     = make_uint4(hi[0], hi[1], hi[2], hi[3]);
        *(uint4*)(dAh + 8) = make_uint4(hi[4], hi[5], hi[6], hi[7]);
        *(uint4*)(dAl)     = make_uint4(lo[0], lo[1], lo[2], lo[3]);
        *(uint4*)(dAl + 8) = make_uint4(lo[4], lo[5], lo[6], lo[7]);
        *(uint4*)(dBh)     = wh0; *(uint4*)(dBh + 8) = wh1;
        *(uint4*)(dBl)     = wl0; *(uint4*)(dBl + 8) = wl1;
        __syncthreads();
        bf16x8 ah[4], al[4], bh[4], bl[4];
#pragma unroll
        for (int mi = 0; mi < 4; ++mi) {
            ah[mi] = *(const bf16x8*)(Ah + (arow + mi * 16) * LDST + koff);
            al[mi] = *(const bf16x8*)(Al + (arow + mi * 16) * LDST + koff);
        }
#pragma unroll
        for (int ni = 0; ni < 4; ++ni) {
            bh[ni] = *(const bf16x8*)(Bh + (brow + ni * 16) * LDST + koff);
            bl[ni] = *(const bf16x8*)(Bl + (brow + ni * 16) * LDST + koff);
        }
#pragma unroll
        for (int mi = 0; mi < 4; ++mi)
#pragma unroll
            for (int ni = 0; ni < 4; ++ni) {
                acc[mi][ni] = __builtin_amdgcn_mfma_f32_16x16x32_bf16(
                    ah[mi], bh[ni], acc[mi][ni], 0, 0, 0);
                acc[mi][ni] = __builtin_amdgcn_mfma_f32_16x16x32_bf16(
                    ah[mi], bl[ni], acc[mi][ni], 0, 0, 0);
                acc[mi][ni] = __builtin_amdgcn_mfma_f32_16x16x32_bf16(
                    al[mi], bh[ni], acc[mi][ni], 0, 0, 0);
            }
    }
#pragma unroll
    for (int mi = 0; mi < 4; ++mi) {
        int mbase = m0 + wm * 64 + mi * 16 + (lane >> 4) * 4;
#pragma unroll
        for (int ni = 0; ni < 4; ++ni) {
            int n = n0 + wn * 64 + ni * 16 + (lane & 15);
#pragma unroll
            for (int r = 0; r < 4; ++r) {
                int m = mbase + r;
                if (m < NN) h[(size_t)m * NF + n] = acc[mi][ni][r];
            }
        }
    }
}

// ---------------------------------------------------------------------------
// K2: routing/attention scalars from h (matches reference contraction h @ a).
__global__ __launch_bounds__(256) void compute_svals_h(
        const float* __restrict__ h, const float* __restrict__ a_k,
        const float* __restrict__ a_att,
        float* __restrict__ s_src, float* __restrict__ s_dst,
        float* __restrict__ s1a, float* __restrict__ s2a) {
    __shared__ float Ak[4][1024];
    __shared__ float Aa[4][256];
    for (int i = threadIdx.x; i < 4096; i += 256) Ak[i >> 10][i & 1023] = a_k[i];
    for (int i = threadIdx.x; i < 1024; i += 256) Aa[i >> 8][i & 255] = a_att[i];
    __syncthreads();
    int w = threadIdx.x >> 6, lane = threadIdx.x & 63;
    int n = blockIdx.x * 4 + w;
    if (n >= NN) return;
    const float* hr = h + (size_t)n * NF;
    float accS[4] = {0, 0, 0, 0}, accD[4] = {0, 0, 0, 0};
    float accQ1[4] = {0, 0, 0, 0}, accQ2[4] = {0, 0, 0, 0};
#pragma unroll
    for (int i = 0; i < 8; ++i) {
        int f = i * 64 + lane;
        float hv = hr[f];
#pragma unroll
        for (int k = 0; k < 4; ++k) {
            accS[k] = fmaf(hv, Ak[k][f], accS[k]);
            accD[k] = fmaf(hv, Ak[k][512 + f], accD[k]);
        }
        accQ1[i >> 1] = fmaf(hv, Aa[i >> 1][f & 127], accQ1[i >> 1]);
        accQ2[i >> 1] = fmaf(hv, Aa[i >> 1][128 + (f & 127)], accQ2[i >> 1]);
    }
#pragma unroll
    for (int off = 32; off >= 1; off >>= 1) {
#pragma unroll
        for (int k = 0; k < 4; ++k) {
            accS[k] += __shfl_xor(accS[k], off);
            accD[k] += __shfl_xor(accD[k], off);
            accQ1[k] += __shfl_xor(accQ1[k], off);
            accQ2[k] += __shfl_xor(accQ2[k], off);
        }
    }
    if (lane == 0) {
#pragma unroll
        for (int k = 0; k < 4; ++k) {
            s_src[n * 4 + k] = accS[k];
            s_dst[n * 4 + k] = accD[k];
            s1a[n * 4 + k]   = accQ1[k];
            s2a[n * 4 + k]   = accQ2[k];
        }
    }
}

// ---------------------------------------------------------------------------
// CSR build: count / scan
__global__ void csr_count(const int* __restrict__ edge, int* __restrict__ cnt) {
    int e = blockIdx.x * 256 + threadIdx.x;
    if (e < NE) atomicAdd(&cnt[edge[e]], 1);
}

__global__ __launch_bounds__(1024) void csr_scan(const int* __restrict__ cnt,
                                                 int* __restrict__ start) {
    __shared__ int part[1024];
    int t = threadIdx.x;
    const int CH = (NN + 1023) / 1024;  // 49
    int base = t * CH;
    int s = 0;
    for (int i = 0; i < CH; ++i) {
        int idx = base + i;
        if (idx < NN) s += cnt[idx];
    }
    part[t] = s;
    __syncthreads();
    for (int off = 1; off < 1024; off <<= 1) {
        int v = (t >= off) ? part[t - off] : 0;
        __syncthreads();
        part[t] += v;
        __syncthreads();
    }
    int run = (t == 0) ? 0 : part[t - 1];
    for (int i = 0; i < CH; ++i) {
        int idx = base + i;
        if (idx < NN) { start[idx] = run; run += cnt[idx]; }
    }
    if (t == 1023) start[NN] = run;
}

// ---------------------------------------------------------------------------
// K3: edge-parallel scalar precompute + CSR fill. One thread per edge.
__global__ __launch_bounds__(256) void edge_pre1(
        const int* __restrict__ edge, const int* __restrict__ start,
        int* __restrict__ cursor,
        const float* __restrict__ s_src, const float* __restrict__ s_dst,
        const float* __restrict__ s1a, const float* __restrict__ s2a,
        int4* __restrict__ rec, double* __restrict__ att_acc) {
    __shared__ float blk[4];
    int tid = threadIdx.x;
    int e = blockIdx.x * 256 + tid;
    float t2 = 0.f;
    if (e < NE) {
        int src = edge[e];
        int dst = edge[NE + e];
        float4 ss = *(const float4*)(s_src + (size_t)src * 4);
        float4 sd = *(const float4*)(s_dst + (size_t)dst * 4);
        float l0 = ss.x + sd.x, l1 = ss.y + sd.y, l2 = ss.z + sd.z, l3 = ss.w + sd.w;
        int i1 = 0; float v1 = l0;
        if (l1 > v1) { v1 = l1; i1 = 1; }
        if (l2 > v1) { v1 = l2; i1 = 2; }
        if (l3 > v1) { v1 = l3; i1 = 3; }
        int i2 = 0; float v2 = -3.4e38f;
        if (i1 != 0)            { v2 = l0; i2 = 0; }
        if (i1 != 1 && l1 > v2) { v2 = l1; i2 = 1; }
        if (i1 != 2 && l2 > v2) { v2 = l2; i2 = 2; }
        if (i1 != 3 && l3 > v2) { v2 = l3; i2 = 3; }
        float esum = expf(l0 - v1) + expf(l1 - v1) + expf(l2 - v1) + expf(l3 - v1);
        t2 = (1.f + expf(v2 - v1)) / esum;
        float4 q1 = *(const float4*)(s1a + (size_t)src * 4);
        float4 q2 = *(const float4*)(s2a + (size_t)dst * 4);
        float q1v1 = i1 == 0 ? q1.x : i1 == 1 ? q1.y : i1 == 2 ? q1.z : q1.w;
        float q2v1 = i1 == 0 ? q2.x : i1 == 1 ? q2.y : i1 == 2 ? q2.z : q2.w;
        float q1v2 = i2 == 0 ? q1.x : i2 == 1 ? q1.y : i2 == 2 ? q1.z : q1.w;
        float q2v2 = i2 == 0 ? q2.x : i2 == 1 ? q2.y : i2 == 2 ? q2.z : q2.w;
        float sv1 = q1v1 + q2v1, sv2 = q1v2 + q2v2;
        float ee1 = expf(-(sv1 >= 0.f ? sv1 : LRELU_ALPHA * sv1));
        float ee2 = expf(-(sv2 >= 0.f ? sv2 : LRELU_ALPHA * sv2));
        int p = start[src] + atomicAdd(&cursor[src], 1);
        rec[p] = make_int4(dst, src | (i1 << 16) | (i2 << 18),
                           __float_as_int(ee1), __float_as_int(ee2));
    }
#pragma unroll
    for (int off = 32; off >= 1; off >>= 1) t2 += __shfl_xor(t2, off);
    if ((tid & 63) == 0) blk[tid >> 6] = t2;
    __syncthreads();
    if (tid == 0)
        atomicAdd(att_acc, (double)(blk[0] + blk[1] + blk[2] + blk[3]));
}

// ---------------------------------------------------------------------------
// K4: layer-1 gather. One block per node; 4 waves split the record list.
__global__ __launch_bounds__(256) void node_gather1(
        const int* __restrict__ start, const int4* __restrict__ rec,
        const float* __restrict__ h, float* __restrict__ hp,
        float* __restrict__ rowsum) {
    __shared__ float red[4][512];
    __shared__ float rsred[4][4];
    int n = blockIdx.x;
    int w = threadIdx.x >> 6, lane = threadIdx.x & 63;
    int j0 = start[n], j1 = start[n + 1];
    float a00 = 0.f, a01 = 0.f, a10 = 0.f, a11 = 0.f;
    float a20 = 0.f, a21 = 0.f, a30 = 0.f, a31 = 0.f;
    float rs0 = 0.f, rs1 = 0.f, rs2 = 0.f, rs3 = 0.f;
    for (int j = j0 + w; j < j1; j += 4) {
        int4 r = rec[j];
        int i1 = (r.y >> 16) & 3, i2 = (r.y >> 18) & 3;
        float w1 = __int_as_float(r.z), w2 = __int_as_float(r.w);
        const float* hr = h + (size_t)r.x * NF + lane;
        float v1a = hr[i1 * 128];
        float v1b = hr[i1 * 128 + 64];
        float v2a = hr[i2 * 128];
        float v2b = hr[i2 * 128 + 64];
        switch (i1) {
            case 0: a00 = fmaf(w1, v1a, a00); a01 = fmaf(w1, v1b, a01); rs0 += w1; break;
            case 1: a10 = fmaf(w1, v1a, a10); a11 = fmaf(w1, v1b, a11); rs1 += w1; break;
            case 2: a20 = fmaf(w1, v1a, a20); a21 = fmaf(w1, v1b, a21); rs2 += w1; break;
            default:a30 = fmaf(w1, v1a, a30); a31 = fmaf(w1, v1b, a31); rs3 += w1; break;
        }
        switch (i2) {
            case 0: a00 = fmaf(w2, v2a, a00); a01 = fmaf(w2, v2b, a01); rs0 += w2; break;
            case 1: a10 = fmaf(w2, v2a, a10); a11 = fmaf(w2, v2b, a11); rs1 += w2; break;
            case 2: a20 = fmaf(w2, v2a, a20); a21 = fmaf(w2, v2b, a21); rs2 += w2; break;
            default:a30 = fmaf(w2, v2a, a30); a31 = fmaf(w2, v2b, a31); rs3 += w2; break;
        }
    }
    red[w][lane]       = a00; red[w][64 + lane]  = a01;
    red[w][128 + lane] = a10; red[w][192 + lane] = a11;
    red[w][256 + lane] = a20; red[w][320 + lane] = a21;
    red[w][384 + lane] = a30; red[w][448 + lane] = a31;
    if (lane == 0) {
        rsred[w][0] = rs0; rsred[w][1] = rs1; rsred[w][2] = rs2; rsred[w][3] = rs3;
    }
    __syncthreads();
    int t = threadIdx.x;
    float s0 = (red[0][t] + red[1][t]) + (red[2][t] + red[3][t]);
    float s1 = (red[0][256 + t] + red[1][256 + t]) + (red[2][256 + t] + red[3][256 + t]);
    float* hpr = hp + (size_t)n * NF;
    hpr[t]       = s0;
    hpr[256 + t] = s1;
    if (t < 4)
        rowsum[n * 4 + t] = (rsred[0][t] + rsred[1][t]) + (rsred[2][t] + rsred[3][t]);
}

// ---------------------------------------------------------------------------
// K5: node pass as tiled GEMM with fused elu + epilogue dots.
__global__ __launch_bounds__(256) void node_pass_gemm(
        const float* __restrict__ hp, const float* __restrict__ rowsum,
        const float* __restrict__ Wo, const float* __restrict__ a_out,
        float* __restrict__ xo0, float* __restrict__ s1o, float* __restrict__ s2o) {
    __shared__ float As[16][128];
    __shared__ float Bs[16][64];
    int m0 = blockIdx.x * 128;
    int tid = threadIdx.x;
    int tm = tid >> 4, tn = tid & 15;
    float acc[8][4];
#pragma unroll
    for (int i = 0; i < 8; ++i)
#pragma unroll
        for (int j = 0; j < 4; ++j) acc[i][j] = 0.f;

    int arow = tid >> 1;
    int akc  = (tid & 1) * 8;
    int am = m0 + arow; if (am >= NN) am = NN - 1;
    int brow = tid >> 4, bcol = (tid & 15) * 4;

    for (int k0 = 0; k0 < NF; k0 += 16) {
        float rs = rowsum[am * 4 + ((k0 + akc) >> 7)] + EPSF;
        float4 v0 = *(const float4*)(hp + (size_t)am * NF + k0 + akc);
        float4 v1 = *(const float4*)(hp + (size_t)am * NF + k0 + akc + 4);
        float v[8] = {v0.x, v0.y, v0.z, v0.w, v1.x, v1.y, v1.z, v1.w};
#pragma unroll
        for (int i = 0; i < 8; ++i) {
            float t = v[i] / rs;
            v[i] = t > 0.f ? t : expm1f(t);
        }
        As[akc + 0][arow] = v[0]; As[akc + 1][arow] = v[1];
        As[akc + 2][arow] = v[2]; As[akc + 3][arow] = v[3];
        As[akc + 4][arow] = v[4]; As[akc + 5][arow] = v[5];
        As[akc + 6][arow] = v[6]; As[akc + 7][arow] = v[7];
        *(float4*)&Bs[brow][bcol] =
            *(const float4*)(Wo + (size_t)(k0 + brow) * NC + bcol);
        __syncthreads();
#pragma unroll
        for (int kk = 0; kk < 16; ++kk) {
            float4 av0 = *(float4*)&As[kk][tm * 8];
            float4 av1 = *(float4*)&As[kk][tm * 8 + 4];
            float4 bv  = *(float4*)&Bs[kk][tn * 4];
            float a[8] = {av0.x, av0.y, av0.z, av0.w, av1.x, av1.y, av1.z, av1.w};
            float b[4] = {bv.x, bv.y, bv.z, bv.w};
#pragma unroll
            for (int i = 0; i < 8; ++i)
#pragma unroll
                for (int j = 0; j < 4; ++j)
                    acc[i][j] = fmaf(a[i], b[j], acc[i][j]);
        }
        __syncthreads();
    }
    float4 ao1 = *(const float4*)(a_out + tn * 4);
    float4 ao2 = *(const float4*)(a_out + 64 + tn * 4);
#pragma unroll
    for (int i = 0; i < 8; ++i) {
        int m = m0 + tm * 8 + i;
        float4 o = make_float4(acc[i][0], acc[i][1], acc[i][2], acc[i][3]);
        float p1 = o.x * ao1.x + o.y * ao1.y + o.z * ao1.z + o.w * ao1.w;
        float p2 = o.x * ao2.x + o.y * ao2.y + o.z * ao2.z + o.w * ao2.w;
#pragma unroll
        for (int off = 8; off >= 1; off >>= 1) {
            p1 += __shfl_xor(p1, off);
            p2 += __shfl_xor(p2, off);
        }
        if (m < NN) {
            *(float4*)(xo0 + (size_t)m * NC + tn * 4) = o;
            if (tn == 0) { s1o[m] = p1; s2o[m] = p2; }
        }
    }
}

// ---------------------------------------------------------------------------
// K6: output attention gather with INLINE e-values (src == n, so
// ee = exp(-lrelu(s1o[n] + s2o[dst])) needs only a wave-uniform s2o load),
// fused with elu + log-softmax.
__global__ __launch_bounds__(256) void node_gather2(
        const int* __restrict__ start, const int4* __restrict__ rec,
        const float* __restrict__ s1o, const float* __restrict__ s2o,
        const float* __restrict__ xo0, float* __restrict__ out) {
    __shared__ float red[4][64];
    __shared__ float rsl[4];
    int n = blockIdx.x;
    int w = threadIdx.x >> 6, lane = threadIdx.x & 63;
    int j0 = start[n], j1 = start[n + 1];
    float s1n = s1o[n];
    float acc = 0.f, rsum = 0.f;
    for (int j = j0 + w; j < j1; j += 4) {
        int d = rec[j].x;
        float sv = s1n + s2o[d];
        float e = expf(-(sv >= 0.f ? sv : LRELU_ALPHA * sv));
        acc = fmaf(e, xo0[(size_t)d * NC + lane], acc);
        rsum += e;
    }
    red[w][lane] = acc;
    if (lane == 0) rsl[w] = rsum;
    __syncthreads();
    if (w == 0) {
        float a = (red[0][lane] + red[1][lane]) + (red[2][lane] + red[3][lane]);
        float r = (rsl[0] + rsl[1]) + (rsl[2] + rsl[3]);
        float t = a / (r + EPSF);
        float v = t > 0.f ? t : expm1f(t);
        float m = v;
#pragma unroll
        for (int off = 32; off >= 1; off >>= 1) m = fmaxf(m, __shfl_xor(m, off));
        float p = expf(v - m);
#pragma unroll
        for (int off = 32; off >= 1; off >>= 1) p += __shfl_xor(p, off);
        out[(size_t)n * NC + lane] = v - m - logf(p);
    }
}

__global__ void finalize_att(const double* __restrict__ att_acc, float* __restrict__ out) {
    out[(size_t)NN * NC] = 1.f - (float)(att_acc[0] / (double)NE);
}

// ---------------------------------------------------------------------------
extern "C" void kernel_launch(void* const* d_in, const int* in_sizes, int n_in,
                              void* d_out, int out_size, void* d_ws, size_t ws_size,
                              hipStream_t stream) {
    const float* x     = (const float*)d_in[0];
    const int*   edge  = (const int*)d_in[1];
    const float* Wks   = (const float*)d_in[2];
    const float* a_k   = (const float*)d_in[3];
    const float* Wo    = (const float*)d_in[4];
    const float* a_att = (const float*)d_in[5];
    const float* a_out = (const float*)d_in[6];
    float* out = (float*)d_out;

    float* wsf = (float*)d_ws;
    float* h      = wsf + OFF_H;
    float* hp     = wsf + OFF_HP;
    int4*  rec    = (int4*)(wsf + OFF_REC);
    float* xo0    = wsf + OFF_XO0;
    float* s_src  = wsf + OFF_SSRC;
    float* s_dst  = wsf + OFF_SDST;
    float* s1a    = wsf + OFF_S1A;
    float* s2a    = wsf + OFF_S2A;
    float* rowsum = wsf + OFF_ROWSUM;
    float* s1o    = wsf + OFF_S1O;
    float* s2o    = wsf + OFF_S2O;
    int*   startp = (int*)(wsf + OFF_START);
    int*   cnt    = (int*)(wsf + OFF_CNT);
    int*   cursor = (int*)(wsf + OFF_CURSOR);
    double* att   = (double*)(wsf + OFF_ATT);

    // Transient alias: Wt_hi/lo live in the rec region (rec written only by
    // edge_pre1, which runs after gemm_h_mfma has consumed them).
    u16* wthi = (u16*)(wsf + OFF_REC);
    u16* wtlo = wthi + (size_t)KF * NH * NF;

    // zero only the accumulation region (cnt, cursor, att) every call
    size_t zero_bytes = (size_t)(WS_FLOATS - OFF_CNT) * sizeof(float);
    hipMemsetAsync((char*)d_ws + (size_t)OFF_CNT * sizeof(float), 0, zero_bytes, stream);

    split_w<<<KF * NH, 256, 0, stream>>>(Wks, wthi, wtlo);
    gemm_h_mfma<<<dim3(4, (NN + 127) / 128), 256, 0, stream>>>(x, wthi, wtlo, h);
    compute_svals_h<<<(NN + 3) / 4, 256, 0, stream>>>(h, a_k, a_att,
                                                      s_src, s_dst, s1a, s2a);
    csr_count<<<(NE + 255) / 256, 256, 0, stream>>>(edge, cnt);
    csr_scan<<<1, 1024, 0, stream>>>(cnt, startp);
    edge_pre1<<<(NE + 255) / 256, 256, 0, stream>>>(edge, startp, cursor,
                                                    s_src, s_dst, s1a, s2a, rec, att);
    node_gather1<<<NN, 256, 0, stream>>>(startp, rec, h, hp, rowsum);
    node_pass_gemm<<<(NN + 127) / 128, 256, 0, stream>>>(hp, rowsum, Wo, a_out,
                                                         xo0, s1o, s2o);
    node_gather2<<<NN, 256, 0, stream>>>(startp, rec, s1o, s2o, xo0, out);
    finalize_att<<<1, 1, 0, stream>>>(att, out);
}

// Round 8
// 752.920 us; speedup vs baseline: 1.0117x; 1.0117x over previous
//
#include <hip/hip_runtime.h>
#include <math.h>

#define NN 50000
#define NE 800000
#define NF 512
#define NH 128
#define KF 4
#define NC 64
#define LRELU_ALPHA 0.2f
#define EPSF 1e-16f

typedef unsigned short u16;
typedef __attribute__((ext_vector_type(8))) short bf16x8;
typedef __attribute__((ext_vector_type(4))) float f32x4;

// ---------------- workspace layout (float offsets) ----------------
#define OFF_H      0LL                                  // h (NN,512)
#define OFF_HP     (OFF_H + (long long)NN * NF)         // hp (NN,512); ALSO xhi/xlo before node_gather1
#define OFF_REC    (OFF_HP + (long long)NN * NF)        // rec (NE int4); ALSO Wt split before edge_pre1
#define OFF_XO0    (OFF_REC + 4LL * NE)                 // (NN,64)
#define OFF_SSRC   (OFF_XO0 + (long long)NN * NC)       // (NN,4)
#define OFF_SDST   (OFF_SSRC + (long long)NN * KF)
#define OFF_S1A    (OFF_SDST + (long long)NN * KF)
#define OFF_S2A    (OFF_S1A + (long long)NN * KF)
#define OFF_ROWSUM (OFF_S2A + (long long)NN * KF)       // (NN,4)
#define OFF_S1O    (OFF_ROWSUM + (long long)NN * KF)    // (NN,)
#define OFF_S2O    (OFF_S1O + NN)
#define OFF_START  (OFF_S2O + NN)                       // (NN+1) ints, pad
// ---- zeroed-each-call region starts here ----
#define OFF_CNT    (OFF_START + NN + 4)                 // NN ints
#define OFF_CURSOR (OFF_CNT + NN)                       // NN ints
#define OFF_ATT    (OFF_CURSOR + NN)                    // double (2 floats)
#define WS_FLOATS  (OFF_ATT + 2)

__device__ __forceinline__ u16 bf16_rne(float f) {
    unsigned int u = __float_as_uint(f);
    return (u16)((u + 0x7FFFu + ((u >> 16) & 1u)) >> 16);
}
__device__ __forceinline__ float bf16_f(u16 b) {
    return __uint_as_float(((unsigned int)b) << 16);
}

// ---------------------------------------------------------------------------
// K0a: split x into hi/lo bf16 (RNE). 8 elements/thread.
__global__ __launch_bounds__(256) void split_x(const float* __restrict__ x,
                                               u16* __restrict__ xhi,
                                               u16* __restrict__ xlo) {
    size_t i = ((size_t)blockIdx.x * 256 + threadIdx.x) * 8;
    float4 v0 = *(const float4*)(x + i);
    float4 v1 = *(const float4*)(x + i + 4);
    float v[8] = {v0.x, v0.y, v0.z, v0.w, v1.x, v1.y, v1.z, v1.w};
    unsigned int hp[4], lp[4];
#pragma unroll
    for (int j = 0; j < 4; ++j) {
        u16 h0 = bf16_rne(v[2 * j]);
        u16 h1 = bf16_rne(v[2 * j + 1]);
        u16 l0 = bf16_rne(v[2 * j] - bf16_f(h0));
        u16 l1 = bf16_rne(v[2 * j + 1] - bf16_f(h1));
        hp[j] = (unsigned int)h0 | ((unsigned int)h1 << 16);
        lp[j] = (unsigned int)l0 | ((unsigned int)l1 << 16);
    }
    *(uint4*)(xhi + i) = make_uint4(hp[0], hp[1], hp[2], hp[3]);
    *(uint4*)(xlo + i) = make_uint4(lp[0], lp[1], lp[2], lp[3]);
}

// K0b: transpose + split W: Wt[kf*128+n][f] = split(Wks[kf][f][n]).
__global__ void split_w(const float* __restrict__ Wks,
                        u16* __restrict__ wthi, u16* __restrict__ wtlo) {
    int b = blockIdx.x;            // 0..511 = kf*128 + n
    int kf = b >> 7, n = b & 127;
    for (int f = threadIdx.x; f < NF; f += 256) {
        float v = Wks[(size_t)kf * (NF * NH) + (size_t)f * NH + n];
        u16 hb = bf16_rne(v);
        u16 lb = bf16_rne(v - bf16_f(hb));
        wthi[(size_t)b * NF + f] = hb;
        wtlo[(size_t)b * NF + f] = lb;
    }
}

// ---------------------------------------------------------------------------
// K1: h = x @ Wcat via 3-term split-bf16 MFMA (hi*hi + hi*lo + lo*hi; lo*lo
// is ~2^-18 relative, dropped). 128x128 tile, BK=32, 4 waves x 64x64
// quadrant, mfma_f32_16x16x32_bf16. C/D: col=lane&15, row=(lane>>4)*4+reg.
#define LDST 40   // shorts per LDS row (32 data + 8 pad) = 80 B, 16B-aligned
__global__ __launch_bounds__(256) void gemm_h_mfma(
        const u16* __restrict__ xhi, const u16* __restrict__ xlo,
        const u16* __restrict__ wthi, const u16* __restrict__ wtlo,
        float* __restrict__ h) {
    __shared__ u16 Ah[128 * LDST], Al[128 * LDST];
    __shared__ u16 Bh[128 * LDST], Bl[128 * LDST];
    int m0 = blockIdx.y * 128, n0 = blockIdx.x * 128;
    int tid = threadIdx.x;
    int lane = tid & 63;
    int wave = tid >> 6, wm = wave >> 1, wn = wave & 1;
    f32x4 acc[4][4];
#pragma unroll
    for (int i = 0; i < 4; ++i)
#pragma unroll
        for (int j = 0; j < 4; ++j) acc[i][j] = (f32x4)(0.f);

    int srow = tid & 127;
    int isB = tid >> 7;
    int am = m0 + srow; if (am >= NN) am = NN - 1;   // clamp; OOB rows unused
    const u16* gh = isB ? (wthi + (size_t)(n0 + srow) * NF)
                        : (xhi + (size_t)am * NF);
    const u16* gl = isB ? (wtlo + (size_t)(n0 + srow) * NF)
                        : (xlo + (size_t)am * NF);
    u16* dh = (isB ? Bh : Ah) + srow * LDST;
    u16* dl = (isB ? Bl : Al) + srow * LDST;

    const int arow = wm * 64 + (lane & 15);
    const int brow = wn * 64 + (lane & 15);
    const int koff = (lane >> 4) * 8;

    for (int k0 = 0; k0 < NF; k0 += 32) {
        uint4 p0 = *(const uint4*)(gh + k0);
        uint4 p1 = *(const uint4*)(gh + k0 + 8);
        uint4 p2 = *(const uint4*)(gh + k0 + 16);
        uint4 p3 = *(const uint4*)(gh + k0 + 24);
        uint4 q0 = *(const uint4*)(gl + k0);
        uint4 q1 = *(const uint4*)(gl + k0 + 8);
        uint4 q2 = *(const uint4*)(gl + k0 + 16);
        uint4 q3 = *(const uint4*)(gl + k0 + 24);
        __syncthreads();   // previous step's frag reads complete
        *(uint4*)(dh)      = p0; *(uint4*)(dh + 8)  = p1;
        *(uint4*)(dh + 16) = p2; *(uint4*)(dh + 24) = p3;
        *(uint4*)(dl)      = q0; *(uint4*)(dl + 8)  = q1;
        *(uint4*)(dl + 16) = q2; *(uint4*)(dl + 24) = q3;
        __syncthreads();
        bf16x8 ah[4], al[4], bh[4], bl[4];
#pragma unroll
        for (int mi = 0; mi < 4; ++mi) {
            ah[mi] = *(const bf16x8*)(Ah + (arow + mi * 16) * LDST + koff);
            al[mi] = *(const bf16x8*)(Al + (arow + mi * 16) * LDST + koff);
        }
#pragma unroll
        for (int ni = 0; ni < 4; ++ni) {
            bh[ni] = *(const bf16x8*)(Bh + (brow + ni * 16) * LDST + koff);
            bl[ni] = *(const bf16x8*)(Bl + (brow + ni * 16) * LDST + koff);
        }
#pragma unroll
        for (int mi = 0; mi < 4; ++mi)
#pragma unroll
            for (int ni = 0; ni < 4; ++ni) {
                acc[mi][ni] = __builtin_amdgcn_mfma_f32_16x16x32_bf16(
                    ah[mi], bh[ni], acc[mi][ni], 0, 0, 0);
                acc[mi][ni] = __builtin_amdgcn_mfma_f32_16x16x32_bf16(
                    ah[mi], bl[ni], acc[mi][ni], 0, 0, 0);
                acc[mi][ni] = __builtin_amdgcn_mfma_f32_16x16x32_bf16(
                    al[mi], bh[ni], acc[mi][ni], 0, 0, 0);
            }
    }
#pragma unroll
    for (int mi = 0; mi < 4; ++mi) {
        int mbase = m0 + wm * 64 + mi * 16 + (lane >> 4) * 4;
#pragma unroll
        for (int ni = 0; ni < 4; ++ni) {
            int n = n0 + wn * 64 + ni * 16 + (lane & 15);
#pragma unroll
            for (int r = 0; r < 4; ++r) {
                int m = mbase + r;
                if (m < NN) h[(size_t)m * NF + n] = acc[mi][ni][r];
            }
        }
    }
}

// ---------------------------------------------------------------------------
// K2: routing/attention scalars from h (matches reference contraction h @ a).
__global__ __launch_bounds__(256) void compute_svals_h(
        const float* __restrict__ h, const float* __restrict__ a_k,
        const float* __restrict__ a_att,
        float* __restrict__ s_src, float* __restrict__ s_dst,
        float* __restrict__ s1a, float* __restrict__ s2a) {
    __shared__ float Ak[4][1024];
    __shared__ float Aa[4][256];
    for (int i = threadIdx.x; i < 4096; i += 256) Ak[i >> 10][i & 1023] = a_k[i];
    for (int i = threadIdx.x; i < 1024; i += 256) Aa[i >> 8][i & 255] = a_att[i];
    __syncthreads();
    int w = threadIdx.x >> 6, lane = threadIdx.x & 63;
    int n = blockIdx.x * 4 + w;
    if (n >= NN) return;
    const float* hr = h + (size_t)n * NF;
    float accS[4] = {0, 0, 0, 0}, accD[4] = {0, 0, 0, 0};
    float accQ1[4] = {0, 0, 0, 0}, accQ2[4] = {0, 0, 0, 0};
#pragma unroll
    for (int i = 0; i < 8; ++i) {
        int f = i * 64 + lane;
        float hv = hr[f];
#pragma unroll
        for (int k = 0; k < 4; ++k) {
            accS[k] = fmaf(hv, Ak[k][f], accS[k]);
            accD[k] = fmaf(hv, Ak[k][512 + f], accD[k]);
        }
        accQ1[i >> 1] = fmaf(hv, Aa[i >> 1][f & 127], accQ1[i >> 1]);
        accQ2[i >> 1] = fmaf(hv, Aa[i >> 1][128 + (f & 127)], accQ2[i >> 1]);
    }
#pragma unroll
    for (int off = 32; off >= 1; off >>= 1) {
#pragma unroll
        for (int k = 0; k < 4; ++k) {
            accS[k] += __shfl_xor(accS[k], off);
            accD[k] += __shfl_xor(accD[k], off);
            accQ1[k] += __shfl_xor(accQ1[k], off);
            accQ2[k] += __shfl_xor(accQ2[k], off);
        }
    }
    if (lane == 0) {
#pragma unroll
        for (int k = 0; k < 4; ++k) {
            s_src[n * 4 + k] = accS[k];
            s_dst[n * 4 + k] = accD[k];
            s1a[n * 4 + k]   = accQ1[k];
            s2a[n * 4 + k]   = accQ2[k];
        }
    }
}

// ---------------------------------------------------------------------------
// CSR build: count / scan
__global__ void csr_count(const int* __restrict__ edge, int* __restrict__ cnt) {
    int e = blockIdx.x * 256 + threadIdx.x;
    if (e < NE) atomicAdd(&cnt[edge[e]], 1);
}

__global__ __launch_bounds__(1024) void csr_scan(const int* __restrict__ cnt,
                                                 int* __restrict__ start) {
    __shared__ int part[1024];
    int t = threadIdx.x;
    const int CH = (NN + 1023) / 1024;  // 49
    int base = t * CH;
    int s = 0;
    for (int i = 0; i < CH; ++i) {
        int idx = base + i;
        if (idx < NN) s += cnt[idx];
    }
    part[t] = s;
    __syncthreads();
    for (int off = 1; off < 1024; off <<= 1) {
        int v = (t >= off) ? part[t - off] : 0;
        __syncthreads();
        part[t] += v;
        __syncthreads();
    }
    int run = (t == 0) ? 0 : part[t - 1];
    for (int i = 0; i < CH; ++i) {
        int idx = base + i;
        if (idx < NN) { start[idx] = run; run += cnt[idx]; }
    }
    if (t == 1023) start[NN] = run;
}

// ---------------------------------------------------------------------------
// K3: edge-parallel scalar precompute + CSR fill. One thread per edge.
__global__ __launch_bounds__(256) void edge_pre1(
        const int* __restrict__ edge, const int* __restrict__ start,
        int* __restrict__ cursor,
        const float* __restrict__ s_src, const float* __restrict__ s_dst,
        const float* __restrict__ s1a, const float* __restrict__ s2a,
        int4* __restrict__ rec, double* __restrict__ att_acc) {
    __shared__ float blk[4];
    int tid = threadIdx.x;
    int e = blockIdx.x * 256 + tid;
    float t2 = 0.f;
    if (e < NE) {
        int src = edge[e];
        int dst = edge[NE + e];
        float4 ss = *(const float4*)(s_src + (size_t)src * 4);
        float4 sd = *(const float4*)(s_dst + (size_t)dst * 4);
        float l0 = ss.x + sd.x, l1 = ss.y + sd.y, l2 = ss.z + sd.z, l3 = ss.w + sd.w;
        int i1 = 0; float v1 = l0;
        if (l1 > v1) { v1 = l1; i1 = 1; }
        if (l2 > v1) { v1 = l2; i1 = 2; }
        if (l3 > v1) { v1 = l3; i1 = 3; }
        int i2 = 0; float v2 = -3.4e38f;
        if (i1 != 0)            { v2 = l0; i2 = 0; }
        if (i1 != 1 && l1 > v2) { v2 = l1; i2 = 1; }
        if (i1 != 2 && l2 > v2) { v2 = l2; i2 = 2; }
        if (i1 != 3 && l3 > v2) { v2 = l3; i2 = 3; }
        float esum = expf(l0 - v1) + expf(l1 - v1) + expf(l2 - v1) + expf(l3 - v1);
        t2 = (1.f + expf(v2 - v1)) / esum;
        float4 q1 = *(const float4*)(s1a + (size_t)src * 4);
        float4 q2 = *(const float4*)(s2a + (size_t)dst * 4);
        float q1v1 = i1 == 0 ? q1.x : i1 == 1 ? q1.y : i1 == 2 ? q1.z : q1.w;
        float q2v1 = i1 == 0 ? q2.x : i1 == 1 ? q2.y : i1 == 2 ? q2.z : q2.w;
        float q1v2 = i2 == 0 ? q1.x : i2 == 1 ? q1.y : i2 == 2 ? q1.z : q1.w;
        float q2v2 = i2 == 0 ? q2.x : i2 == 1 ? q2.y : i2 == 2 ? q2.z : q2.w;
        float sv1 = q1v1 + q2v1, sv2 = q1v2 + q2v2;
        float ee1 = expf(-(sv1 >= 0.f ? sv1 : LRELU_ALPHA * sv1));
        float ee2 = expf(-(sv2 >= 0.f ? sv2 : LRELU_ALPHA * sv2));
        int p = start[src] + atomicAdd(&cursor[src], 1);
        rec[p] = make_int4(dst, src | (i1 << 16) | (i2 << 18),
                           __float_as_int(ee1), __float_as_int(ee2));
    }
#pragma unroll
    for (int off = 32; off >= 1; off >>= 1) t2 += __shfl_xor(t2, off);
    if ((tid & 63) == 0) blk[tid >> 6] = t2;
    __syncthreads();
    if (tid == 0)
        atomicAdd(att_acc, (double)(blk[0] + blk[1] + blk[2] + blk[3]));
}

// ---------------------------------------------------------------------------
// K4: layer-1 gather. One block per node; 4 waves split the record list.
__global__ __launch_bounds__(256) void node_gather1(
        const int* __restrict__ start, const int4* __restrict__ rec,
        const float* __restrict__ h, float* __restrict__ hp,
        float* __restrict__ rowsum) {
    __shared__ float red[4][512];
    __shared__ float rsred[4][4];
    int n = blockIdx.x;
    int w = threadIdx.x >> 6, lane = threadIdx.x & 63;
    int j0 = start[n], j1 = start[n + 1];
    float a00 = 0.f, a01 = 0.f, a10 = 0.f, a11 = 0.f;
    float a20 = 0.f, a21 = 0.f, a30 = 0.f, a31 = 0.f;
    float rs0 = 0.f, rs1 = 0.f, rs2 = 0.f, rs3 = 0.f;
    for (int j = j0 + w; j < j1; j += 4) {
        int4 r = rec[j];
        int i1 = (r.y >> 16) & 3, i2 = (r.y >> 18) & 3;
        float w1 = __int_as_float(r.z), w2 = __int_as_float(r.w);
        const float* hr = h + (size_t)r.x * NF + lane;
        float v1a = hr[i1 * 128];
        float v1b = hr[i1 * 128 + 64];
        float v2a = hr[i2 * 128];
        float v2b = hr[i2 * 128 + 64];
        switch (i1) {
            case 0: a00 = fmaf(w1, v1a, a00); a01 = fmaf(w1, v1b, a01); rs0 += w1; break;
            case 1: a10 = fmaf(w1, v1a, a10); a11 = fmaf(w1, v1b, a11); rs1 += w1; break;
            case 2: a20 = fmaf(w1, v1a, a20); a21 = fmaf(w1, v1b, a21); rs2 += w1; break;
            default:a30 = fmaf(w1, v1a, a30); a31 = fmaf(w1, v1b, a31); rs3 += w1; break;
        }
        switch (i2) {
            case 0: a00 = fmaf(w2, v2a, a00); a01 = fmaf(w2, v2b, a01); rs0 += w2; break;
            case 1: a10 = fmaf(w2, v2a, a10); a11 = fmaf(w2, v2b, a11); rs1 += w2; break;
            case 2: a20 = fmaf(w2, v2a, a20); a21 = fmaf(w2, v2b, a21); rs2 += w2; break;
            default:a30 = fmaf(w2, v2a, a30); a31 = fmaf(w2, v2b, a31); rs3 += w2; break;
        }
    }
    red[w][lane]       = a00; red[w][64 + lane]  = a01;
    red[w][128 + lane] = a10; red[w][192 + lane] = a11;
    red[w][256 + lane] = a20; red[w][320 + lane] = a21;
    red[w][384 + lane] = a30; red[w][448 + lane] = a31;
    if (lane == 0) {
        rsred[w][0] = rs0; rsred[w][1] = rs1; rsred[w][2] = rs2; rsred[w][3] = rs3;
    }
    __syncthreads();
    int t = threadIdx.x;
    float s0 = (red[0][t] + red[1][t]) + (red[2][t] + red[3][t]);
    float s1 = (red[0][256 + t] + red[1][256 + t]) + (red[2][256 + t] + red[3][256 + t]);
    float* hpr = hp + (size_t)n * NF;
    hpr[t]       = s0;
    hpr[256 + t] = s1;
    if (t < 4)
        rowsum[n * 4 + t] = (rsred[0][t] + rsred[1][t]) + (rsred[2][t] + rsred[3][t]);
}

// ---------------------------------------------------------------------------
// K5: node pass as tiled GEMM with fused elu + epilogue dots.
__global__ __launch_bounds__(256) void node_pass_gemm(
        const float* __restrict__ hp, const float* __restrict__ rowsum,
        const float* __restrict__ Wo, const float* __restrict__ a_out,
        float* __restrict__ xo0, float* __restrict__ s1o, float* __restrict__ s2o) {
    __shared__ float As[16][128];
    __shared__ float Bs[16][64];
    int m0 = blockIdx.x * 128;
    int tid = threadIdx.x;
    int tm = tid >> 4, tn = tid & 15;
    float acc[8][4];
#pragma unroll
    for (int i = 0; i < 8; ++i)
#pragma unroll
        for (int j = 0; j < 4; ++j) acc[i][j] = 0.f;

    int arow = tid >> 1;
    int akc  = (tid & 1) * 8;
    int am = m0 + arow; if (am >= NN) am = NN - 1;
    int brow = tid >> 4, bcol = (tid & 15) * 4;

    for (int k0 = 0; k0 < NF; k0 += 16) {
        float rs = rowsum[am * 4 + ((k0 + akc) >> 7)] + EPSF;
        float4 v0 = *(const float4*)(hp + (size_t)am * NF + k0 + akc);
        float4 v1 = *(const float4*)(hp + (size_t)am * NF + k0 + akc + 4);
        float v[8] = {v0.x, v0.y, v0.z, v0.w, v1.x, v1.y, v1.z, v1.w};
#pragma unroll
        for (int i = 0; i < 8; ++i) {
            float t = v[i] / rs;
            v[i] = t > 0.f ? t : expm1f(t);
        }
        As[akc + 0][arow] = v[0]; As[akc + 1][arow] = v[1];
        As[akc + 2][arow] = v[2]; As[akc + 3][arow] = v[3];
        As[akc + 4][arow] = v[4]; As[akc + 5][arow] = v[5];
        As[akc + 6][arow] = v[6]; As[akc + 7][arow] = v[7];
        *(float4*)&Bs[brow][bcol] =
            *(const float4*)(Wo + (size_t)(k0 + brow) * NC + bcol);
        __syncthreads();
#pragma unroll
        for (int kk = 0; kk < 16; ++kk) {
            float4 av0 = *(float4*)&As[kk][tm * 8];
            float4 av1 = *(float4*)&As[kk][tm * 8 + 4];
            float4 bv  = *(float4*)&Bs[kk][tn * 4];
            float a[8] = {av0.x, av0.y, av0.z, av0.w, av1.x, av1.y, av1.z, av1.w};
            float b[4] = {bv.x, bv.y, bv.z, bv.w};
#pragma unroll
            for (int i = 0; i < 8; ++i)
#pragma unroll
                for (int j = 0; j < 4; ++j)
                    acc[i][j] = fmaf(a[i], b[j], acc[i][j]);
        }
        __syncthreads();
    }
    float4 ao1 = *(const float4*)(a_out + tn * 4);
    float4 ao2 = *(const float4*)(a_out + 64 + tn * 4);
#pragma unroll
    for (int i = 0; i < 8; ++i) {
        int m = m0 + tm * 8 + i;
        float4 o = make_float4(acc[i][0], acc[i][1], acc[i][2], acc[i][3]);
        float p1 = o.x * ao1.x + o.y * ao1.y + o.z * ao1.z + o.w * ao1.w;
        float p2 = o.x * ao2.x + o.y * ao2.y + o.z * ao2.z + o.w * ao2.w;
#pragma unroll
        for (int off = 8; off >= 1; off >>= 1) {
            p1 += __shfl_xor(p1, off);
            p2 += __shfl_xor(p2, off);
        }
        if (m < NN) {
            *(float4*)(xo0 + (size_t)m * NC + tn * 4) = o;
            if (tn == 0) { s1o[m] = p1; s2o[m] = p2; }
        }
    }
}

// ---------------------------------------------------------------------------
// K6: output attention gather with inline e-values (src == n), fused with
// elu + log-softmax.
__global__ __launch_bounds__(256) void node_gather2(
        const int* __restrict__ start, const int4* __restrict__ rec,
        const float* __restrict__ s1o, const float* __restrict__ s2o,
        const float* __restrict__ xo0, float* __restrict__ out) {
    __shared__ float red[4][64];
    __shared__ float rsl[4];
    int n = blockIdx.x;
    int w = threadIdx.x >> 6, lane = threadIdx.x & 63;
    int j0 = start[n], j1 = start[n + 1];
    float s1n = s1o[n];
    float acc = 0.f, rsum = 0.f;
    for (int j = j0 + w; j < j1; j += 4) {
        int d = rec[j].x;
        float sv = s1n + s2o[d];
        float e = expf(-(sv >= 0.f ? sv : LRELU_ALPHA * sv));
        acc = fmaf(e, xo0[(size_t)d * NC + lane], acc);
        rsum += e;
    }
    red[w][lane] = acc;
    if (lane == 0) rsl[w] = rsum;
    __syncthreads();
    if (w == 0) {
        float a = (red[0][lane] + red[1][lane]) + (red[2][lane] + red[3][lane]);
        float r = (rsl[0] + rsl[1]) + (rsl[2] + rsl[3]);
        float t = a / (r + EPSF);
        float v = t > 0.f ? t : expm1f(t);
        float m = v;
#pragma unroll
        for (int off = 32; off >= 1; off >>= 1) m = fmaxf(m, __shfl_xor(m, off));
        float p = expf(v - m);
#pragma unroll
        for (int off = 32; off >= 1; off >>= 1) p += __shfl_xor(p, off);
        out[(size_t)n * NC + lane] = v - m - logf(p);
    }
}

__global__ void finalize_att(const double* __restrict__ att_acc, float* __restrict__ out) {
    out[(size_t)NN * NC] = 1.f - (float)(att_acc[0] / (double)NE);
}

// ---------------------------------------------------------------------------
extern "C" void kernel_launch(void* const* d_in, const int* in_sizes, int n_in,
                              void* d_out, int out_size, void* d_ws, size_t ws_size,
                              hipStream_t stream) {
    const float* x     = (const float*)d_in[0];
    const int*   edge  = (const int*)d_in[1];
    const float* Wks   = (const float*)d_in[2];
    const float* a_k   = (const float*)d_in[3];
    const float* Wo    = (const float*)d_in[4];
    const float* a_att = (const float*)d_in[5];
    const float* a_out = (const float*)d_in[6];
    float* out = (float*)d_out;

    float* wsf = (float*)d_ws;
    float* h      = wsf + OFF_H;
    float* hp     = wsf + OFF_HP;
    int4*  rec    = (int4*)(wsf + OFF_REC);
    float* xo0    = wsf + OFF_XO0;
    float* s_src  = wsf + OFF_SSRC;
    float* s_dst  = wsf + OFF_SDST;
    float* s1a    = wsf + OFF_S1A;
    float* s2a    = wsf + OFF_S2A;
    float* rowsum = wsf + OFF_ROWSUM;
    float* s1o    = wsf + OFF_S1O;
    float* s2o    = wsf + OFF_S2O;
    int*   startp = (int*)(wsf + OFF_START);
    int*   cnt    = (int*)(wsf + OFF_CNT);
    int*   cursor = (int*)(wsf + OFF_CURSOR);
    double* att   = (double*)(wsf + OFF_ATT);

    // Transient aliases (dead before their regions' real users run):
    // xhi/xlo live in the hp region (hp written only by node_gather1, later);
    // Wt_hi/lo live in the rec region (rec written only by edge_pre1, later).
    u16* xhi  = (u16*)(wsf + OFF_HP);
    u16* xlo  = xhi + (size_t)NN * NF;
    u16* wthi = (u16*)(wsf + OFF_REC);
    u16* wtlo = wthi + (size_t)KF * NH * NF;

    // zero only the accumulation region (cnt, cursor, att) every call
    size_t zero_bytes = (size_t)(WS_FLOATS - OFF_CNT) * sizeof(float);
    hipMemsetAsync((char*)d_ws + (size_t)OFF_CNT * sizeof(float), 0, zero_bytes, stream);

    split_x<<<(NN * NF / 8 + 255) / 256, 256, 0, stream>>>(x, xhi, xlo);
    split_w<<<KF * NH, 256, 0, stream>>>(Wks, wthi, wtlo);
    gemm_h_mfma<<<dim3(4, (NN + 127) / 128), 256, 0, stream>>>(xhi, xlo, wthi, wtlo, h);
    compute_svals_h<<<(NN + 3) / 4, 256, 0, stream>>>(h, a_k, a_att,
                                                      s_src, s_dst, s1a, s2a);
    csr_count<<<(NE + 255) / 256, 256, 0, stream>>>(edge, cnt);
    csr_scan<<<1, 1024, 0, stream>>>(cnt, startp);
    edge_pre1<<<(NE + 255) / 256, 256, 0, stream>>>(edge, startp, cursor,
                                                    s_src, s_dst, s1a, s2a, rec, att);
    node_gather1<<<NN, 256, 0, stream>>>(startp, rec, h, hp, rowsum);
    node_pass_gemm<<<(NN + 127) / 128, 256, 0, stream>>>(hp, rowsum, Wo, a_out,
                                                         xo0, s1o, s2o);
    node_gather2<<<NN, 256, 0, stream>>>(startp, rec, s1o, s2o, xo0, out);
    finalize_att<<<1, 1, 0, stream>>>(att, out);
}

// Round 9
// 723.686 us; speedup vs baseline: 1.0526x; 1.0404x over previous
//
#include <hip/hip_runtime.h>
#include <math.h>

#define NN 50000
#define NE 800000
#define NF 512
#define NH 128
#define KF 4
#define NC 64
#define LRELU_ALPHA 0.2f
#define EPSF 1e-16f

typedef unsigned short u16;
typedef __attribute__((ext_vector_type(8))) short bf16x8;
typedef __attribute__((ext_vector_type(4))) float f32x4;

// ---------------- workspace layout (float offsets) ----------------
#define OFF_H      0LL                                  // h (NN,512)
#define OFF_HP     (OFF_H + (long long)NN * NF)         // hp (NN,512); ALSO xhi/xlo before node_gather1
#define OFF_REC    (OFF_HP + (long long)NN * NF)        // rec (NE int4); ALSO Wt split before edge_pre1
#define OFF_XO0    (OFF_REC + 4LL * NE)                 // (NN,64)
#define OFF_SSRC   (OFF_XO0 + (long long)NN * NC)       // (NN,4)
#define OFF_SDST   (OFF_SSRC + (long long)NN * KF)
#define OFF_S1A    (OFF_SDST + (long long)NN * KF)
#define OFF_S2A    (OFF_S1A + (long long)NN * KF)
#define OFF_ROWSUM (OFF_S2A + (long long)NN * KF)       // (NN,4)
#define OFF_S1O    (OFF_ROWSUM + (long long)NN * KF)    // (NN,)
#define OFF_S2O    (OFF_S1O + NN)
#define OFF_START  (OFF_S2O + NN)                       // (NN+1) ints, pad
// ---- zeroed-each-call region starts here ----
#define OFF_CNT    (OFF_START + NN + 4)                 // NN ints
#define OFF_CURSOR (OFF_CNT + NN)                       // NN ints
#define OFF_ATT    (OFF_CURSOR + NN)                    // double (2 floats)
#define WS_FLOATS  (OFF_ATT + 2)

__device__ __forceinline__ u16 bf16_rne(float f) {
    unsigned int u = __float_as_uint(f);
    return (u16)((u + 0x7FFFu + ((u >> 16) & 1u)) >> 16);
}
__device__ __forceinline__ float bf16_f(u16 b) {
    return __uint_as_float(((unsigned int)b) << 16);
}

// async global->LDS 16B: dest = wave-uniform base + lane*16 (HW rule)
__device__ __forceinline__ void gload_lds16(const u16* g, u16* l) {
    __builtin_amdgcn_global_load_lds(
        (const __attribute__((address_space(1))) void*)g,
        (__attribute__((address_space(3))) void*)l, 16, 0, 0);
}

// ---------------------------------------------------------------------------
// K0a: split x into hi/lo bf16 (RNE). 8 elements/thread.
__global__ __launch_bounds__(256) void split_x(const float* __restrict__ x,
                                               u16* __restrict__ xhi,
                                               u16* __restrict__ xlo) {
    size_t i = ((size_t)blockIdx.x * 256 + threadIdx.x) * 8;
    float4 v0 = *(const float4*)(x + i);
    float4 v1 = *(const float4*)(x + i + 4);
    float v[8] = {v0.x, v0.y, v0.z, v0.w, v1.x, v1.y, v1.z, v1.w};
    unsigned int hp[4], lp[4];
#pragma unroll
    for (int j = 0; j < 4; ++j) {
        u16 h0 = bf16_rne(v[2 * j]);
        u16 h1 = bf16_rne(v[2 * j + 1]);
        u16 l0 = bf16_rne(v[2 * j] - bf16_f(h0));
        u16 l1 = bf16_rne(v[2 * j + 1] - bf16_f(h1));
        hp[j] = (unsigned int)h0 | ((unsigned int)h1 << 16);
        lp[j] = (unsigned int)l0 | ((unsigned int)l1 << 16);
    }
    *(uint4*)(xhi + i) = make_uint4(hp[0], hp[1], hp[2], hp[3]);
    *(uint4*)(xlo + i) = make_uint4(lp[0], lp[1], lp[2], lp[3]);
}

// K0b: transpose + split W: Wt[kf*128+n][f] = split(Wks[kf][f][n]).
__global__ void split_w(const float* __restrict__ Wks,
                        u16* __restrict__ wthi, u16* __restrict__ wtlo) {
    int b = blockIdx.x;            // 0..511 = kf*128 + n
    int kf = b >> 7, n = b & 127;
    for (int f = threadIdx.x; f < NF; f += 256) {
        float v = Wks[(size_t)kf * (NF * NH) + (size_t)f * NH + n];
        u16 hb = bf16_rne(v);
        u16 lb = bf16_rne(v - bf16_f(hb));
        wthi[(size_t)b * NF + f] = hb;
        wtlo[(size_t)b * NF + f] = lb;
    }
}

// ---------------------------------------------------------------------------
// K1: h = x @ Wcat via 3-term split-bf16 MFMA. 128x128 tile, BK=32, 4 waves.
// Staging via global_load_lds dwordx4 into linear [128][32]-u16 buffers with
// involutive XOR col-swizzle c16 ^= (r&3)^((r>>2)&3) applied on the SOURCE
// address (gload_lds writes linearly) and on the fragment ds_read -> max
// 2-way bank aliasing (free). MFMA order identical to R8 -> h bit-identical.
__global__ __launch_bounds__(256) void gemm_h_mfma(
        const u16* __restrict__ xhi, const u16* __restrict__ xlo,
        const u16* __restrict__ wthi, const u16* __restrict__ wtlo,
        float* __restrict__ h) {
    __shared__ u16 Ah[128 * 32], Al[128 * 32], Bh[128 * 32], Bl[128 * 32];
    int m0 = blockIdx.y * 128, n0 = blockIdx.x * 128;
    int tid = threadIdx.x;
    int lane = tid & 63;
    int wave = tid >> 6, wm = wave >> 1, wn = wave & 1;
    f32x4 acc[4][4];
#pragma unroll
    for (int i = 0; i < 4; ++i)
#pragma unroll
        for (int j = 0; j < 4; ++j) acc[i][j] = (f32x4)(0.f);

    // -------- staging setup: wave w fills buffer w via 8 gload_lds --------
    u16* sbuf = (wave == 0) ? Ah : (wave == 1) ? Al : (wave == 2) ? Bh : Bl;
    const u16* gbase = (wave == 0) ? xhi : (wave == 1) ? xlo
                     : (wave == 2) ? wthi : wtlo;
    int rowbase = (wave < 2) ? m0 : n0;
    // source col16 pre-swizzle: c16_src = (l&3) ^ swz(r), r = 16i + (l>>2),
    // swz(r) = (r&3)^((r>>2)&3) = ((l>>2)&3) ^ (l>>4)   (i-independent)
    int c16s = (lane & 3) ^ ((lane >> 2) & 3) ^ (lane >> 4);
    const u16* gsrc[8];
#pragma unroll
    for (int i = 0; i < 8; ++i) {
        int rowg = rowbase + 16 * i + (lane >> 2);
        if (wave < 2 && rowg >= NN) rowg = NN - 1;  // clamp; OOB rows unused
        gsrc[i] = gbase + (size_t)rowg * NF + c16s * 8;
    }

    // -------- fragment-read addressing (swizzled) --------
    const int arow = wm * 64 + (lane & 15);
    const int brow = wn * 64 + (lane & 15);
    // rc16 = (lane>>4) ^ swz(row); swz(row) = (lane&3)^((lane>>2)&3) for all
    // frag rows (row = q*16 + (lane&15), q arbitrary)
    const int rc16 = (lane >> 4) ^ ((lane & 3) ^ ((lane >> 2) & 3));
    const int fragoff = rc16 * 8;   // u16 units

    for (int k0 = 0; k0 < NF; k0 += 32) {
        __syncthreads();   // previous step's frag reads complete
#pragma unroll
        for (int i = 0; i < 8; ++i)
            gload_lds16(gsrc[i] + k0, sbuf + i * 512);
        __syncthreads();   // vmcnt(0) drain + barrier
        bf16x8 ah[4], al[4], bh[4], bl[4];
#pragma unroll
        for (int mi = 0; mi < 4; ++mi) {
            ah[mi] = *(const bf16x8*)(Ah + (arow + mi * 16) * 32 + fragoff);
            al[mi] = *(const bf16x8*)(Al + (arow + mi * 16) * 32 + fragoff);
        }
#pragma unroll
        for (int ni = 0; ni < 4; ++ni) {
            bh[ni] = *(const bf16x8*)(Bh + (brow + ni * 16) * 32 + fragoff);
            bl[ni] = *(const bf16x8*)(Bl + (brow + ni * 16) * 32 + fragoff);
        }
#pragma unroll
        for (int mi = 0; mi < 4; ++mi)
#pragma unroll
            for (int ni = 0; ni < 4; ++ni) {
                acc[mi][ni] = __builtin_amdgcn_mfma_f32_16x16x32_bf16(
                    ah[mi], bh[ni], acc[mi][ni], 0, 0, 0);
                acc[mi][ni] = __builtin_amdgcn_mfma_f32_16x16x32_bf16(
                    ah[mi], bl[ni], acc[mi][ni], 0, 0, 0);
                acc[mi][ni] = __builtin_amdgcn_mfma_f32_16x16x32_bf16(
                    al[mi], bh[ni], acc[mi][ni], 0, 0, 0);
            }
    }
#pragma unroll
    for (int mi = 0; mi < 4; ++mi) {
        int mbase = m0 + wm * 64 + mi * 16 + (lane >> 4) * 4;
#pragma unroll
        for (int ni = 0; ni < 4; ++ni) {
            int n = n0 + wn * 64 + ni * 16 + (lane & 15);
#pragma unroll
            for (int r = 0; r < 4; ++r) {
                int m = mbase + r;
                if (m < NN) h[(size_t)m * NF + n] = acc[mi][ni][r];
            }
        }
    }
}

// ---------------------------------------------------------------------------
// K2: routing/attention scalars from h. Grid-stride over nodes so the 20KB
// LDS staging of a_k/a_att is amortized (~50 node-groups per block).
__global__ __launch_bounds__(256) void compute_svals_h(
        const float* __restrict__ h, const float* __restrict__ a_k,
        const float* __restrict__ a_att,
        float* __restrict__ s_src, float* __restrict__ s_dst,
        float* __restrict__ s1a, float* __restrict__ s2a) {
    __shared__ float Ak[4][1024];
    __shared__ float Aa[4][256];
    for (int i = threadIdx.x; i < 4096; i += 256) Ak[i >> 10][i & 1023] = a_k[i];
    for (int i = threadIdx.x; i < 1024; i += 256) Aa[i >> 8][i & 255] = a_att[i];
    __syncthreads();
    int w = threadIdx.x >> 6, lane = threadIdx.x & 63;
    for (int n = blockIdx.x * 4 + w; n < NN; n += gridDim.x * 4) {
        const float* hr = h + (size_t)n * NF;
        float accS[4] = {0, 0, 0, 0}, accD[4] = {0, 0, 0, 0};
        float accQ1[4] = {0, 0, 0, 0}, accQ2[4] = {0, 0, 0, 0};
#pragma unroll
        for (int i = 0; i < 8; ++i) {
            int f = i * 64 + lane;
            float hv = hr[f];
#pragma unroll
            for (int k = 0; k < 4; ++k) {
                accS[k] = fmaf(hv, Ak[k][f], accS[k]);
                accD[k] = fmaf(hv, Ak[k][512 + f], accD[k]);
            }
            accQ1[i >> 1] = fmaf(hv, Aa[i >> 1][f & 127], accQ1[i >> 1]);
            accQ2[i >> 1] = fmaf(hv, Aa[i >> 1][128 + (f & 127)], accQ2[i >> 1]);
        }
#pragma unroll
        for (int off = 32; off >= 1; off >>= 1) {
#pragma unroll
            for (int k = 0; k < 4; ++k) {
                accS[k] += __shfl_xor(accS[k], off);
                accD[k] += __shfl_xor(accD[k], off);
                accQ1[k] += __shfl_xor(accQ1[k], off);
                accQ2[k] += __shfl_xor(accQ2[k], off);
            }
        }
        if (lane == 0) {
#pragma unroll
            for (int k = 0; k < 4; ++k) {
                s_src[n * 4 + k] = accS[k];
                s_dst[n * 4 + k] = accD[k];
                s1a[n * 4 + k]   = accQ1[k];
                s2a[n * 4 + k]   = accQ2[k];
            }
        }
    }
}

// ---------------------------------------------------------------------------
// CSR build: count / scan
__global__ void csr_count(const int* __restrict__ edge, int* __restrict__ cnt) {
    int e = blockIdx.x * 256 + threadIdx.x;
    if (e < NE) atomicAdd(&cnt[edge[e]], 1);
}

__global__ __launch_bounds__(1024) void csr_scan(const int* __restrict__ cnt,
                                                 int* __restrict__ start) {
    __shared__ int part[1024];
    int t = threadIdx.x;
    const int CH = (NN + 1023) / 1024;  // 49
    int base = t * CH;
    int s = 0;
    for (int i = 0; i < CH; ++i) {
        int idx = base + i;
        if (idx < NN) s += cnt[idx];
    }
    part[t] = s;
    __syncthreads();
    for (int off = 1; off < 1024; off <<= 1) {
        int v = (t >= off) ? part[t - off] : 0;
        __syncthreads();
        part[t] += v;
        __syncthreads();
    }
    int run = (t == 0) ? 0 : part[t - 1];
    for (int i = 0; i < CH; ++i) {
        int idx = base + i;
        if (idx < NN) { start[idx] = run; run += cnt[idx]; }
    }
    if (t == 1023) start[NN] = run;
}

// ---------------------------------------------------------------------------
// K3: edge-parallel scalar precompute + CSR fill. One thread per edge.
__global__ __launch_bounds__(256) void edge_pre1(
        const int* __restrict__ edge, const int* __restrict__ start,
        int* __restrict__ cursor,
        const float* __restrict__ s_src, const float* __restrict__ s_dst,
        const float* __restrict__ s1a, const float* __restrict__ s2a,
        int4* __restrict__ rec, double* __restrict__ att_acc) {
    __shared__ float blk[4];
    int tid = threadIdx.x;
    int e = blockIdx.x * 256 + tid;
    float t2 = 0.f;
    if (e < NE) {
        int src = edge[e];
        int dst = edge[NE + e];
        float4 ss = *(const float4*)(s_src + (size_t)src * 4);
        float4 sd = *(const float4*)(s_dst + (size_t)dst * 4);
        float l0 = ss.x + sd.x, l1 = ss.y + sd.y, l2 = ss.z + sd.z, l3 = ss.w + sd.w;
        int i1 = 0; float v1 = l0;
        if (l1 > v1) { v1 = l1; i1 = 1; }
        if (l2 > v1) { v1 = l2; i1 = 2; }
        if (l3 > v1) { v1 = l3; i1 = 3; }
        int i2 = 0; float v2 = -3.4e38f;
        if (i1 != 0)            { v2 = l0; i2 = 0; }
        if (i1 != 1 && l1 > v2) { v2 = l1; i2 = 1; }
        if (i1 != 2 && l2 > v2) { v2 = l2; i2 = 2; }
        if (i1 != 3 && l3 > v2) { v2 = l3; i2 = 3; }
        float esum = expf(l0 - v1) + expf(l1 - v1) + expf(l2 - v1) + expf(l3 - v1);
        t2 = (1.f + expf(v2 - v1)) / esum;
        float4 q1 = *(const float4*)(s1a + (size_t)src * 4);
        float4 q2 = *(const float4*)(s2a + (size_t)dst * 4);
        float q1v1 = i1 == 0 ? q1.x : i1 == 1 ? q1.y : i1 == 2 ? q1.z : q1.w;
        float q2v1 = i1 == 0 ? q2.x : i1 == 1 ? q2.y : i1 == 2 ? q2.z : q2.w;
        float q1v2 = i2 == 0 ? q1.x : i2 == 1 ? q1.y : i2 == 2 ? q1.z : q1.w;
        float q2v2 = i2 == 0 ? q2.x : i2 == 1 ? q2.y : i2 == 2 ? q2.z : q2.w;
        float sv1 = q1v1 + q2v1, sv2 = q1v2 + q2v2;
        float ee1 = expf(-(sv1 >= 0.f ? sv1 : LRELU_ALPHA * sv1));
        float ee2 = expf(-(sv2 >= 0.f ? sv2 : LRELU_ALPHA * sv2));
        int p = start[src] + atomicAdd(&cursor[src], 1);
        rec[p] = make_int4(dst, src | (i1 << 16) | (i2 << 18),
                           __float_as_int(ee1), __float_as_int(ee2));
    }
#pragma unroll
    for (int off = 32; off >= 1; off >>= 1) t2 += __shfl_xor(t2, off);
    if ((tid & 63) == 0) blk[tid >> 6] = t2;
    __syncthreads();
    if (tid == 0)
        atomicAdd(att_acc, (double)(blk[0] + blk[1] + blk[2] + blk[3]));
}

// ---------------------------------------------------------------------------
// K4: layer-1 gather. One block per node; 4 waves split the record list.
__global__ __launch_bounds__(256) void node_gather1(
        const int* __restrict__ start, const int4* __restrict__ rec,
        const float* __restrict__ h, float* __restrict__ hp,
        float* __restrict__ rowsum) {
    __shared__ float red[4][512];
    __shared__ float rsred[4][4];
    int n = blockIdx.x;
    int w = threadIdx.x >> 6, lane = threadIdx.x & 63;
    int j0 = start[n], j1 = start[n + 1];
    float a00 = 0.f, a01 = 0.f, a10 = 0.f, a11 = 0.f;
    float a20 = 0.f, a21 = 0.f, a30 = 0.f, a31 = 0.f;
    float rs0 = 0.f, rs1 = 0.f, rs2 = 0.f, rs3 = 0.f;
    for (int j = j0 + w; j < j1; j += 4) {
        int4 r = rec[j];
        int i1 = (r.y >> 16) & 3, i2 = (r.y >> 18) & 3;
        float w1 = __int_as_float(r.z), w2 = __int_as_float(r.w);
        const float* hr = h + (size_t)r.x * NF + lane;
        float v1a = hr[i1 * 128];
        float v1b = hr[i1 * 128 + 64];
        float v2a = hr[i2 * 128];
        float v2b = hr[i2 * 128 + 64];
        switch (i1) {
            case 0: a00 = fmaf(w1, v1a, a00); a01 = fmaf(w1, v1b, a01); rs0 += w1; break;
            case 1: a10 = fmaf(w1, v1a, a10); a11 = fmaf(w1, v1b, a11); rs1 += w1; break;
            case 2: a20 = fmaf(w1, v1a, a20); a21 = fmaf(w1, v1b, a21); rs2 += w1; break;
            default:a30 = fmaf(w1, v1a, a30); a31 = fmaf(w1, v1b, a31); rs3 += w1; break;
        }
        switch (i2) {
            case 0: a00 = fmaf(w2, v2a, a00); a01 = fmaf(w2, v2b, a01); rs0 += w2; break;
            case 1: a10 = fmaf(w2, v2a, a10); a11 = fmaf(w2, v2b, a11); rs1 += w2; break;
            case 2: a20 = fmaf(w2, v2a, a20); a21 = fmaf(w2, v2b, a21); rs2 += w2; break;
            default:a30 = fmaf(w2, v2a, a30); a31 = fmaf(w2, v2b, a31); rs3 += w2; break;
        }
    }
    red[w][lane]       = a00; red[w][64 + lane]  = a01;
    red[w][128 + lane] = a10; red[w][192 + lane] = a11;
    red[w][256 + lane] = a20; red[w][320 + lane] = a21;
    red[w][384 + lane] = a30; red[w][448 + lane] = a31;
    if (lane == 0) {
        rsred[w][0] = rs0; rsred[w][1] = rs1; rsred[w][2] = rs2; rsred[w][3] = rs3;
    }
    __syncthreads();
    int t = threadIdx.x;
    float s0 = (red[0][t] + red[1][t]) + (red[2][t] + red[3][t]);
    float s1 = (red[0][256 + t] + red[1][256 + t]) + (red[2][256 + t] + red[3][256 + t]);
    float* hpr = hp + (size_t)n * NF;
    hpr[t]       = s0;
    hpr[256 + t] = s1;
    if (t < 4)
        rowsum[n * 4 + t] = (rsred[0][t] + rsred[1][t]) + (rsred[2][t] + rsred[3][t]);
}

// ---------------------------------------------------------------------------
// K5: node pass as tiled GEMM with fused elu + epilogue dots.
__global__ __launch_bounds__(256) void node_pass_gemm(
        const float* __restrict__ hp, const float* __restrict__ rowsum,
        const float* __restrict__ Wo, const float* __restrict__ a_out,
        float* __restrict__ xo0, float* __restrict__ s1o, float* __restrict__ s2o) {
    __shared__ float As[16][128];
    __shared__ float Bs[16][64];
    int m0 = blockIdx.x * 128;
    int tid = threadIdx.x;
    int tm = tid >> 4, tn = tid & 15;
    float acc[8][4];
#pragma unroll
    for (int i = 0; i < 8; ++i)
#pragma unroll
        for (int j = 0; j < 4; ++j) acc[i][j] = 0.f;

    int arow = tid >> 1;
    int akc  = (tid & 1) * 8;
    int am = m0 + arow; if (am >= NN) am = NN - 1;
    int brow = tid >> 4, bcol = (tid & 15) * 4;

    for (int k0 = 0; k0 < NF; k0 += 16) {
        float rs = rowsum[am * 4 + ((k0 + akc) >> 7)] + EPSF;
        float4 v0 = *(const float4*)(hp + (size_t)am * NF + k0 + akc);
        float4 v1 = *(const float4*)(hp + (size_t)am * NF + k0 + akc + 4);
        float v[8] = {v0.x, v0.y, v0.z, v0.w, v1.x, v1.y, v1.z, v1.w};
#pragma unroll
        for (int i = 0; i < 8; ++i) {
            float t = v[i] / rs;
            v[i] = t > 0.f ? t : expm1f(t);
        }
        As[akc + 0][arow] = v[0]; As[akc + 1][arow] = v[1];
        As[akc + 2][arow] = v[2]; As[akc + 3][arow] = v[3];
        As[akc + 4][arow] = v[4]; As[akc + 5][arow] = v[5];
        As[akc + 6][arow] = v[6]; As[akc + 7][arow] = v[7];
        *(float4*)&Bs[brow][bcol] =
            *(const float4*)(Wo + (size_t)(k0 + brow) * NC + bcol);
        __syncthreads();
#pragma unroll
        for (int kk = 0; kk < 16; ++kk) {
            float4 av0 = *(float4*)&As[kk][tm * 8];
            float4 av1 = *(float4*)&As[kk][tm * 8 + 4];
            float4 bv  = *(float4*)&Bs[kk][tn * 4];
            float a[8] = {av0.x, av0.y, av0.z, av0.w, av1.x, av1.y, av1.z, av1.w};
            float b[4] = {bv.x, bv.y, bv.z, bv.w};
#pragma unroll
            for (int i = 0; i < 8; ++i)
#pragma unroll
                for (int j = 0; j < 4; ++j)
                    acc[i][j] = fmaf(a[i], b[j], acc[i][j]);
        }
        __syncthreads();
    }
    float4 ao1 = *(const float4*)(a_out + tn * 4);
    float4 ao2 = *(const float4*)(a_out + 64 + tn * 4);
#pragma unroll
    for (int i = 0; i < 8; ++i) {
        int m = m0 + tm * 8 + i;
        float4 o = make_float4(acc[i][0], acc[i][1], acc[i][2], acc[i][3]);
        float p1 = o.x * ao1.x + o.y * ao1.y + o.z * ao1.z + o.w * ao1.w;
        float p2 = o.x * ao2.x + o.y * ao2.y + o.z * ao2.z + o.w * ao2.w;
#pragma unroll
        for (int off = 8; off >= 1; off >>= 1) {
            p1 += __shfl_xor(p1, off);
            p2 += __shfl_xor(p2, off);
        }
        if (m < NN) {
            *(float4*)(xo0 + (size_t)m * NC + tn * 4) = o;
            if (tn == 0) { s1o[m] = p1; s2o[m] = p2; }
        }
    }
}

// ---------------------------------------------------------------------------
// K6: output attention gather with inline e-values (src == n), fused with
// elu + log-softmax.
__global__ __launch_bounds__(256) void node_gather2(
        const int* __restrict__ start, const int4* __restrict__ rec,
        const float* __restrict__ s1o, const float* __restrict__ s2o,
        const float* __restrict__ xo0, float* __restrict__ out) {
    __shared__ float red[4][64];
    __shared__ float rsl[4];
    int n = blockIdx.x;
    int w = threadIdx.x >> 6, lane = threadIdx.x & 63;
    int j0 = start[n], j1 = start[n + 1];
    float s1n = s1o[n];
    float acc = 0.f, rsum = 0.f;
    for (int j = j0 + w; j < j1; j += 4) {
        int d = rec[j].x;
        float sv = s1n + s2o[d];
        float e = expf(-(sv >= 0.f ? sv : LRELU_ALPHA * sv));
        acc = fmaf(e, xo0[(size_t)d * NC + lane], acc);
        rsum += e;
    }
    red[w][lane] = acc;
    if (lane == 0) rsl[w] = rsum;
    __syncthreads();
    if (w == 0) {
        float a = (red[0][lane] + red[1][lane]) + (red[2][lane] + red[3][lane]);
        float r = (rsl[0] + rsl[1]) + (rsl[2] + rsl[3]);
        float t = a / (r + EPSF);
        float v = t > 0.f ? t : expm1f(t);
        float m = v;
#pragma unroll
        for (int off = 32; off >= 1; off >>= 1) m = fmaxf(m, __shfl_xor(m, off));
        float p = expf(v - m);
#pragma unroll
        for (int off = 32; off >= 1; off >>= 1) p += __shfl_xor(p, off);
        out[(size_t)n * NC + lane] = v - m - logf(p);
    }
}

__global__ void finalize_att(const double* __restrict__ att_acc, float* __restrict__ out) {
    out[(size_t)NN * NC] = 1.f - (float)(att_acc[0] / (double)NE);
}

// ---------------------------------------------------------------------------
extern "C" void kernel_launch(void* const* d_in, const int* in_sizes, int n_in,
                              void* d_out, int out_size, void* d_ws, size_t ws_size,
                              hipStream_t stream) {
    const float* x     = (const float*)d_in[0];
    const int*   edge  = (const int*)d_in[1];
    const float* Wks   = (const float*)d_in[2];
    const float* a_k   = (const float*)d_in[3];
    const float* Wo    = (const float*)d_in[4];
    const float* a_att = (const float*)d_in[5];
    const float* a_out = (const float*)d_in[6];
    float* out = (float*)d_out;

    float* wsf = (float*)d_ws;
    float* h      = wsf + OFF_H;
    float* hp     = wsf + OFF_HP;
    int4*  rec    = (int4*)(wsf + OFF_REC);
    float* xo0    = wsf + OFF_XO0;
    float* s_src  = wsf + OFF_SSRC;
    float* s_dst  = wsf + OFF_SDST;
    float* s1a    = wsf + OFF_S1A;
    float* s2a    = wsf + OFF_S2A;
    float* rowsum = wsf + OFF_ROWSUM;
    float* s1o    = wsf + OFF_S1O;
    float* s2o    = wsf + OFF_S2O;
    int*   startp = (int*)(wsf + OFF_START);
    int*   cnt    = (int*)(wsf + OFF_CNT);
    int*   cursor = (int*)(wsf + OFF_CURSOR);
    double* att   = (double*)(wsf + OFF_ATT);

    // Transient aliases (dead before their regions' real users run):
    // xhi/xlo live in the hp region (hp written only by node_gather1, later);
    // Wt_hi/lo live in the rec region (rec written only by edge_pre1, later).
    u16* xhi  = (u16*)(wsf + OFF_HP);
    u16* xlo  = xhi + (size_t)NN * NF;
    u16* wthi = (u16*)(wsf + OFF_REC);
    u16* wtlo = wthi + (size_t)KF * NH * NF;

    // zero only the accumulation region (cnt, cursor, att) every call
    size_t zero_bytes = (size_t)(WS_FLOATS - OFF_CNT) * sizeof(float);
    hipMemsetAsync((char*)d_ws + (size_t)OFF_CNT * sizeof(float), 0, zero_bytes, stream);

    split_x<<<(NN * NF / 8 + 255) / 256, 256, 0, stream>>>(x, xhi, xlo);
    split_w<<<KF * NH, 256, 0, stream>>>(Wks, wthi, wtlo);
    gemm_h_mfma<<<dim3(4, (NN + 127) / 128), 256, 0, stream>>>(xhi, xlo, wthi, wtlo, h);
    compute_svals_h<<<256, 256, 0, stream>>>(h, a_k, a_att,
                                             s_src, s_dst, s1a, s2a);
    csr_count<<<(NE + 255) / 256, 256, 0, stream>>>(edge, cnt);
    csr_scan<<<1, 1024, 0, stream>>>(cnt, startp);
    edge_pre1<<<(NE + 255) / 256, 256, 0, stream>>>(edge, startp, cursor,
                                                    s_src, s_dst, s1a, s2a, rec, att);
    node_gather1<<<NN, 256, 0, stream>>>(startp, rec, h, hp, rowsum);
    node_pass_gemm<<<(NN + 127) / 128, 256, 0, stream>>>(hp, rowsum, Wo, a_out,
                                                         xo0, s1o, s2o);
    node_gather2<<<NN, 256, 0, stream>>>(startp, rec, s1o, s2o, xo0, out);
    finalize_att<<<1, 1, 0, stream>>>(att, out);
}

// Round 10
// 647.915 us; speedup vs baseline: 1.1757x; 1.1169x over previous
//
#include <hip/hip_runtime.h>
#include <math.h>

#define NN 50000
#define NE 800000
#define NF 512
#define NH 128
#define KF 4
#define NC 64
#define LRELU_ALPHA 0.2f
#define EPSF 1e-16f

typedef unsigned short u16;
typedef __attribute__((ext_vector_type(8))) short bf16x8;
typedef __attribute__((ext_vector_type(4))) float f32x4;

// ---------------- workspace layout (float offsets) ----------------
#define OFF_H      0LL                                  // h (NN,512)
#define OFF_HP     (OFF_H + (long long)NN * NF)         // xhi/xlo (gemm in), then ahi/alo (elu-split planes)
#define OFF_REC    (OFF_HP + (long long)NN * NF)        // rec (NE int4); ALSO Wt split before edge_pre1
#define OFF_XO0    (OFF_REC + 4LL * NE)                 // (NN,64)
#define OFF_SSRC   (OFF_XO0 + (long long)NN * NC)       // (NN,4)
#define OFF_SDST   (OFF_SSRC + (long long)NN * KF)
#define OFF_S1A    (OFF_SDST + (long long)NN * KF)
#define OFF_S2A    (OFF_S1A + (long long)NN * KF)
#define OFF_WOT    (OFF_S2A + (long long)NN * KF)       // wohi/wolo (64x512 u16 each) in old rowsum slot
#define OFF_S1O    (OFF_WOT + (long long)NN * KF)       // (NN,)
#define OFF_S2O    (OFF_S1O + NN)
#define OFF_START  (OFF_S2O + NN)                       // (NN+1) ints, pad
// ---- zeroed-each-call region starts here ----
#define OFF_CNT    (OFF_START + NN + 4)                 // NN ints
#define OFF_CURSOR (OFF_CNT + NN)                       // NN ints
#define OFF_ATT    (OFF_CURSOR + NN)                    // double (2 floats)
#define WS_FLOATS  (OFF_ATT + 2)

__device__ __forceinline__ u16 bf16_rne(float f) {
    unsigned int u = __float_as_uint(f);
    return (u16)((u + 0x7FFFu + ((u >> 16) & 1u)) >> 16);
}
__device__ __forceinline__ float bf16_f(u16 b) {
    return __uint_as_float(((unsigned int)b) << 16);
}

// async global->LDS 16B: dest = wave-uniform base + lane*16 (HW rule)
__device__ __forceinline__ void gload_lds16(const u16* g, u16* l) {
    __builtin_amdgcn_global_load_lds(
        (const __attribute__((address_space(1))) void*)g,
        (__attribute__((address_space(3))) void*)l, 16, 0, 0);
}

// ---------------------------------------------------------------------------
// K0a: split x into hi/lo bf16 (blocks < NSPLIT) + csr_count (rest).
#define NSPLIT 12500   // NN*NF/8/256
__global__ __launch_bounds__(256) void split_x_count(
        const float* __restrict__ x, u16* __restrict__ xhi, u16* __restrict__ xlo,
        const int* __restrict__ edge, int* __restrict__ cnt) {
    if (blockIdx.x < NSPLIT) {
        size_t i = ((size_t)blockIdx.x * 256 + threadIdx.x) * 8;
        float4 v0 = *(const float4*)(x + i);
        float4 v1 = *(const float4*)(x + i + 4);
        float v[8] = {v0.x, v0.y, v0.z, v0.w, v1.x, v1.y, v1.z, v1.w};
        unsigned int hp[4], lp[4];
#pragma unroll
        for (int j = 0; j < 4; ++j) {
            u16 h0 = bf16_rne(v[2 * j]);
            u16 h1 = bf16_rne(v[2 * j + 1]);
            u16 l0 = bf16_rne(v[2 * j] - bf16_f(h0));
            u16 l1 = bf16_rne(v[2 * j + 1] - bf16_f(h1));
            hp[j] = (unsigned int)h0 | ((unsigned int)h1 << 16);
            lp[j] = (unsigned int)l0 | ((unsigned int)l1 << 16);
        }
        *(uint4*)(xhi + i) = make_uint4(hp[0], hp[1], hp[2], hp[3]);
        *(uint4*)(xlo + i) = make_uint4(lp[0], lp[1], lp[2], lp[3]);
    } else {
        int e = (blockIdx.x - NSPLIT) * 256 + threadIdx.x;
        if (e < NE) atomicAdd(&cnt[edge[e]], 1);
    }
}

// K0b: blocks 0..511: Wt[kf*128+n][f] = split(Wks[kf][f][n]);
//      blocks 512..575: WoT[n][f] = split(Wo[f][n]).
__global__ void split_w(const float* __restrict__ Wks, const float* __restrict__ Wo,
                        u16* __restrict__ wthi, u16* __restrict__ wtlo,
                        u16* __restrict__ wohi, u16* __restrict__ wolo) {
    int b = blockIdx.x;
    if (b < 512) {
        int kf = b >> 7, n = b & 127;
        for (int f = threadIdx.x; f < NF; f += 256) {
            float v = Wks[(size_t)kf * (NF * NH) + (size_t)f * NH + n];
            u16 hb = bf16_rne(v);
            u16 lb = bf16_rne(v - bf16_f(hb));
            wthi[(size_t)b * NF + f] = hb;
            wtlo[(size_t)b * NF + f] = lb;
        }
    } else {
        int n = b - 512;   // 0..63
        for (int f = threadIdx.x; f < NF; f += 256) {
            float v = Wo[(size_t)f * NC + n];
            u16 hb = bf16_rne(v);
            u16 lb = bf16_rne(v - bf16_f(hb));
            wohi[(size_t)n * NF + f] = hb;
            wolo[(size_t)n * NF + f] = lb;
        }
    }
}

// ---------------------------------------------------------------------------
// K1: h = x @ Wcat via 3-term split-bf16 MFMA, gload_lds staging, XCD-chunked
// bijective block swizzle (consecutive wg share the A row-block -> L2 reuse).
__global__ __launch_bounds__(256) void gemm_h_mfma(
        const u16* __restrict__ xhi, const u16* __restrict__ xlo,
        const u16* __restrict__ wthi, const u16* __restrict__ wtlo,
        float* __restrict__ h) {
    __shared__ u16 Ah[128 * 32], Al[128 * 32], Bh[128 * 32], Bl[128 * 32];
    // bijective XCD swizzle (m204): nwg = 4*391 = 1564, q=195, r=4
    const int nwg = 4 * ((NN + 127) / 128);
    const int q = nwg / 8, r = nwg % 8;
    int o = blockIdx.x;
    int xcd = o & 7, pos = o >> 3;
    int wg = (xcd < r ? xcd * (q + 1) : r * (q + 1) + (xcd - r) * q) + pos;
    int m0 = (wg >> 2) * 128, n0 = (wg & 3) * 128;

    int tid = threadIdx.x;
    int lane = tid & 63;
    int wave = tid >> 6, wm = wave >> 1, wn = wave & 1;
    f32x4 acc[4][4];
#pragma unroll
    for (int i = 0; i < 4; ++i)
#pragma unroll
        for (int j = 0; j < 4; ++j) acc[i][j] = (f32x4)(0.f);

    u16* sbuf = (wave == 0) ? Ah : (wave == 1) ? Al : (wave == 2) ? Bh : Bl;
    const u16* gbase = (wave == 0) ? xhi : (wave == 1) ? xlo
                     : (wave == 2) ? wthi : wtlo;
    int rowbase = (wave < 2) ? m0 : n0;
    int c16s = (lane & 3) ^ ((lane >> 2) & 3) ^ (lane >> 4);
    const u16* gsrc[8];
#pragma unroll
    for (int i = 0; i < 8; ++i) {
        int rowg = rowbase + 16 * i + (lane >> 2);
        if (wave < 2 && rowg >= NN) rowg = NN - 1;
        gsrc[i] = gbase + (size_t)rowg * NF + c16s * 8;
    }

    const int arow = wm * 64 + (lane & 15);
    const int brow = wn * 64 + (lane & 15);
    const int rc16 = (lane >> 4) ^ ((lane & 3) ^ ((lane >> 2) & 3));
    const int fragoff = rc16 * 8;

    for (int k0 = 0; k0 < NF; k0 += 32) {
        __syncthreads();
#pragma unroll
        for (int i = 0; i < 8; ++i)
            gload_lds16(gsrc[i] + k0, sbuf + i * 512);
        __syncthreads();
        bf16x8 ah[4], al[4], bh[4], bl[4];
#pragma unroll
        for (int mi = 0; mi < 4; ++mi) {
            ah[mi] = *(const bf16x8*)(Ah + (arow + mi * 16) * 32 + fragoff);
            al[mi] = *(const bf16x8*)(Al + (arow + mi * 16) * 32 + fragoff);
        }
#pragma unroll
        for (int ni = 0; ni < 4; ++ni) {
            bh[ni] = *(const bf16x8*)(Bh + (brow + ni * 16) * 32 + fragoff);
            bl[ni] = *(const bf16x8*)(Bl + (brow + ni * 16) * 32 + fragoff);
        }
#pragma unroll
        for (int mi = 0; mi < 4; ++mi)
#pragma unroll
            for (int ni = 0; ni < 4; ++ni) {
                acc[mi][ni] = __builtin_amdgcn_mfma_f32_16x16x32_bf16(
                    ah[mi], bh[ni], acc[mi][ni], 0, 0, 0);
                acc[mi][ni] = __builtin_amdgcn_mfma_f32_16x16x32_bf16(
                    ah[mi], bl[ni], acc[mi][ni], 0, 0, 0);
                acc[mi][ni] = __builtin_amdgcn_mfma_f32_16x16x32_bf16(
                    al[mi], bh[ni], acc[mi][ni], 0, 0, 0);
            }
    }
#pragma unroll
    for (int mi = 0; mi < 4; ++mi) {
        int mbase = m0 + wm * 64 + mi * 16 + (lane >> 4) * 4;
#pragma unroll
        for (int ni = 0; ni < 4; ++ni) {
            int n = n0 + wn * 64 + ni * 16 + (lane & 15);
#pragma unroll
            for (int r2 = 0; r2 < 4; ++r2) {
                int m = mbase + r2;
                if (m < NN) h[(size_t)m * NF + n] = acc[mi][ni][r2];
            }
        }
    }
}

// ---------------------------------------------------------------------------
// K2: routing/attention scalars from h. Grid-stride, LDS-staged a_k/a_att.
__global__ __launch_bounds__(256) void compute_svals_h(
        const float* __restrict__ h, const float* __restrict__ a_k,
        const float* __restrict__ a_att,
        float* __restrict__ s_src, float* __restrict__ s_dst,
        float* __restrict__ s1a, float* __restrict__ s2a) {
    __shared__ float Ak[4][1024];
    __shared__ float Aa[4][256];
    for (int i = threadIdx.x; i < 4096; i += 256) Ak[i >> 10][i & 1023] = a_k[i];
    for (int i = threadIdx.x; i < 1024; i += 256) Aa[i >> 8][i & 255] = a_att[i];
    __syncthreads();
    int w = threadIdx.x >> 6, lane = threadIdx.x & 63;
    for (int n = blockIdx.x * 4 + w; n < NN; n += gridDim.x * 4) {
        const float* hr = h + (size_t)n * NF;
        float accS[4] = {0, 0, 0, 0}, accD[4] = {0, 0, 0, 0};
        float accQ1[4] = {0, 0, 0, 0}, accQ2[4] = {0, 0, 0, 0};
#pragma unroll
        for (int i = 0; i < 8; ++i) {
            int f = i * 64 + lane;
            float hv = hr[f];
#pragma unroll
            for (int k = 0; k < 4; ++k) {
                accS[k] = fmaf(hv, Ak[k][f], accS[k]);
                accD[k] = fmaf(hv, Ak[k][512 + f], accD[k]);
            }
            accQ1[i >> 1] = fmaf(hv, Aa[i >> 1][f & 127], accQ1[i >> 1]);
            accQ2[i >> 1] = fmaf(hv, Aa[i >> 1][128 + (f & 127)], accQ2[i >> 1]);
        }
#pragma unroll
        for (int off = 32; off >= 1; off >>= 1) {
#pragma unroll
            for (int k = 0; k < 4; ++k) {
                accS[k] += __shfl_xor(accS[k], off);
                accD[k] += __shfl_xor(accD[k], off);
                accQ1[k] += __shfl_xor(accQ1[k], off);
                accQ2[k] += __shfl_xor(accQ2[k], off);
            }
        }
        if (lane == 0) {
#pragma unroll
            for (int k = 0; k < 4; ++k) {
                s_src[n * 4 + k] = accS[k];
                s_dst[n * 4 + k] = accD[k];
                s1a[n * 4 + k]   = accQ1[k];
                s2a[n * 4 + k]   = accQ2[k];
            }
        }
    }
}

// ---------------------------------------------------------------------------
__global__ __launch_bounds__(1024) void csr_scan(const int* __restrict__ cnt,
                                                 int* __restrict__ start) {
    __shared__ int part[1024];
    int t = threadIdx.x;
    const int CH = (NN + 1023) / 1024;  // 49
    int base = t * CH;
    int s = 0;
    for (int i = 0; i < CH; ++i) {
        int idx = base + i;
        if (idx < NN) s += cnt[idx];
    }
    part[t] = s;
    __syncthreads();
    for (int off = 1; off < 1024; off <<= 1) {
        int v = (t >= off) ? part[t - off] : 0;
        __syncthreads();
        part[t] += v;
        __syncthreads();
    }
    int run = (t == 0) ? 0 : part[t - 1];
    for (int i = 0; i < CH; ++i) {
        int idx = base + i;
        if (idx < NN) { start[idx] = run; run += cnt[idx]; }
    }
    if (t == 1023) start[NN] = run;
}

// ---------------------------------------------------------------------------
// K3: edge-parallel scalar precompute + CSR fill. One thread per edge.
__global__ __launch_bounds__(256) void edge_pre1(
        const int* __restrict__ edge, const int* __restrict__ start,
        int* __restrict__ cursor,
        const float* __restrict__ s_src, const float* __restrict__ s_dst,
        const float* __restrict__ s1a, const float* __restrict__ s2a,
        int4* __restrict__ rec, double* __restrict__ att_acc) {
    __shared__ float blk[4];
    int tid = threadIdx.x;
    int e = blockIdx.x * 256 + tid;
    float t2 = 0.f;
    if (e < NE) {
        int src = edge[e];
        int dst = edge[NE + e];
        float4 ss = *(const float4*)(s_src + (size_t)src * 4);
        float4 sd = *(const float4*)(s_dst + (size_t)dst * 4);
        float l0 = ss.x + sd.x, l1 = ss.y + sd.y, l2 = ss.z + sd.z, l3 = ss.w + sd.w;
        int i1 = 0; float v1 = l0;
        if (l1 > v1) { v1 = l1; i1 = 1; }
        if (l2 > v1) { v1 = l2; i1 = 2; }
        if (l3 > v1) { v1 = l3; i1 = 3; }
        int i2 = 0; float v2 = -3.4e38f;
        if (i1 != 0)            { v2 = l0; i2 = 0; }
        if (i1 != 1 && l1 > v2) { v2 = l1; i2 = 1; }
        if (i1 != 2 && l2 > v2) { v2 = l2; i2 = 2; }
        if (i1 != 3 && l3 > v2) { v2 = l3; i2 = 3; }
        float esum = expf(l0 - v1) + expf(l1 - v1) + expf(l2 - v1) + expf(l3 - v1);
        t2 = (1.f + expf(v2 - v1)) / esum;
        float4 q1 = *(const float4*)(s1a + (size_t)src * 4);
        float4 q2 = *(const float4*)(s2a + (size_t)dst * 4);
        float q1v1 = i1 == 0 ? q1.x : i1 == 1 ? q1.y : i1 == 2 ? q1.z : q1.w;
        float q2v1 = i1 == 0 ? q2.x : i1 == 1 ? q2.y : i1 == 2 ? q2.z : q2.w;
        float q1v2 = i2 == 0 ? q1.x : i2 == 1 ? q1.y : i2 == 2 ? q1.z : q1.w;
        float q2v2 = i2 == 0 ? q2.x : i2 == 1 ? q2.y : i2 == 2 ? q2.z : q2.w;
        float sv1 = q1v1 + q2v1, sv2 = q1v2 + q2v2;
        float ee1 = expf(-(sv1 >= 0.f ? sv1 : LRELU_ALPHA * sv1));
        float ee2 = expf(-(sv2 >= 0.f ? sv2 : LRELU_ALPHA * sv2));
        int p = start[src] + atomicAdd(&cursor[src], 1);
        rec[p] = make_int4(dst, src | (i1 << 16) | (i2 << 18),
                           __float_as_int(ee1), __float_as_int(ee2));
    }
#pragma unroll
    for (int off = 32; off >= 1; off >>= 1) t2 += __shfl_xor(t2, off);
    if ((tid & 63) == 0) blk[tid >> 6] = t2;
    __syncthreads();
    if (tid == 0)
        atomicAdd(att_acc, (double)(blk[0] + blk[1] + blk[2] + blk[3]));
}

// ---------------------------------------------------------------------------
// K4: layer-1 gather. One block per node; 4 waves split the record list.
// Epilogue applies elu(hp/rowsum) and writes hi/lo bf16 planes (ahi/alo)
// ready for node_pass_mfma's gload_lds staging.
__global__ __launch_bounds__(256) void node_gather1(
        const int* __restrict__ start, const int4* __restrict__ rec,
        const float* __restrict__ h,
        u16* __restrict__ ahi, u16* __restrict__ alo) {
    __shared__ float red[4][512];
    __shared__ float rsred[4][4];
    int n = blockIdx.x;
    int w = threadIdx.x >> 6, lane = threadIdx.x & 63;
    int j0 = start[n], j1 = start[n + 1];
    float a00 = 0.f, a01 = 0.f, a10 = 0.f, a11 = 0.f;
    float a20 = 0.f, a21 = 0.f, a30 = 0.f, a31 = 0.f;
    float rs0 = 0.f, rs1 = 0.f, rs2 = 0.f, rs3 = 0.f;
    for (int j = j0 + w; j < j1; j += 4) {
        int4 r = rec[j];
        int i1 = (r.y >> 16) & 3, i2 = (r.y >> 18) & 3;
        float w1 = __int_as_float(r.z), w2 = __int_as_float(r.w);
        const float* hr = h + (size_t)r.x * NF + lane;
        float v1a = hr[i1 * 128];
        float v1b = hr[i1 * 128 + 64];
        float v2a = hr[i2 * 128];
        float v2b = hr[i2 * 128 + 64];
        switch (i1) {
            case 0: a00 = fmaf(w1, v1a, a00); a01 = fmaf(w1, v1b, a01); rs0 += w1; break;
            case 1: a10 = fmaf(w1, v1a, a10); a11 = fmaf(w1, v1b, a11); rs1 += w1; break;
            case 2: a20 = fmaf(w1, v1a, a20); a21 = fmaf(w1, v1b, a21); rs2 += w1; break;
            default:a30 = fmaf(w1, v1a, a30); a31 = fmaf(w1, v1b, a31); rs3 += w1; break;
        }
        switch (i2) {
            case 0: a00 = fmaf(w2, v2a, a00); a01 = fmaf(w2, v2b, a01); rs0 += w2; break;
            case 1: a10 = fmaf(w2, v2a, a10); a11 = fmaf(w2, v2b, a11); rs1 += w2; break;
            case 2: a20 = fmaf(w2, v2a, a20); a21 = fmaf(w2, v2b, a21); rs2 += w2; break;
            default:a30 = fmaf(w2, v2a, a30); a31 = fmaf(w2, v2b, a31); rs3 += w2; break;
        }
    }
    red[w][lane]       = a00; red[w][64 + lane]  = a01;
    red[w][128 + lane] = a10; red[w][192 + lane] = a11;
    red[w][256 + lane] = a20; red[w][320 + lane] = a21;
    red[w][384 + lane] = a30; red[w][448 + lane] = a31;
    if (lane == 0) {
        rsred[w][0] = rs0; rsred[w][1] = rs1; rsred[w][2] = rs2; rsred[w][3] = rs3;
    }
    __syncthreads();
    int t = threadIdx.x;
    float s0 = (red[0][t] + red[1][t]) + (red[2][t] + red[3][t]);
    float s1 = (red[0][256 + t] + red[1][256 + t]) + (red[2][256 + t] + red[3][256 + t]);
    int f0 = t >> 7, f1 = 2 + (t >> 7);
    float rsa = (rsred[0][f0] + rsred[1][f0]) + (rsred[2][f0] + rsred[3][f0]) + EPSF;
    float rsb = (rsred[0][f1] + rsred[1][f1]) + (rsred[2][f1] + rsred[3][f1]) + EPSF;
    float e0 = s0 / rsa; e0 = e0 > 0.f ? e0 : expm1f(e0);
    float e1 = s1 / rsb; e1 = e1 > 0.f ? e1 : expm1f(e1);
    u16 h0 = bf16_rne(e0), l0 = bf16_rne(e0 - bf16_f(h0));
    u16 h1 = bf16_rne(e1), l1 = bf16_rne(e1 - bf16_f(h1));
    u16* ah = ahi + (size_t)n * NF;
    u16* al = alo + (size_t)n * NF;
    ah[t] = h0; ah[256 + t] = h1;
    al[t] = l0; al[256 + t] = l1;
}

// ---------------------------------------------------------------------------
// K5: xo0 = elu_cat @ W_o via 3-term split-bf16 MFMA, gload_lds staging.
// M=NN tile 128, N=64, K=512 BK=32. 4 waves: wm=wave>>1 (64-row half),
// wn=wave&1 (32-col half), acc[4][2].
__global__ __launch_bounds__(256) void node_pass_mfma(
        const u16* __restrict__ ahi, const u16* __restrict__ alo,
        const u16* __restrict__ wohi, const u16* __restrict__ wolo,
        float* __restrict__ xo0) {
    __shared__ u16 Ah[128 * 32], Al[128 * 32], Bh[64 * 32], Bl[64 * 32];
    int m0 = blockIdx.x * 128;
    int tid = threadIdx.x;
    int lane = tid & 63;
    int wave = tid >> 6, wm = wave >> 1, wn = wave & 1;
    f32x4 acc[4][2];
#pragma unroll
    for (int i = 0; i < 4; ++i)
#pragma unroll
        for (int j = 0; j < 2; ++j) acc[i][j] = (f32x4)(0.f);

    u16* sbuf = (wave == 0) ? Ah : (wave == 1) ? Al : (wave == 2) ? Bh : Bl;
    const u16* gbase = (wave == 0) ? ahi : (wave == 1) ? alo
                     : (wave == 2) ? wohi : wolo;
    int nld = (wave < 2) ? 8 : 4;
    int c16s = (lane & 3) ^ ((lane >> 2) & 3) ^ (lane >> 4);
    const u16* gsrc[8];
#pragma unroll
    for (int i = 0; i < 8; ++i) {
        int rowg = ((wave < 2) ? m0 : 0) + 16 * i + (lane >> 2);
        if (wave < 2 && rowg >= NN) rowg = NN - 1;
        gsrc[i] = gbase + (size_t)rowg * NF + c16s * 8;
    }

    const int arow = wm * 64 + (lane & 15);
    const int brow = wn * 32 + (lane & 15);
    const int rc16 = (lane >> 4) ^ ((lane & 3) ^ ((lane >> 2) & 3));
    const int fragoff = rc16 * 8;

    for (int k0 = 0; k0 < NF; k0 += 32) {
        __syncthreads();
        for (int i = 0; i < nld; ++i)
            gload_lds16(gsrc[i] + k0, sbuf + i * 512);
        __syncthreads();
        bf16x8 ah[4], al[4], bh[2], bl[2];
#pragma unroll
        for (int mi = 0; mi < 4; ++mi) {
            ah[mi] = *(const bf16x8*)(Ah + (arow + mi * 16) * 32 + fragoff);
            al[mi] = *(const bf16x8*)(Al + (arow + mi * 16) * 32 + fragoff);
        }
#pragma unroll
        for (int ni = 0; ni < 2; ++ni) {
            bh[ni] = *(const bf16x8*)(Bh + (brow + ni * 16) * 32 + fragoff);
            bl[ni] = *(const bf16x8*)(Bl + (brow + ni * 16) * 32 + fragoff);
        }
#pragma unroll
        for (int mi = 0; mi < 4; ++mi)
#pragma unroll
            for (int ni = 0; ni < 2; ++ni) {
                acc[mi][ni] = __builtin_amdgcn_mfma_f32_16x16x32_bf16(
                    ah[mi], bh[ni], acc[mi][ni], 0, 0, 0);
                acc[mi][ni] = __builtin_amdgcn_mfma_f32_16x16x32_bf16(
                    ah[mi], bl[ni], acc[mi][ni], 0, 0, 0);
                acc[mi][ni] = __builtin_amdgcn_mfma_f32_16x16x32_bf16(
                    al[mi], bh[ni], acc[mi][ni], 0, 0, 0);
            }
    }
#pragma unroll
    for (int mi = 0; mi < 4; ++mi) {
        int mbase = m0 + wm * 64 + mi * 16 + (lane >> 4) * 4;
#pragma unroll
        for (int ni = 0; ni < 2; ++ni) {
            int n = wn * 32 + ni * 16 + (lane & 15);
#pragma unroll
            for (int r2 = 0; r2 < 4; ++r2) {
                int m = mbase + r2;
                if (m < NN) xo0[(size_t)m * NC + n] = acc[mi][ni][r2];
            }
        }
    }
}

// ---------------------------------------------------------------------------
// K5b: s1o/s2o = xo0 . a_out halves (wave per node) + att_loss finalize.
__global__ __launch_bounds__(256) void dots_out(
        const float* __restrict__ xo0, const float* __restrict__ a_out,
        const double* __restrict__ att_acc,
        float* __restrict__ s1o, float* __restrict__ s2o, float* __restrict__ out) {
    if (blockIdx.x == 0 && threadIdx.x == 0)
        out[(size_t)NN * NC] = 1.f - (float)(att_acc[0] / (double)NE);
    int w = threadIdx.x >> 6, lane = threadIdx.x & 63;
    int n = blockIdx.x * 4 + w;
    if (n >= NN) return;
    float v = xo0[(size_t)n * NC + lane];
    float p1 = v * a_out[lane];
    float p2 = v * a_out[64 + lane];
#pragma unroll
    for (int off = 32; off >= 1; off >>= 1) {
        p1 += __shfl_xor(p1, off);
        p2 += __shfl_xor(p2, off);
    }
    if (lane == 0) { s1o[n] = p1; s2o[n] = p2; }
}

// ---------------------------------------------------------------------------
// K6: output attention gather with inline e-values, fused elu + log-softmax.
__global__ __launch_bounds__(256) void node_gather2(
        const int* __restrict__ start, const int4* __restrict__ rec,
        const float* __restrict__ s1o, const float* __restrict__ s2o,
        const float* __restrict__ xo0, float* __restrict__ out) {
    __shared__ float red[4][64];
    __shared__ float rsl[4];
    int n = blockIdx.x;
    int w = threadIdx.x >> 6, lane = threadIdx.x & 63;
    int j0 = start[n], j1 = start[n + 1];
    float s1n = s1o[n];
    float acc = 0.f, rsum = 0.f;
    for (int j = j0 + w; j < j1; j += 4) {
        int d = rec[j].x;
        float sv = s1n + s2o[d];
        float e = expf(-(sv >= 0.f ? sv : LRELU_ALPHA * sv));
        acc = fmaf(e, xo0[(size_t)d * NC + lane], acc);
        rsum += e;
    }
    red[w][lane] = acc;
    if (lane == 0) rsl[w] = rsum;
    __syncthreads();
    if (w == 0) {
        float a = (red[0][lane] + red[1][lane]) + (red[2][lane] + red[3][lane]);
        float r = (rsl[0] + rsl[1]) + (rsl[2] + rsl[3]);
        float t = a / (r + EPSF);
        float v = t > 0.f ? t : expm1f(t);
        float m = v;
#pragma unroll
        for (int off = 32; off >= 1; off >>= 1) m = fmaxf(m, __shfl_xor(m, off));
        float p = expf(v - m);
#pragma unroll
        for (int off = 32; off >= 1; off >>= 1) p += __shfl_xor(p, off);
        out[(size_t)n * NC + lane] = v - m - logf(p);
    }
}

// ---------------------------------------------------------------------------
extern "C" void kernel_launch(void* const* d_in, const int* in_sizes, int n_in,
                              void* d_out, int out_size, void* d_ws, size_t ws_size,
                              hipStream_t stream) {
    const float* x     = (const float*)d_in[0];
    const int*   edge  = (const int*)d_in[1];
    const float* Wks   = (const float*)d_in[2];
    const float* a_k   = (const float*)d_in[3];
    const float* Wo    = (const float*)d_in[4];
    const float* a_att = (const float*)d_in[5];
    const float* a_out = (const float*)d_in[6];
    float* out = (float*)d_out;

    float* wsf = (float*)d_ws;
    float* h      = wsf + OFF_H;
    int4*  rec    = (int4*)(wsf + OFF_REC);
    float* xo0    = wsf + OFF_XO0;
    float* s_src  = wsf + OFF_SSRC;
    float* s_dst  = wsf + OFF_SDST;
    float* s1a    = wsf + OFF_S1A;
    float* s2a    = wsf + OFF_S2A;
    float* s1o    = wsf + OFF_S1O;
    float* s2o    = wsf + OFF_S2O;
    int*   startp = (int*)(wsf + OFF_START);
    int*   cnt    = (int*)(wsf + OFF_CNT);
    int*   cursor = (int*)(wsf + OFF_CURSOR);
    double* att   = (double*)(wsf + OFF_ATT);

    // Region aliases:
    //  OFF_HP region: xhi/xlo (written by split_x, read by gemm) then
    //                 ahi/alo (written by node_gather1, read by node_pass_mfma)
    //  OFF_REC region: wthi/wtlo (split_w -> gemm) then rec (edge_pre1 ->)
    //  OFF_WOT region: wohi/wolo (split_w -> node_pass_mfma)
    u16* xhi  = (u16*)(wsf + OFF_HP);
    u16* xlo  = xhi + (size_t)NN * NF;
    u16* ahi  = xhi;
    u16* alo  = xlo;
    u16* wthi = (u16*)(wsf + OFF_REC);
    u16* wtlo = wthi + (size_t)KF * NH * NF;
    u16* wohi = (u16*)(wsf + OFF_WOT);
    u16* wolo = wohi + (size_t)NC * NF;

    // zero only the accumulation region (cnt, cursor, att) every call
    size_t zero_bytes = (size_t)(WS_FLOATS - OFF_CNT) * sizeof(float);
    hipMemsetAsync((char*)d_ws + (size_t)OFF_CNT * sizeof(float), 0, zero_bytes, stream);

    split_x_count<<<NSPLIT + (NE + 255) / 256, 256, 0, stream>>>(x, xhi, xlo, edge, cnt);
    split_w<<<512 + NC, 256, 0, stream>>>(Wks, Wo, wthi, wtlo, wohi, wolo);
    csr_scan<<<1, 1024, 0, stream>>>(cnt, startp);
    gemm_h_mfma<<<4 * ((NN + 127) / 128), 256, 0, stream>>>(xhi, xlo, wthi, wtlo, h);
    compute_svals_h<<<256, 256, 0, stream>>>(h, a_k, a_att, s_src, s_dst, s1a, s2a);
    edge_pre1<<<(NE + 255) / 256, 256, 0, stream>>>(edge, startp, cursor,
                                                    s_src, s_dst, s1a, s2a, rec, att);
    node_gather1<<<NN, 256, 0, stream>>>(startp, rec, h, ahi, alo);
    node_pass_mfma<<<(NN + 127) / 128, 256, 0, stream>>>(ahi, alo, wohi, wolo, xo0);
    dots_out<<<(NN + 3) / 4, 256, 0, stream>>>(xo0, a_out, att, s1o, s2o, out);
    node_gather2<<<NN, 256, 0, stream>>>(startp, rec, s1o, s2o, xo0, out);
}

// Round 11
// 606.480 us; speedup vs baseline: 1.2560x; 1.0683x over previous
//
#include <hip/hip_runtime.h>
#include <math.h>

#define NN 50000
#define NE 800000
#define NF 512
#define NH 128
#define KF 4
#define NC 64
#define LRELU_ALPHA 0.2f
#define EPSF 1e-16f

typedef unsigned short u16;
typedef __attribute__((ext_vector_type(8))) short bf16x8;
typedef __attribute__((ext_vector_type(4))) float f32x4;

// ---------------- workspace layout (float offsets) ----------------
#define OFF_H      0LL                                  // h (NN,512)
#define OFF_HP     (OFF_H + (long long)NN * NF)         // xhi/xlo (gemm in), then ahi/alo (elu-split planes)
#define OFF_REC    (OFF_HP + (long long)NN * NF)        // rec (NE int4); ALSO Wt split before edge_pre1
#define OFF_XO0    (OFF_REC + 4LL * NE)                 // (NN,64)
#define OFF_SSRC   (OFF_XO0 + (long long)NN * NC)       // (NN,4)
#define OFF_SDST   (OFF_SSRC + (long long)NN * KF)
#define OFF_S1A    (OFF_SDST + (long long)NN * KF)
#define OFF_S2A    (OFF_S1A + (long long)NN * KF)
#define OFF_WOT    (OFF_S2A + (long long)NN * KF)       // wohi/wolo (64x512 u16 each)
#define OFF_S1O    (OFF_WOT + (long long)NN * KF)       // (NN,)
#define OFF_S2O    (OFF_S1O + NN)
#define OFF_START  (OFF_S2O + NN)                       // (NN+1) ints, pad
// ---- zeroed-each-call region starts here ----
#define OFF_CNT    (OFF_START + NN + 4)                 // NN ints
#define OFF_CURSOR (OFF_CNT + NN)                       // NN ints
#define OFF_ATT    (OFF_CURSOR + NN)                    // double (2 floats)
#define WS_FLOATS  (OFF_ATT + 2)

__device__ __forceinline__ u16 bf16_rne(float f) {
    unsigned int u = __float_as_uint(f);
    return (u16)((u + 0x7FFFu + ((u >> 16) & 1u)) >> 16);
}
__device__ __forceinline__ float bf16_f(u16 b) {
    return __uint_as_float(((unsigned int)b) << 16);
}

// async global->LDS 16B: dest = wave-uniform base + lane*16 (HW rule)
__device__ __forceinline__ void gload_lds16(const u16* g, u16* l) {
    __builtin_amdgcn_global_load_lds(
        (const __attribute__((address_space(1))) void*)g,
        (__attribute__((address_space(3))) void*)l, 16, 0, 0);
}

// ---------------------------------------------------------------------------
// K0: fused preprocessing. Blocks [0,NSPLIT): split x into hi/lo bf16;
// [NSPLIT, NSPLIT+NCNT): csr_count; rest: W / Wo transpose+split.
#define NSPLIT 12500                 // NN*NF/8/256
#define NCNT   ((NE + 255) / 256)    // 3125
__global__ __launch_bounds__(256) void split_all(
        const float* __restrict__ x, u16* __restrict__ xhi, u16* __restrict__ xlo,
        const int* __restrict__ edge, int* __restrict__ cnt,
        const float* __restrict__ Wks, const float* __restrict__ Wo,
        u16* __restrict__ wthi, u16* __restrict__ wtlo,
        u16* __restrict__ wohi, u16* __restrict__ wolo) {
    if (blockIdx.x < NSPLIT) {
        size_t i = ((size_t)blockIdx.x * 256 + threadIdx.x) * 8;
        float4 v0 = *(const float4*)(x + i);
        float4 v1 = *(const float4*)(x + i + 4);
        float v[8] = {v0.x, v0.y, v0.z, v0.w, v1.x, v1.y, v1.z, v1.w};
        unsigned int hp[4], lp[4];
#pragma unroll
        for (int j = 0; j < 4; ++j) {
            u16 h0 = bf16_rne(v[2 * j]);
            u16 h1 = bf16_rne(v[2 * j + 1]);
            u16 l0 = bf16_rne(v[2 * j] - bf16_f(h0));
            u16 l1 = bf16_rne(v[2 * j + 1] - bf16_f(h1));
            hp[j] = (unsigned int)h0 | ((unsigned int)h1 << 16);
            lp[j] = (unsigned int)l0 | ((unsigned int)l1 << 16);
        }
        *(uint4*)(xhi + i) = make_uint4(hp[0], hp[1], hp[2], hp[3]);
        *(uint4*)(xlo + i) = make_uint4(lp[0], lp[1], lp[2], lp[3]);
    } else if (blockIdx.x < NSPLIT + NCNT) {
        int e = (blockIdx.x - NSPLIT) * 256 + threadIdx.x;
        if (e < NE) atomicAdd(&cnt[edge[e]], 1);
    } else {
        int b = blockIdx.x - NSPLIT - NCNT;   // 0..575
        if (b < 512) {
            int kf = b >> 7, n = b & 127;
            for (int f = threadIdx.x; f < NF; f += 256) {
                float v = Wks[(size_t)kf * (NF * NH) + (size_t)f * NH + n];
                u16 hb = bf16_rne(v);
                u16 lb = bf16_rne(v - bf16_f(hb));
                wthi[(size_t)b * NF + f] = hb;
                wtlo[(size_t)b * NF + f] = lb;
            }
        } else {
            int n = b - 512;   // 0..63
            for (int f = threadIdx.x; f < NF; f += 256) {
                float v = Wo[(size_t)f * NC + n];
                u16 hb = bf16_rne(v);
                u16 lb = bf16_rne(v - bf16_f(hb));
                wohi[(size_t)n * NF + f] = hb;
                wolo[(size_t)n * NF + f] = lb;
            }
        }
    }
}

// ---------------------------------------------------------------------------
// K1: h = x @ Wcat via 3-term split-bf16 MFMA, gload_lds staging, XCD-chunked
// bijective block swizzle.
__global__ __launch_bounds__(256) void gemm_h_mfma(
        const u16* __restrict__ xhi, const u16* __restrict__ xlo,
        const u16* __restrict__ wthi, const u16* __restrict__ wtlo,
        float* __restrict__ h) {
    __shared__ u16 Ah[128 * 32], Al[128 * 32], Bh[128 * 32], Bl[128 * 32];
    const int nwg = 4 * ((NN + 127) / 128);
    const int q = nwg / 8, r = nwg % 8;
    int o = blockIdx.x;
    int xcd = o & 7, pos = o >> 3;
    int wg = (xcd < r ? xcd * (q + 1) : r * (q + 1) + (xcd - r) * q) + pos;
    int m0 = (wg >> 2) * 128, n0 = (wg & 3) * 128;

    int tid = threadIdx.x;
    int lane = tid & 63;
    int wave = tid >> 6, wm = wave >> 1, wn = wave & 1;
    f32x4 acc[4][4];
#pragma unroll
    for (int i = 0; i < 4; ++i)
#pragma unroll
        for (int j = 0; j < 4; ++j) acc[i][j] = (f32x4)(0.f);

    u16* sbuf = (wave == 0) ? Ah : (wave == 1) ? Al : (wave == 2) ? Bh : Bl;
    const u16* gbase = (wave == 0) ? xhi : (wave == 1) ? xlo
                     : (wave == 2) ? wthi : wtlo;
    int rowbase = (wave < 2) ? m0 : n0;
    int c16s = (lane & 3) ^ ((lane >> 2) & 3) ^ (lane >> 4);
    const u16* gsrc[8];
#pragma unroll
    for (int i = 0; i < 8; ++i) {
        int rowg = rowbase + 16 * i + (lane >> 2);
        if (wave < 2 && rowg >= NN) rowg = NN - 1;
        gsrc[i] = gbase + (size_t)rowg * NF + c16s * 8;
    }

    const int arow = wm * 64 + (lane & 15);
    const int brow = wn * 64 + (lane & 15);
    const int rc16 = (lane >> 4) ^ ((lane & 3) ^ ((lane >> 2) & 3));
    const int fragoff = rc16 * 8;

    for (int k0 = 0; k0 < NF; k0 += 32) {
        __syncthreads();
#pragma unroll
        for (int i = 0; i < 8; ++i)
            gload_lds16(gsrc[i] + k0, sbuf + i * 512);
        __syncthreads();
        bf16x8 ah[4], al[4], bh[4], bl[4];
#pragma unroll
        for (int mi = 0; mi < 4; ++mi) {
            ah[mi] = *(const bf16x8*)(Ah + (arow + mi * 16) * 32 + fragoff);
            al[mi] = *(const bf16x8*)(Al + (arow + mi * 16) * 32 + fragoff);
        }
#pragma unroll
        for (int ni = 0; ni < 4; ++ni) {
            bh[ni] = *(const bf16x8*)(Bh + (brow + ni * 16) * 32 + fragoff);
            bl[ni] = *(const bf16x8*)(Bl + (brow + ni * 16) * 32 + fragoff);
        }
#pragma unroll
        for (int mi = 0; mi < 4; ++mi)
#pragma unroll
            for (int ni = 0; ni < 4; ++ni) {
                acc[mi][ni] = __builtin_amdgcn_mfma_f32_16x16x32_bf16(
                    ah[mi], bh[ni], acc[mi][ni], 0, 0, 0);
                acc[mi][ni] = __builtin_amdgcn_mfma_f32_16x16x32_bf16(
                    ah[mi], bl[ni], acc[mi][ni], 0, 0, 0);
                acc[mi][ni] = __builtin_amdgcn_mfma_f32_16x16x32_bf16(
                    al[mi], bh[ni], acc[mi][ni], 0, 0, 0);
            }
    }
#pragma unroll
    for (int mi = 0; mi < 4; ++mi) {
        int mbase = m0 + wm * 64 + mi * 16 + (lane >> 4) * 4;
#pragma unroll
        for (int ni = 0; ni < 4; ++ni) {
            int n = n0 + wn * 64 + ni * 16 + (lane & 15);
#pragma unroll
            for (int r2 = 0; r2 < 4; ++r2) {
                int m = mbase + r2;
                if (m < NN) h[(size_t)m * NF + n] = acc[mi][ni][r2];
            }
        }
    }
}

// ---------------------------------------------------------------------------
// K2: routing/attention scalars from h. Grid-stride, LDS-staged a_k/a_att.
__global__ __launch_bounds__(256) void compute_svals_h(
        const float* __restrict__ h, const float* __restrict__ a_k,
        const float* __restrict__ a_att,
        float* __restrict__ s_src, float* __restrict__ s_dst,
        float* __restrict__ s1a, float* __restrict__ s2a) {
    __shared__ float Ak[4][1024];
    __shared__ float Aa[4][256];
    for (int i = threadIdx.x; i < 4096; i += 256) Ak[i >> 10][i & 1023] = a_k[i];
    for (int i = threadIdx.x; i < 1024; i += 256) Aa[i >> 8][i & 255] = a_att[i];
    __syncthreads();
    int w = threadIdx.x >> 6, lane = threadIdx.x & 63;
    for (int n = blockIdx.x * 4 + w; n < NN; n += gridDim.x * 4) {
        const float* hr = h + (size_t)n * NF;
        float accS[4] = {0, 0, 0, 0}, accD[4] = {0, 0, 0, 0};
        float accQ1[4] = {0, 0, 0, 0}, accQ2[4] = {0, 0, 0, 0};
#pragma unroll
        for (int i = 0; i < 8; ++i) {
            int f = i * 64 + lane;
            float hv = hr[f];
#pragma unroll
            for (int k = 0; k < 4; ++k) {
                accS[k] = fmaf(hv, Ak[k][f], accS[k]);
                accD[k] = fmaf(hv, Ak[k][512 + f], accD[k]);
            }
            accQ1[i >> 1] = fmaf(hv, Aa[i >> 1][f & 127], accQ1[i >> 1]);
            accQ2[i >> 1] = fmaf(hv, Aa[i >> 1][128 + (f & 127)], accQ2[i >> 1]);
        }
#pragma unroll
        for (int off = 32; off >= 1; off >>= 1) {
#pragma unroll
            for (int k = 0; k < 4; ++k) {
                accS[k] += __shfl_xor(accS[k], off);
                accD[k] += __shfl_xor(accD[k], off);
                accQ1[k] += __shfl_xor(accQ1[k], off);
                accQ2[k] += __shfl_xor(accQ2[k], off);
            }
        }
        if (lane == 0) {
#pragma unroll
            for (int k = 0; k < 4; ++k) {
                s_src[n * 4 + k] = accS[k];
                s_dst[n * 4 + k] = accD[k];
                s1a[n * 4 + k]   = accQ1[k];
                s2a[n * 4 + k]   = accQ2[k];
            }
        }
    }
}

// ---------------------------------------------------------------------------
__global__ __launch_bounds__(1024) void csr_scan(const int* __restrict__ cnt,
                                                 int* __restrict__ start) {
    __shared__ int part[1024];
    int t = threadIdx.x;
    const int CH = (NN + 1023) / 1024;  // 49
    int base = t * CH;
    int s = 0;
    for (int i = 0; i < CH; ++i) {
        int idx = base + i;
        if (idx < NN) s += cnt[idx];
    }
    part[t] = s;
    __syncthreads();
    for (int off = 1; off < 1024; off <<= 1) {
        int v = (t >= off) ? part[t - off] : 0;
        __syncthreads();
        part[t] += v;
        __syncthreads();
    }
    int run = (t == 0) ? 0 : part[t - 1];
    for (int i = 0; i < CH; ++i) {
        int idx = base + i;
        if (idx < NN) { start[idx] = run; run += cnt[idx]; }
    }
    if (t == 1023) start[NN] = run;
}

// ---------------------------------------------------------------------------
// K3: edge-parallel scalar precompute + CSR fill. One thread per edge.
__global__ __launch_bounds__(256) void edge_pre1(
        const int* __restrict__ edge, const int* __restrict__ start,
        int* __restrict__ cursor,
        const float* __restrict__ s_src, const float* __restrict__ s_dst,
        const float* __restrict__ s1a, const float* __restrict__ s2a,
        int4* __restrict__ rec, double* __restrict__ att_acc) {
    __shared__ float blk[4];
    int tid = threadIdx.x;
    int e = blockIdx.x * 256 + tid;
    float t2 = 0.f;
    if (e < NE) {
        int src = edge[e];
        int dst = edge[NE + e];
        float4 ss = *(const float4*)(s_src + (size_t)src * 4);
        float4 sd = *(const float4*)(s_dst + (size_t)dst * 4);
        float l0 = ss.x + sd.x, l1 = ss.y + sd.y, l2 = ss.z + sd.z, l3 = ss.w + sd.w;
        int i1 = 0; float v1 = l0;
        if (l1 > v1) { v1 = l1; i1 = 1; }
        if (l2 > v1) { v1 = l2; i1 = 2; }
        if (l3 > v1) { v1 = l3; i1 = 3; }
        int i2 = 0; float v2 = -3.4e38f;
        if (i1 != 0)            { v2 = l0; i2 = 0; }
        if (i1 != 1 && l1 > v2) { v2 = l1; i2 = 1; }
        if (i1 != 2 && l2 > v2) { v2 = l2; i2 = 2; }
        if (i1 != 3 && l3 > v2) { v2 = l3; i2 = 3; }
        float esum = expf(l0 - v1) + expf(l1 - v1) + expf(l2 - v1) + expf(l3 - v1);
        t2 = (1.f + expf(v2 - v1)) / esum;
        float4 q1 = *(const float4*)(s1a + (size_t)src * 4);
        float4 q2 = *(const float4*)(s2a + (size_t)dst * 4);
        float q1v1 = i1 == 0 ? q1.x : i1 == 1 ? q1.y : i1 == 2 ? q1.z : q1.w;
        float q2v1 = i1 == 0 ? q2.x : i1 == 1 ? q2.y : i1 == 2 ? q2.z : q2.w;
        float q1v2 = i2 == 0 ? q1.x : i2 == 1 ? q1.y : i2 == 2 ? q1.z : q1.w;
        float q2v2 = i2 == 0 ? q2.x : i2 == 1 ? q2.y : i2 == 2 ? q2.z : q2.w;
        float sv1 = q1v1 + q2v1, sv2 = q1v2 + q2v2;
        float ee1 = expf(-(sv1 >= 0.f ? sv1 : LRELU_ALPHA * sv1));
        float ee2 = expf(-(sv2 >= 0.f ? sv2 : LRELU_ALPHA * sv2));
        int p = start[src] + atomicAdd(&cursor[src], 1);
        rec[p] = make_int4(dst, src | (i1 << 16) | (i2 << 18),
                           __float_as_int(ee1), __float_as_int(ee2));
    }
#pragma unroll
    for (int off = 32; off >= 1; off >>= 1) t2 += __shfl_xor(t2, off);
    if ((tid & 63) == 0) blk[tid >> 6] = t2;
    __syncthreads();
    if (tid == 0)
        atomicAdd(att_acc, (double)(blk[0] + blk[1] + blk[2] + blk[3]));
}

// ---------------------------------------------------------------------------
// K4: layer-1 gather, unrolled x2 for memory-level parallelism (accumulation
// sequence identical to the rolled loop -> bit-identical results). Epilogue
// applies elu(hp/rowsum) and writes hi/lo bf16 planes for node_pass_mfma.
#define G1_BODY(RR)                                                             \
    {   int i1 = ((RR).y >> 16) & 3, i2 = ((RR).y >> 18) & 3;                   \
        float w1 = __int_as_float((RR).z), w2 = __int_as_float((RR).w);         \
        const float* hr = h + (size_t)(RR).x * NF + lane;                       \
        float v1a = hr[i1 * 128];                                               \
        float v1b = hr[i1 * 128 + 64];                                          \
        float v2a = hr[i2 * 128];                                               \
        float v2b = hr[i2 * 128 + 64];                                          \
        switch (i1) {                                                           \
            case 0: a00 = fmaf(w1, v1a, a00); a01 = fmaf(w1, v1b, a01); rs0 += w1; break; \
            case 1: a10 = fmaf(w1, v1a, a10); a11 = fmaf(w1, v1b, a11); rs1 += w1; break; \
            case 2: a20 = fmaf(w1, v1a, a20); a21 = fmaf(w1, v1b, a21); rs2 += w1; break; \
            default:a30 = fmaf(w1, v1a, a30); a31 = fmaf(w1, v1b, a31); rs3 += w1; break; \
        }                                                                       \
        switch (i2) {                                                           \
            case 0: a00 = fmaf(w2, v2a, a00); a01 = fmaf(w2, v2b, a01); rs0 += w2; break; \
            case 1: a10 = fmaf(w2, v2a, a10); a11 = fmaf(w2, v2b, a11); rs1 += w2; break; \
            case 2: a20 = fmaf(w2, v2a, a20); a21 = fmaf(w2, v2b, a21); rs2 += w2; break; \
            default:a30 = fmaf(w2, v2a, a30); a31 = fmaf(w2, v2b, a31); rs3 += w2; break; \
        }                                                                       \
    }

__global__ __launch_bounds__(256) void node_gather1(
        const int* __restrict__ start, const int4* __restrict__ rec,
        const float* __restrict__ h,
        u16* __restrict__ ahi, u16* __restrict__ alo) {
    __shared__ float red[4][512];
    __shared__ float rsred[4][4];
    int n = blockIdx.x;
    int w = threadIdx.x >> 6, lane = threadIdx.x & 63;
    int j0 = start[n], j1 = start[n + 1];
    float a00 = 0.f, a01 = 0.f, a10 = 0.f, a11 = 0.f;
    float a20 = 0.f, a21 = 0.f, a30 = 0.f, a31 = 0.f;
    float rs0 = 0.f, rs1 = 0.f, rs2 = 0.f, rs3 = 0.f;
    int j = j0 + w;
    for (; j + 4 < j1; j += 8) {        // two records; loads overlap
        int4 ra = rec[j];
        int4 rb = rec[j + 4];
        G1_BODY(ra)
        G1_BODY(rb)
    }
    if (j < j1) {
        int4 ra = rec[j];
        G1_BODY(ra)
    }
    red[w][lane]       = a00; red[w][64 + lane]  = a01;
    red[w][128 + lane] = a10; red[w][192 + lane] = a11;
    red[w][256 + lane] = a20; red[w][320 + lane] = a21;
    red[w][384 + lane] = a30; red[w][448 + lane] = a31;
    if (lane == 0) {
        rsred[w][0] = rs0; rsred[w][1] = rs1; rsred[w][2] = rs2; rsred[w][3] = rs3;
    }
    __syncthreads();
    int t = threadIdx.x;
    float s0 = (red[0][t] + red[1][t]) + (red[2][t] + red[3][t]);
    float s1 = (red[0][256 + t] + red[1][256 + t]) + (red[2][256 + t] + red[3][256 + t]);
    int f0 = t >> 7, f1 = 2 + (t >> 7);
    float rsa = (rsred[0][f0] + rsred[1][f0]) + (rsred[2][f0] + rsred[3][f0]) + EPSF;
    float rsb = (rsred[0][f1] + rsred[1][f1]) + (rsred[2][f1] + rsred[3][f1]) + EPSF;
    float e0 = s0 / rsa; e0 = e0 > 0.f ? e0 : expm1f(e0);
    float e1 = s1 / rsb; e1 = e1 > 0.f ? e1 : expm1f(e1);
    u16 h0 = bf16_rne(e0), l0 = bf16_rne(e0 - bf16_f(h0));
    u16 h1 = bf16_rne(e1), l1 = bf16_rne(e1 - bf16_f(h1));
    u16* ah = ahi + (size_t)n * NF;
    u16* al = alo + (size_t)n * NF;
    ah[t] = h0; ah[256 + t] = h1;
    al[t] = l0; al[256 + t] = l1;
}

// ---------------------------------------------------------------------------
// K5: xo0 = elu_cat @ W_o via 3-term split-bf16 MFMA + FUSED s1o/s2o dots
// (each block holds the full 64-col rows in acc; 16-lane shfl tree + 2KB LDS
// cross-wave combine -> no xo0 re-read).
__global__ __launch_bounds__(256) void node_pass_mfma(
        const u16* __restrict__ ahi, const u16* __restrict__ alo,
        const u16* __restrict__ wohi, const u16* __restrict__ wolo,
        const float* __restrict__ a_out,
        float* __restrict__ xo0, float* __restrict__ s1o, float* __restrict__ s2o) {
    __shared__ u16 Ah[128 * 32], Al[128 * 32], Bh[64 * 32], Bl[64 * 32];
    __shared__ float part1[2][64][2];
    __shared__ float part2[2][64][2];
    int m0 = blockIdx.x * 128;
    int tid = threadIdx.x;
    int lane = tid & 63;
    int wave = tid >> 6, wm = wave >> 1, wn = wave & 1;
    f32x4 acc[4][2];
#pragma unroll
    for (int i = 0; i < 4; ++i)
#pragma unroll
        for (int j = 0; j < 2; ++j) acc[i][j] = (f32x4)(0.f);

    u16* sbuf = (wave == 0) ? Ah : (wave == 1) ? Al : (wave == 2) ? Bh : Bl;
    const u16* gbase = (wave == 0) ? ahi : (wave == 1) ? alo
                     : (wave == 2) ? wohi : wolo;
    int nld = (wave < 2) ? 8 : 4;
    int c16s = (lane & 3) ^ ((lane >> 2) & 3) ^ (lane >> 4);
    const u16* gsrc[8];
#pragma unroll
    for (int i = 0; i < 8; ++i) {
        int rowg = ((wave < 2) ? m0 : 0) + 16 * i + (lane >> 2);
        if (wave < 2 && rowg >= NN) rowg = NN - 1;
        gsrc[i] = gbase + (size_t)rowg * NF + c16s * 8;
    }

    const int arow = wm * 64 + (lane & 15);
    const int brow = wn * 32 + (lane & 15);
    const int rc16 = (lane >> 4) ^ ((lane & 3) ^ ((lane >> 2) & 3));
    const int fragoff = rc16 * 8;

    for (int k0 = 0; k0 < NF; k0 += 32) {
        __syncthreads();
        for (int i = 0; i < nld; ++i)
            gload_lds16(gsrc[i] + k0, sbuf + i * 512);
        __syncthreads();
        bf16x8 ah[4], al[4], bh[2], bl[2];
#pragma unroll
        for (int mi = 0; mi < 4; ++mi) {
            ah[mi] = *(const bf16x8*)(Ah + (arow + mi * 16) * 32 + fragoff);
            al[mi] = *(const bf16x8*)(Al + (arow + mi * 16) * 32 + fragoff);
        }
#pragma unroll
        for (int ni = 0; ni < 2; ++ni) {
            bh[ni] = *(const bf16x8*)(Bh + (brow + ni * 16) * 32 + fragoff);
            bl[ni] = *(const bf16x8*)(Bl + (brow + ni * 16) * 32 + fragoff);
        }
#pragma unroll
        for (int mi = 0; mi < 4; ++mi)
#pragma unroll
            for (int ni = 0; ni < 2; ++ni) {
                acc[mi][ni] = __builtin_amdgcn_mfma_f32_16x16x32_bf16(
                    ah[mi], bh[ni], acc[mi][ni], 0, 0, 0);
                acc[mi][ni] = __builtin_amdgcn_mfma_f32_16x16x32_bf16(
                    ah[mi], bl[ni], acc[mi][ni], 0, 0, 0);
                acc[mi][ni] = __builtin_amdgcn_mfma_f32_16x16x32_bf16(
                    al[mi], bh[ni], acc[mi][ni], 0, 0, 0);
            }
    }
    // xo0 store
#pragma unroll
    for (int mi = 0; mi < 4; ++mi) {
        int mbase = m0 + wm * 64 + mi * 16 + (lane >> 4) * 4;
#pragma unroll
        for (int ni = 0; ni < 2; ++ni) {
            int n = wn * 32 + ni * 16 + (lane & 15);
#pragma unroll
            for (int r2 = 0; r2 < 4; ++r2) {
                int m = mbase + r2;
                if (m < NN) xo0[(size_t)m * NC + n] = acc[mi][ni][r2];
            }
        }
    }
    // fused dots: per lane 2 cols; reduce over the 16 (lane&15) lanes
    float ao1[2], ao2[2];
#pragma unroll
    for (int ni = 0; ni < 2; ++ni) {
        int c = wn * 32 + ni * 16 + (lane & 15);
        ao1[ni] = a_out[c];
        ao2[ni] = a_out[64 + c];
    }
#pragma unroll
    for (int mi = 0; mi < 4; ++mi)
#pragma unroll
        for (int r2 = 0; r2 < 4; ++r2) {
            float p1 = acc[mi][0][r2] * ao1[0] + acc[mi][1][r2] * ao1[1];
            float p2 = acc[mi][0][r2] * ao2[0] + acc[mi][1][r2] * ao2[1];
#pragma unroll
            for (int off = 8; off >= 1; off >>= 1) {
                p1 += __shfl_xor(p1, off);
                p2 += __shfl_xor(p2, off);
            }
            if ((lane & 15) == 0) {
                int rl = mi * 16 + (lane >> 4) * 4 + r2;
                part1[wm][rl][wn] = p1;
                part2[wm][rl][wn] = p2;
            }
        }
    __syncthreads();
    if (tid < 128) {
        int m = m0 + tid;
        if (m < NN) {
            s1o[m] = part1[tid >> 6][tid & 63][0] + part1[tid >> 6][tid & 63][1];
            s2o[m] = part2[tid >> 6][tid & 63][0] + part2[tid >> 6][tid & 63][1];
        }
    }
}

// ---------------------------------------------------------------------------
// K6: output attention gather with inline e-values, unrolled x2, fused
// elu + log-softmax; block 0 finalizes att_loss.
__global__ __launch_bounds__(256) void node_gather2(
        const int* __restrict__ start, const int4* __restrict__ rec,
        const float* __restrict__ s1o, const float* __restrict__ s2o,
        const float* __restrict__ xo0, const double* __restrict__ att_acc,
        float* __restrict__ out) {
    __shared__ float red[4][64];
    __shared__ float rsl[4];
    if (blockIdx.x == 0 && threadIdx.x == 0)
        out[(size_t)NN * NC] = 1.f - (float)(att_acc[0] / (double)NE);
    int n = blockIdx.x;
    int w = threadIdx.x >> 6, lane = threadIdx.x & 63;
    int j0 = start[n], j1 = start[n + 1];
    float s1n = s1o[n];
    float acc = 0.f, rsum = 0.f;
    int j = j0 + w;
    for (; j + 4 < j1; j += 8) {
        int da = rec[j].x;
        int db = rec[j + 4].x;
        float sva = s1n + s2o[da];
        float svb = s1n + s2o[db];
        float ea = expf(-(sva >= 0.f ? sva : LRELU_ALPHA * sva));
        float eb = expf(-(svb >= 0.f ? svb : LRELU_ALPHA * svb));
        float xa = xo0[(size_t)da * NC + lane];
        float xb = xo0[(size_t)db * NC + lane];
        acc = fmaf(ea, xa, acc);
        rsum += ea;
        acc = fmaf(eb, xb, acc);
        rsum += eb;
    }
    if (j < j1) {
        int d = rec[j].x;
        float sv = s1n + s2o[d];
        float e = expf(-(sv >= 0.f ? sv : LRELU_ALPHA * sv));
        acc = fmaf(e, xo0[(size_t)d * NC + lane], acc);
        rsum += e;
    }
    red[w][lane] = acc;
    if (lane == 0) rsl[w] = rsum;
    __syncthreads();
    if (w == 0) {
        float a = (red[0][lane] + red[1][lane]) + (red[2][lane] + red[3][lane]);
        float r = (rsl[0] + rsl[1]) + (rsl[2] + rsl[3]);
        float t = a / (r + EPSF);
        float v = t > 0.f ? t : expm1f(t);
        float m = v;
#pragma unroll
        for (int off = 32; off >= 1; off >>= 1) m = fmaxf(m, __shfl_xor(m, off));
        float p = expf(v - m);
#pragma unroll
        for (int off = 32; off >= 1; off >>= 1) p += __shfl_xor(p, off);
        out[(size_t)n * NC + lane] = v - m - logf(p);
    }
}

// ---------------------------------------------------------------------------
extern "C" void kernel_launch(void* const* d_in, const int* in_sizes, int n_in,
                              void* d_out, int out_size, void* d_ws, size_t ws_size,
                              hipStream_t stream) {
    const float* x     = (const float*)d_in[0];
    const int*   edge  = (const int*)d_in[1];
    const float* Wks   = (const float*)d_in[2];
    const float* a_k   = (const float*)d_in[3];
    const float* Wo    = (const float*)d_in[4];
    const float* a_att = (const float*)d_in[5];
    const float* a_out = (const float*)d_in[6];
    float* out = (float*)d_out;

    float* wsf = (float*)d_ws;
    float* h      = wsf + OFF_H;
    int4*  rec    = (int4*)(wsf + OFF_REC);
    float* xo0    = wsf + OFF_XO0;
    float* s_src  = wsf + OFF_SSRC;
    float* s_dst  = wsf + OFF_SDST;
    float* s1a    = wsf + OFF_S1A;
    float* s2a    = wsf + OFF_S2A;
    float* s1o    = wsf + OFF_S1O;
    float* s2o    = wsf + OFF_S2O;
    int*   startp = (int*)(wsf + OFF_START);
    int*   cnt    = (int*)(wsf + OFF_CNT);
    int*   cursor = (int*)(wsf + OFF_CURSOR);
    double* att   = (double*)(wsf + OFF_ATT);

    u16* xhi  = (u16*)(wsf + OFF_HP);
    u16* xlo  = xhi + (size_t)NN * NF;
    u16* ahi  = xhi;
    u16* alo  = xlo;
    u16* wthi = (u16*)(wsf + OFF_REC);
    u16* wtlo = wthi + (size_t)KF * NH * NF;
    u16* wohi = (u16*)(wsf + OFF_WOT);
    u16* wolo = wohi + (size_t)NC * NF;

    size_t zero_bytes = (size_t)(WS_FLOATS - OFF_CNT) * sizeof(float);
    hipMemsetAsync((char*)d_ws + (size_t)OFF_CNT * sizeof(float), 0, zero_bytes, stream);

    split_all<<<NSPLIT + NCNT + 576, 256, 0, stream>>>(
        x, xhi, xlo, edge, cnt, Wks, Wo, wthi, wtlo, wohi, wolo);
    csr_scan<<<1, 1024, 0, stream>>>(cnt, startp);
    gemm_h_mfma<<<4 * ((NN + 127) / 128), 256, 0, stream>>>(xhi, xlo, wthi, wtlo, h);
    compute_svals_h<<<256, 256, 0, stream>>>(h, a_k, a_att, s_src, s_dst, s1a, s2a);
    edge_pre1<<<(NE + 255) / 256, 256, 0, stream>>>(edge, startp, cursor,
                                                    s_src, s_dst, s1a, s2a, rec, att);
    node_gather1<<<NN, 256, 0, stream>>>(startp, rec, h, ahi, alo);
    node_pass_mfma<<<(NN + 127) / 128, 256, 0, stream>>>(ahi, alo, wohi, wolo,
                                                         a_out, xo0, s1o, s2o);
    node_gather2<<<NN, 256, 0, stream>>>(startp, rec, s1o, s2o, xo0, att, out);
}

// Round 12
// 601.084 us; speedup vs baseline: 1.2673x; 1.0090x over previous
//
#include <hip/hip_runtime.h>
#include <math.h>

#define NN 50000
#define NE 800000
#define NF 512
#define NH 128
#define KF 4
#define NC 64
#define LRELU_ALPHA 0.2f
#define EPSF 1e-16f

typedef unsigned short u16;
typedef __attribute__((ext_vector_type(8))) short bf16x8;
typedef __attribute__((ext_vector_type(4))) float f32x4;

// ---------------- workspace layout (float offsets) ----------------
#define OFF_H      0LL                                  // h (NN,512)
#define OFF_HP     (OFF_H + (long long)NN * NF)         // xhi/xlo (gemm in), then ahi/alo (elu-split planes)
#define OFF_REC    (OFF_HP + (long long)NN * NF)        // rec (NE int4); ALSO Wt split before edge_pre1
#define OFF_XO0    (OFF_REC + 4LL * NE)                 // (NN,64)
#define OFF_SV1    (OFF_XO0 + (long long)NN * NC)       // (NN,8): s_src[4] | s1a[4]
#define OFF_SV2    (OFF_SV1 + (long long)NN * 8)        // (NN,8): s_dst[4] | s2a[4]
#define OFF_WOT    (OFF_SV2 + (long long)NN * 8)        // wohi/wolo (64x512 u16 each)
#define OFF_S1O    (OFF_WOT + (long long)NN * KF)       // (NN,)
#define OFF_S2O    (OFF_S1O + NN)
#define OFF_START  (OFF_S2O + NN)                       // (NN+1) ints, pad
// ---- zeroed-each-call region starts here ----
#define OFF_CNT    (OFF_START + NN + 4)                 // NN ints
#define OFF_CURSOR (OFF_CNT + NN)                       // NN ints
#define OFF_ATT    (OFF_CURSOR + NN)                    // double (2 floats)
#define WS_FLOATS  (OFF_ATT + 2)

__device__ __forceinline__ u16 bf16_rne(float f) {
    unsigned int u = __float_as_uint(f);
    return (u16)((u + 0x7FFFu + ((u >> 16) & 1u)) >> 16);
}
__device__ __forceinline__ float bf16_f(u16 b) {
    return __uint_as_float(((unsigned int)b) << 16);
}

// async global->LDS 16B: dest = wave-uniform base + lane*16 (HW rule)
__device__ __forceinline__ void gload_lds16(const u16* g, u16* l) {
    __builtin_amdgcn_global_load_lds(
        (const __attribute__((address_space(1))) void*)g,
        (__attribute__((address_space(3))) void*)l, 16, 0, 0);
}

// ---------------------------------------------------------------------------
// K0: fused preprocessing. Blocks [0,NSPLIT): split x into hi/lo bf16;
// [NSPLIT, NSPLIT+NCNT): csr_count; rest: W / Wo transpose+split.
#define NSPLIT 12500                 // NN*NF/8/256
#define NCNT   ((NE + 255) / 256)    // 3125
__global__ __launch_bounds__(256) void split_all(
        const float* __restrict__ x, u16* __restrict__ xhi, u16* __restrict__ xlo,
        const int* __restrict__ edge, int* __restrict__ cnt,
        const float* __restrict__ Wks, const float* __restrict__ Wo,
        u16* __restrict__ wthi, u16* __restrict__ wtlo,
        u16* __restrict__ wohi, u16* __restrict__ wolo) {
    if (blockIdx.x < NSPLIT) {
        size_t i = ((size_t)blockIdx.x * 256 + threadIdx.x) * 8;
        float4 v0 = *(const float4*)(x + i);
        float4 v1 = *(const float4*)(x + i + 4);
        float v[8] = {v0.x, v0.y, v0.z, v0.w, v1.x, v1.y, v1.z, v1.w};
        unsigned int hp[4], lp[4];
#pragma unroll
        for (int j = 0; j < 4; ++j) {
            u16 h0 = bf16_rne(v[2 * j]);
            u16 h1 = bf16_rne(v[2 * j + 1]);
            u16 l0 = bf16_rne(v[2 * j] - bf16_f(h0));
            u16 l1 = bf16_rne(v[2 * j + 1] - bf16_f(h1));
            hp[j] = (unsigned int)h0 | ((unsigned int)h1 << 16);
            lp[j] = (unsigned int)l0 | ((unsigned int)l1 << 16);
        }
        *(uint4*)(xhi + i) = make_uint4(hp[0], hp[1], hp[2], hp[3]);
        *(uint4*)(xlo + i) = make_uint4(lp[0], lp[1], lp[2], lp[3]);
    } else if (blockIdx.x < NSPLIT + NCNT) {
        int e = (blockIdx.x - NSPLIT) * 256 + threadIdx.x;
        if (e < NE) atomicAdd(&cnt[edge[e]], 1);
    } else {
        int b = blockIdx.x - NSPLIT - NCNT;   // 0..575
        if (b < 512) {
            int kf = b >> 7, n = b & 127;
            for (int f = threadIdx.x; f < NF; f += 256) {
                float v = Wks[(size_t)kf * (NF * NH) + (size_t)f * NH + n];
                u16 hb = bf16_rne(v);
                u16 lb = bf16_rne(v - bf16_f(hb));
                wthi[(size_t)b * NF + f] = hb;
                wtlo[(size_t)b * NF + f] = lb;
            }
        } else {
            int n = b - 512;   // 0..63
            for (int f = threadIdx.x; f < NF; f += 256) {
                float v = Wo[(size_t)f * NC + n];
                u16 hb = bf16_rne(v);
                u16 lb = bf16_rne(v - bf16_f(hb));
                wohi[(size_t)n * NF + f] = hb;
                wolo[(size_t)n * NF + f] = lb;
            }
        }
    }
}

// ---------------------------------------------------------------------------
// K1: h = x @ Wcat via 3-term split-bf16 MFMA, gload_lds staging, XCD-chunked
// bijective block swizzle.
__global__ __launch_bounds__(256) void gemm_h_mfma(
        const u16* __restrict__ xhi, const u16* __restrict__ xlo,
        const u16* __restrict__ wthi, const u16* __restrict__ wtlo,
        float* __restrict__ h) {
    __shared__ u16 Ah[128 * 32], Al[128 * 32], Bh[128 * 32], Bl[128 * 32];
    const int nwg = 4 * ((NN + 127) / 128);
    const int q = nwg / 8, r = nwg % 8;
    int o = blockIdx.x;
    int xcd = o & 7, pos = o >> 3;
    int wg = (xcd < r ? xcd * (q + 1) : r * (q + 1) + (xcd - r) * q) + pos;
    int m0 = (wg >> 2) * 128, n0 = (wg & 3) * 128;

    int tid = threadIdx.x;
    int lane = tid & 63;
    int wave = tid >> 6, wm = wave >> 1, wn = wave & 1;
    f32x4 acc[4][4];
#pragma unroll
    for (int i = 0; i < 4; ++i)
#pragma unroll
        for (int j = 0; j < 4; ++j) acc[i][j] = (f32x4)(0.f);

    u16* sbuf = (wave == 0) ? Ah : (wave == 1) ? Al : (wave == 2) ? Bh : Bl;
    const u16* gbase = (wave == 0) ? xhi : (wave == 1) ? xlo
                     : (wave == 2) ? wthi : wtlo;
    int rowbase = (wave < 2) ? m0 : n0;
    int c16s = (lane & 3) ^ ((lane >> 2) & 3) ^ (lane >> 4);
    const u16* gsrc[8];
#pragma unroll
    for (int i = 0; i < 8; ++i) {
        int rowg = rowbase + 16 * i + (lane >> 2);
        if (wave < 2 && rowg >= NN) rowg = NN - 1;
        gsrc[i] = gbase + (size_t)rowg * NF + c16s * 8;
    }

    const int arow = wm * 64 + (lane & 15);
    const int brow = wn * 64 + (lane & 15);
    const int rc16 = (lane >> 4) ^ ((lane & 3) ^ ((lane >> 2) & 3));
    const int fragoff = rc16 * 8;

    for (int k0 = 0; k0 < NF; k0 += 32) {
        __syncthreads();
#pragma unroll
        for (int i = 0; i < 8; ++i)
            gload_lds16(gsrc[i] + k0, sbuf + i * 512);
        __syncthreads();
        bf16x8 ah[4], al[4], bh[4], bl[4];
#pragma unroll
        for (int mi = 0; mi < 4; ++mi) {
            ah[mi] = *(const bf16x8*)(Ah + (arow + mi * 16) * 32 + fragoff);
            al[mi] = *(const bf16x8*)(Al + (arow + mi * 16) * 32 + fragoff);
        }
#pragma unroll
        for (int ni = 0; ni < 4; ++ni) {
            bh[ni] = *(const bf16x8*)(Bh + (brow + ni * 16) * 32 + fragoff);
            bl[ni] = *(const bf16x8*)(Bl + (brow + ni * 16) * 32 + fragoff);
        }
#pragma unroll
        for (int mi = 0; mi < 4; ++mi)
#pragma unroll
            for (int ni = 0; ni < 4; ++ni) {
                acc[mi][ni] = __builtin_amdgcn_mfma_f32_16x16x32_bf16(
                    ah[mi], bh[ni], acc[mi][ni], 0, 0, 0);
                acc[mi][ni] = __builtin_amdgcn_mfma_f32_16x16x32_bf16(
                    ah[mi], bl[ni], acc[mi][ni], 0, 0, 0);
                acc[mi][ni] = __builtin_amdgcn_mfma_f32_16x16x32_bf16(
                    al[mi], bh[ni], acc[mi][ni], 0, 0, 0);
            }
    }
#pragma unroll
    for (int mi = 0; mi < 4; ++mi) {
        int mbase = m0 + wm * 64 + mi * 16 + (lane >> 4) * 4;
#pragma unroll
        for (int ni = 0; ni < 4; ++ni) {
            int n = n0 + wn * 64 + ni * 16 + (lane & 15);
#pragma unroll
            for (int r2 = 0; r2 < 4; ++r2) {
                int m = mbase + r2;
                if (m < NN) h[(size_t)m * NF + n] = acc[mi][ni][r2];
            }
        }
    }
}

// ---------------------------------------------------------------------------
// K2: routing/attention scalars from h, written PACKED per node:
// sv1[n] = {s_src[0..3], s1a[0..3]}, sv2[n] = {s_dst[0..3], s2a[0..3]}.
__global__ __launch_bounds__(256) void compute_svals_h(
        const float* __restrict__ h, const float* __restrict__ a_k,
        const float* __restrict__ a_att,
        float* __restrict__ sv1, float* __restrict__ sv2) {
    __shared__ float Ak[4][1024];
    __shared__ float Aa[4][256];
    for (int i = threadIdx.x; i < 4096; i += 256) Ak[i >> 10][i & 1023] = a_k[i];
    for (int i = threadIdx.x; i < 1024; i += 256) Aa[i >> 8][i & 255] = a_att[i];
    __syncthreads();
    int w = threadIdx.x >> 6, lane = threadIdx.x & 63;
    for (int n = blockIdx.x * 4 + w; n < NN; n += gridDim.x * 4) {
        const float* hr = h + (size_t)n * NF;
        float accS[4] = {0, 0, 0, 0}, accD[4] = {0, 0, 0, 0};
        float accQ1[4] = {0, 0, 0, 0}, accQ2[4] = {0, 0, 0, 0};
#pragma unroll
        for (int i = 0; i < 8; ++i) {
            int f = i * 64 + lane;
            float hv = hr[f];
#pragma unroll
            for (int k = 0; k < 4; ++k) {
                accS[k] = fmaf(hv, Ak[k][f], accS[k]);
                accD[k] = fmaf(hv, Ak[k][512 + f], accD[k]);
            }
            accQ1[i >> 1] = fmaf(hv, Aa[i >> 1][f & 127], accQ1[i >> 1]);
            accQ2[i >> 1] = fmaf(hv, Aa[i >> 1][128 + (f & 127)], accQ2[i >> 1]);
        }
#pragma unroll
        for (int off = 32; off >= 1; off >>= 1) {
#pragma unroll
            for (int k = 0; k < 4; ++k) {
                accS[k] += __shfl_xor(accS[k], off);
                accD[k] += __shfl_xor(accD[k], off);
                accQ1[k] += __shfl_xor(accQ1[k], off);
                accQ2[k] += __shfl_xor(accQ2[k], off);
            }
        }
        if (lane == 0) {
#pragma unroll
            for (int k = 0; k < 4; ++k) {
                sv1[(size_t)n * 8 + k]     = accS[k];
                sv1[(size_t)n * 8 + 4 + k] = accQ1[k];
                sv2[(size_t)n * 8 + k]     = accD[k];
                sv2[(size_t)n * 8 + 4 + k] = accQ2[k];
            }
        }
    }
}

// ---------------------------------------------------------------------------
__global__ __launch_bounds__(1024) void csr_scan(const int* __restrict__ cnt,
                                                 int* __restrict__ start) {
    __shared__ int part[1024];
    int t = threadIdx.x;
    const int CH = (NN + 1023) / 1024;  // 49
    int base = t * CH;
    int s = 0;
    for (int i = 0; i < CH; ++i) {
        int idx = base + i;
        if (idx < NN) s += cnt[idx];
    }
    part[t] = s;
    __syncthreads();
    for (int off = 1; off < 1024; off <<= 1) {
        int v = (t >= off) ? part[t - off] : 0;
        __syncthreads();
        part[t] += v;
        __syncthreads();
    }
    int run = (t == 0) ? 0 : part[t - 1];
    for (int i = 0; i < CH; ++i) {
        int idx = base + i;
        if (idx < NN) { start[idx] = run; run += cnt[idx]; }
    }
    if (t == 1023) start[NN] = run;
}

// ---------------------------------------------------------------------------
// K3: edge-parallel scalar precompute + CSR fill. One thread per edge.
// Packed sval reads: 2 adjacent float4 pairs per endpoint.
__global__ __launch_bounds__(256) void edge_pre1(
        const int* __restrict__ edge, const int* __restrict__ start,
        int* __restrict__ cursor,
        const float* __restrict__ sv1, const float* __restrict__ sv2,
        int4* __restrict__ rec, double* __restrict__ att_acc) {
    __shared__ float blk[4];
    int tid = threadIdx.x;
    int e = blockIdx.x * 256 + tid;
    float t2 = 0.f;
    if (e < NE) {
        int src = edge[e];
        int dst = edge[NE + e];
        const float* p1 = sv1 + (size_t)src * 8;
        const float* p2 = sv2 + (size_t)dst * 8;
        float4 ss = *(const float4*)(p1);
        float4 q1 = *(const float4*)(p1 + 4);
        float4 sd = *(const float4*)(p2);
        float4 q2 = *(const float4*)(p2 + 4);
        float l0 = ss.x + sd.x, l1 = ss.y + sd.y, l2 = ss.z + sd.z, l3 = ss.w + sd.w;
        int i1 = 0; float v1 = l0;
        if (l1 > v1) { v1 = l1; i1 = 1; }
        if (l2 > v1) { v1 = l2; i1 = 2; }
        if (l3 > v1) { v1 = l3; i1 = 3; }
        int i2 = 0; float v2 = -3.4e38f;
        if (i1 != 0)            { v2 = l0; i2 = 0; }
        if (i1 != 1 && l1 > v2) { v2 = l1; i2 = 1; }
        if (i1 != 2 && l2 > v2) { v2 = l2; i2 = 2; }
        if (i1 != 3 && l3 > v2) { v2 = l3; i2 = 3; }
        float esum = expf(l0 - v1) + expf(l1 - v1) + expf(l2 - v1) + expf(l3 - v1);
        t2 = (1.f + expf(v2 - v1)) / esum;
        float q1v1 = i1 == 0 ? q1.x : i1 == 1 ? q1.y : i1 == 2 ? q1.z : q1.w;
        float q2v1 = i1 == 0 ? q2.x : i1 == 1 ? q2.y : i1 == 2 ? q2.z : q2.w;
        float q1v2 = i2 == 0 ? q1.x : i2 == 1 ? q1.y : i2 == 2 ? q1.z : q1.w;
        float q2v2 = i2 == 0 ? q2.x : i2 == 1 ? q2.y : i2 == 2 ? q2.z : q2.w;
        float sv1v = q1v1 + q2v1, sv2v = q1v2 + q2v2;
        float ee1 = expf(-(sv1v >= 0.f ? sv1v : LRELU_ALPHA * sv1v));
        float ee2 = expf(-(sv2v >= 0.f ? sv2v : LRELU_ALPHA * sv2v));
        int p = start[src] + atomicAdd(&cursor[src], 1);
        rec[p] = make_int4(dst, src | (i1 << 16) | (i2 << 18),
                           __float_as_int(ee1), __float_as_int(ee2));
    }
#pragma unroll
    for (int off = 32; off >= 1; off >>= 1) t2 += __shfl_xor(t2, off);
    if ((tid & 63) == 0) blk[tid >> 6] = t2;
    __syncthreads();
    if (tid == 0)
        atomicAdd(att_acc, (double)(blk[0] + blk[1] + blk[2] + blk[3]));
}

// ---------------------------------------------------------------------------
// K4: layer-1 gather, unrolled x2, SCALARIZED: rec fields are wave-uniform ->
// readfirstlane puts them in SGPRs, so the factor switches become scalar
// branches (1 case executed, not 4 masked) and gather addresses are
// SGPR-base + lane. Arithmetic identical -> bit-identical results.
#define G1_BODY(RR)                                                             \
    {   int i1 = __builtin_amdgcn_readfirstlane(((RR).y >> 16) & 3);            \
        int i2 = __builtin_amdgcn_readfirstlane(((RR).y >> 18) & 3);            \
        int dd = __builtin_amdgcn_readfirstlane((RR).x);                        \
        float w1 = __uint_as_float(__builtin_amdgcn_readfirstlane((RR).z));     \
        float w2 = __uint_as_float(__builtin_amdgcn_readfirstlane((RR).w));     \
        const float* hr = h + (size_t)dd * NF + lane;                           \
        float v1a = hr[i1 * 128];                                               \
        float v1b = hr[i1 * 128 + 64];                                          \
        float v2a = hr[i2 * 128];                                               \
        float v2b = hr[i2 * 128 + 64];                                          \
        switch (i1) {                                                           \
            case 0: a00 = fmaf(w1, v1a, a00); a01 = fmaf(w1, v1b, a01); rs0 += w1; break; \
            case 1: a10 = fmaf(w1, v1a, a10); a11 = fmaf(w1, v1b, a11); rs1 += w1; break; \
            case 2: a20 = fmaf(w1, v1a, a20); a21 = fmaf(w1, v1b, a21); rs2 += w1; break; \
            default:a30 = fmaf(w1, v1a, a30); a31 = fmaf(w1, v1b, a31); rs3 += w1; break; \
        }                                                                       \
        switch (i2) {                                                           \
            case 0: a00 = fmaf(w2, v2a, a00); a01 = fmaf(w2, v2b, a01); rs0 += w2; break; \
            case 1: a10 = fmaf(w2, v2a, a10); a11 = fmaf(w2, v2b, a11); rs1 += w2; break; \
            case 2: a20 = fmaf(w2, v2a, a20); a21 = fmaf(w2, v2b, a21); rs2 += w2; break; \
            default:a30 = fmaf(w2, v2a, a30); a31 = fmaf(w2, v2b, a31); rs3 += w2; break; \
        }                                                                       \
    }

__global__ __launch_bounds__(256) void node_gather1(
        const int* __restrict__ start, const int4* __restrict__ rec,
        const float* __restrict__ h,
        u16* __restrict__ ahi, u16* __restrict__ alo) {
    __shared__ float red[4][512];
    __shared__ float rsred[4][4];
    int n = blockIdx.x;
    int w = threadIdx.x >> 6, lane = threadIdx.x & 63;
    int j0 = __builtin_amdgcn_readfirstlane(start[n]);
    int j1 = __builtin_amdgcn_readfirstlane(start[n + 1]);
    float a00 = 0.f, a01 = 0.f, a10 = 0.f, a11 = 0.f;
    float a20 = 0.f, a21 = 0.f, a30 = 0.f, a31 = 0.f;
    float rs0 = 0.f, rs1 = 0.f, rs2 = 0.f, rs3 = 0.f;
    int j = j0 + w;
    for (; j + 4 < j1; j += 8) {        // two records; loads overlap
        int4 ra = rec[j];
        int4 rb = rec[j + 4];
        G1_BODY(ra)
        G1_BODY(rb)
    }
    if (j < j1) {
        int4 ra = rec[j];
        G1_BODY(ra)
    }
    red[w][lane]       = a00; red[w][64 + lane]  = a01;
    red[w][128 + lane] = a10; red[w][192 + lane] = a11;
    red[w][256 + lane] = a20; red[w][320 + lane] = a21;
    red[w][384 + lane] = a30; red[w][448 + lane] = a31;
    if (lane == 0) {
        rsred[w][0] = rs0; rsred[w][1] = rs1; rsred[w][2] = rs2; rsred[w][3] = rs3;
    }
    __syncthreads();
    int t = threadIdx.x;
    float s0 = (red[0][t] + red[1][t]) + (red[2][t] + red[3][t]);
    float s1 = (red[0][256 + t] + red[1][256 + t]) + (red[2][256 + t] + red[3][256 + t]);
    int f0 = t >> 7, f1 = 2 + (t >> 7);
    float rsa = (rsred[0][f0] + rsred[1][f0]) + (rsred[2][f0] + rsred[3][f0]) + EPSF;
    float rsb = (rsred[0][f1] + rsred[1][f1]) + (rsred[2][f1] + rsred[3][f1]) + EPSF;
    float e0 = s0 / rsa; e0 = e0 > 0.f ? e0 : expm1f(e0);
    float e1 = s1 / rsb; e1 = e1 > 0.f ? e1 : expm1f(e1);
    u16 h0 = bf16_rne(e0), l0 = bf16_rne(e0 - bf16_f(h0));
    u16 h1 = bf16_rne(e1), l1 = bf16_rne(e1 - bf16_f(h1));
    u16* ah = ahi + (size_t)n * NF;
    u16* al = alo + (size_t)n * NF;
    ah[t] = h0; ah[256 + t] = h1;
    al[t] = l0; al[256 + t] = l1;
}

// ---------------------------------------------------------------------------
// K5: xo0 = elu_cat @ W_o via 3-term split-bf16 MFMA + fused s1o/s2o dots.
__global__ __launch_bounds__(256) void node_pass_mfma(
        const u16* __restrict__ ahi, const u16* __restrict__ alo,
        const u16* __restrict__ wohi, const u16* __restrict__ wolo,
        const float* __restrict__ a_out,
        float* __restrict__ xo0, float* __restrict__ s1o, float* __restrict__ s2o) {
    __shared__ u16 Ah[128 * 32], Al[128 * 32], Bh[64 * 32], Bl[64 * 32];
    __shared__ float part1[2][64][2];
    __shared__ float part2[2][64][2];
    int m0 = blockIdx.x * 128;
    int tid = threadIdx.x;
    int lane = tid & 63;
    int wave = tid >> 6, wm = wave >> 1, wn = wave & 1;
    f32x4 acc[4][2];
#pragma unroll
    for (int i = 0; i < 4; ++i)
#pragma unroll
        for (int j = 0; j < 2; ++j) acc[i][j] = (f32x4)(0.f);

    u16* sbuf = (wave == 0) ? Ah : (wave == 1) ? Al : (wave == 2) ? Bh : Bl;
    const u16* gbase = (wave == 0) ? ahi : (wave == 1) ? alo
                     : (wave == 2) ? wohi : wolo;
    int nld = (wave < 2) ? 8 : 4;
    int c16s = (lane & 3) ^ ((lane >> 2) & 3) ^ (lane >> 4);
    const u16* gsrc[8];
#pragma unroll
    for (int i = 0; i < 8; ++i) {
        int rowg = ((wave < 2) ? m0 : 0) + 16 * i + (lane >> 2);
        if (wave < 2 && rowg >= NN) rowg = NN - 1;
        gsrc[i] = gbase + (size_t)rowg * NF + c16s * 8;
    }

    const int arow = wm * 64 + (lane & 15);
    const int brow = wn * 32 + (lane & 15);
    const int rc16 = (lane >> 4) ^ ((lane & 3) ^ ((lane >> 2) & 3));
    const int fragoff = rc16 * 8;

    for (int k0 = 0; k0 < NF; k0 += 32) {
        __syncthreads();
        for (int i = 0; i < nld; ++i)
            gload_lds16(gsrc[i] + k0, sbuf + i * 512);
        __syncthreads();
        bf16x8 ah[4], al[4], bh[2], bl[2];
#pragma unroll
        for (int mi = 0; mi < 4; ++mi) {
            ah[mi] = *(const bf16x8*)(Ah + (arow + mi * 16) * 32 + fragoff);
            al[mi] = *(const bf16x8*)(Al + (arow + mi * 16) * 32 + fragoff);
        }
#pragma unroll
        for (int ni = 0; ni < 2; ++ni) {
            bh[ni] = *(const bf16x8*)(Bh + (brow + ni * 16) * 32 + fragoff);
            bl[ni] = *(const bf16x8*)(Bl + (brow + ni * 16) * 32 + fragoff);
        }
#pragma unroll
        for (int mi = 0; mi < 4; ++mi)
#pragma unroll
            for (int ni = 0; ni < 2; ++ni) {
                acc[mi][ni] = __builtin_amdgcn_mfma_f32_16x16x32_bf16(
                    ah[mi], bh[ni], acc[mi][ni], 0, 0, 0);
                acc[mi][ni] = __builtin_amdgcn_mfma_f32_16x16x32_bf16(
                    ah[mi], bl[ni], acc[mi][ni], 0, 0, 0);
                acc[mi][ni] = __builtin_amdgcn_mfma_f32_16x16x32_bf16(
                    al[mi], bh[ni], acc[mi][ni], 0, 0, 0);
            }
    }
    // xo0 store
#pragma unroll
    for (int mi = 0; mi < 4; ++mi) {
        int mbase = m0 + wm * 64 + mi * 16 + (lane >> 4) * 4;
#pragma unroll
        for (int ni = 0; ni < 2; ++ni) {
            int n = wn * 32 + ni * 16 + (lane & 15);
#pragma unroll
            for (int r2 = 0; r2 < 4; ++r2) {
                int m = mbase + r2;
                if (m < NN) xo0[(size_t)m * NC + n] = acc[mi][ni][r2];
            }
        }
    }
    // fused dots
    float ao1[2], ao2[2];
#pragma unroll
    for (int ni = 0; ni < 2; ++ni) {
        int c = wn * 32 + ni * 16 + (lane & 15);
        ao1[ni] = a_out[c];
        ao2[ni] = a_out[64 + c];
    }
#pragma unroll
    for (int mi = 0; mi < 4; ++mi)
#pragma unroll
        for (int r2 = 0; r2 < 4; ++r2) {
            float p1 = acc[mi][0][r2] * ao1[0] + acc[mi][1][r2] * ao1[1];
            float p2 = acc[mi][0][r2] * ao2[0] + acc[mi][1][r2] * ao2[1];
#pragma unroll
            for (int off = 8; off >= 1; off >>= 1) {
                p1 += __shfl_xor(p1, off);
                p2 += __shfl_xor(p2, off);
            }
            if ((lane & 15) == 0) {
                int rl = mi * 16 + (lane >> 4) * 4 + r2;
                part1[wm][rl][wn] = p1;
                part2[wm][rl][wn] = p2;
            }
        }
    __syncthreads();
    if (tid < 128) {
        int m = m0 + tid;
        if (m < NN) {
            s1o[m] = part1[tid >> 6][tid & 63][0] + part1[tid >> 6][tid & 63][1];
            s2o[m] = part2[tid >> 6][tid & 63][0] + part2[tid >> 6][tid & 63][1];
        }
    }
}

// ---------------------------------------------------------------------------
// K6: output attention gather, scalarized (wave-uniform rec/s2o in SGPRs),
// unrolled x2, fused elu + log-softmax; block 0 finalizes att_loss.
__global__ __launch_bounds__(256) void node_gather2(
        const int* __restrict__ start, const int4* __restrict__ rec,
        const float* __restrict__ s1o, const float* __restrict__ s2o,
        const float* __restrict__ xo0, const double* __restrict__ att_acc,
        float* __restrict__ out) {
    __shared__ float red[4][64];
    __shared__ float rsl[4];
    if (blockIdx.x == 0 && threadIdx.x == 0)
        out[(size_t)NN * NC] = 1.f - (float)(att_acc[0] / (double)NE);
    int n = blockIdx.x;
    int w = threadIdx.x >> 6, lane = threadIdx.x & 63;
    int j0 = __builtin_amdgcn_readfirstlane(start[n]);
    int j1 = __builtin_amdgcn_readfirstlane(start[n + 1]);
    float s1n = s1o[n];
    float acc = 0.f, rsum = 0.f;
    int j = j0 + w;
    for (; j + 4 < j1; j += 8) {
        int da = __builtin_amdgcn_readfirstlane(rec[j].x);
        int db = __builtin_amdgcn_readfirstlane(rec[j + 4].x);
        float sva = s1n + s2o[da];
        float svb = s1n + s2o[db];
        float ea = expf(-(sva >= 0.f ? sva : LRELU_ALPHA * sva));
        float eb = expf(-(svb >= 0.f ? svb : LRELU_ALPHA * svb));
        float xa = xo0[(size_t)da * NC + lane];
        float xb = xo0[(size_t)db * NC + lane];
        acc = fmaf(ea, xa, acc);
        rsum += ea;
        acc = fmaf(eb, xb, acc);
        rsum += eb;
    }
    if (j < j1) {
        int d = __builtin_amdgcn_readfirstlane(rec[j].x);
        float sv = s1n + s2o[d];
        float e = expf(-(sv >= 0.f ? sv : LRELU_ALPHA * sv));
        acc = fmaf(e, xo0[(size_t)d * NC + lane], acc);
        rsum += e;
    }
    red[w][lane] = acc;
    if (lane == 0) rsl[w] = rsum;
    __syncthreads();
    if (w == 0) {
        float a = (red[0][lane] + red[1][lane]) + (red[2][lane] + red[3][lane]);
        float r = (rsl[0] + rsl[1]) + (rsl[2] + rsl[3]);
        float t = a / (r + EPSF);
        float v = t > 0.f ? t : expm1f(t);
        float m = v;
#pragma unroll
        for (int off = 32; off >= 1; off >>= 1) m = fmaxf(m, __shfl_xor(m, off));
        float p = expf(v - m);
#pragma unroll
        for (int off = 32; off >= 1; off >>= 1) p += __shfl_xor(p, off);
        out[(size_t)n * NC + lane] = v - m - logf(p);
    }
}

// ---------------------------------------------------------------------------
extern "C" void kernel_launch(void* const* d_in, const int* in_sizes, int n_in,
                              void* d_out, int out_size, void* d_ws, size_t ws_size,
                              hipStream_t stream) {
    const float* x     = (const float*)d_in[0];
    const int*   edge  = (const int*)d_in[1];
    const float* Wks   = (const float*)d_in[2];
    const float* a_k   = (const float*)d_in[3];
    const float* Wo    = (const float*)d_in[4];
    const float* a_att = (const float*)d_in[5];
    const float* a_out = (const float*)d_in[6];
    float* out = (float*)d_out;

    float* wsf = (float*)d_ws;
    float* h      = wsf + OFF_H;
    int4*  rec    = (int4*)(wsf + OFF_REC);
    float* xo0    = wsf + OFF_XO0;
    float* sv1    = wsf + OFF_SV1;
    float* sv2    = wsf + OFF_SV2;
    float* s1o    = wsf + OFF_S1O;
    float* s2o    = wsf + OFF_S2O;
    int*   startp = (int*)(wsf + OFF_START);
    int*   cnt    = (int*)(wsf + OFF_CNT);
    int*   cursor = (int*)(wsf + OFF_CURSOR);
    double* att   = (double*)(wsf + OFF_ATT);

    u16* xhi  = (u16*)(wsf + OFF_HP);
    u16* xlo  = xhi + (size_t)NN * NF;
    u16* ahi  = xhi;
    u16* alo  = xlo;
    u16* wthi = (u16*)(wsf + OFF_REC);
    u16* wtlo = wthi + (size_t)KF * NH * NF;
    u16* wohi = (u16*)(wsf + OFF_WOT);
    u16* wolo = wohi + (size_t)NC * NF;

    size_t zero_bytes = (size_t)(WS_FLOATS - OFF_CNT) * sizeof(float);
    hipMemsetAsync((char*)d_ws + (size_t)OFF_CNT * sizeof(float), 0, zero_bytes, stream);

    split_all<<<NSPLIT + NCNT + 576, 256, 0, stream>>>(
        x, xhi, xlo, edge, cnt, Wks, Wo, wthi, wtlo, wohi, wolo);
    csr_scan<<<1, 1024, 0, stream>>>(cnt, startp);
    gemm_h_mfma<<<4 * ((NN + 127) / 128), 256, 0, stream>>>(xhi, xlo, wthi, wtlo, h);
    compute_svals_h<<<256, 256, 0, stream>>>(h, a_k, a_att, sv1, sv2);
    edge_pre1<<<(NE + 255) / 256, 256, 0, stream>>>(edge, startp, cursor,
                                                    sv1, sv2, rec, att);
    node_gather1<<<NN, 256, 0, stream>>>(startp, rec, h, ahi, alo);
    node_pass_mfma<<<(NN + 127) / 128, 256, 0, stream>>>(ahi, alo, wohi, wolo,
                                                         a_out, xo0, s1o, s2o);
    node_gather2<<<NN, 256, 0, stream>>>(startp, rec, s1o, s2o, xo0, att, out);
}

// Round 13
// 585.512 us; speedup vs baseline: 1.3010x; 1.0266x over previous
//
#include <hip/hip_runtime.h>
#include <math.h>

#define NN 50000
#define NE 800000
#define NF 512
#define NH 128
#define KF 4
#define NC 64
#define LRELU_ALPHA 0.2f
#define EPSF 1e-16f

typedef unsigned short u16;
typedef __attribute__((ext_vector_type(8))) short bf16x8;
typedef __attribute__((ext_vector_type(4))) float f32x4;

// ---------------- workspace layout (float offsets) ----------------
#define OFF_H      0LL                                  // h (NN,512)
#define OFF_HP     (OFF_H + (long long)NN * NF)         // xhi/xlo (gemm in), then ahi/alo (elu-split planes)
#define OFF_REC    (OFF_HP + (long long)NN * NF)        // rec (NE int4); ALSO Wt split before edge_pre1
#define OFF_XO0    (OFF_REC + 4LL * NE)                 // (NN,64)
#define OFF_SV1    (OFF_XO0 + (long long)NN * NC)       // (NN,8): s_src[4] | s1a[4]
#define OFF_SV2    (OFF_SV1 + (long long)NN * 8)        // (NN,8): s_dst[4] | s2a[4]
#define OFF_WOT    (OFF_SV2 + (long long)NN * 8)        // wohi/wolo (64x512 u16 each)
#define OFF_S1O    (OFF_WOT + (long long)NN * KF)       // (NN,)
#define OFF_S2O    (OFF_S1O + NN)
#define OFF_START  (OFF_S2O + NN)                       // (NN+1) ints, pad
// ---- zeroed-each-call region starts here ----
#define OFF_CNT    (OFF_START + NN + 4)                 // NN ints
#define OFF_CURSOR (OFF_CNT + NN)                       // NN ints
#define OFF_ATT    (OFF_CURSOR + NN)                    // double (2 floats)
#define WS_FLOATS  (OFF_ATT + 2)

__device__ __forceinline__ u16 bf16_rne(float f) {
    unsigned int u = __float_as_uint(f);
    return (u16)((u + 0x7FFFu + ((u >> 16) & 1u)) >> 16);
}
__device__ __forceinline__ float bf16_f(u16 b) {
    return __uint_as_float(((unsigned int)b) << 16);
}

// async global->LDS 16B: dest = wave-uniform base + lane*16 (HW rule)
__device__ __forceinline__ void gload_lds16(const u16* g, u16* l) {
    __builtin_amdgcn_global_load_lds(
        (const __attribute__((address_space(1))) void*)g,
        (__attribute__((address_space(3))) void*)l, 16, 0, 0);
}

// ---------------------------------------------------------------------------
// K0: fused preprocessing. Blocks [0,NSPLIT): split x into hi/lo bf16;
// [NSPLIT, NSPLIT+NCNT): csr_count; rest: W / Wo transpose+split.
#define NSPLIT 12500                 // NN*NF/8/256
#define NCNT   ((NE + 255) / 256)    // 3125
__global__ __launch_bounds__(256) void split_all(
        const float* __restrict__ x, u16* __restrict__ xhi, u16* __restrict__ xlo,
        const int* __restrict__ edge, int* __restrict__ cnt,
        const float* __restrict__ Wks, const float* __restrict__ Wo,
        u16* __restrict__ wthi, u16* __restrict__ wtlo,
        u16* __restrict__ wohi, u16* __restrict__ wolo) {
    if (blockIdx.x < NSPLIT) {
        size_t i = ((size_t)blockIdx.x * 256 + threadIdx.x) * 8;
        float4 v0 = *(const float4*)(x + i);
        float4 v1 = *(const float4*)(x + i + 4);
        float v[8] = {v0.x, v0.y, v0.z, v0.w, v1.x, v1.y, v1.z, v1.w};
        unsigned int hp[4], lp[4];
#pragma unroll
        for (int j = 0; j < 4; ++j) {
            u16 h0 = bf16_rne(v[2 * j]);
            u16 h1 = bf16_rne(v[2 * j + 1]);
            u16 l0 = bf16_rne(v[2 * j] - bf16_f(h0));
            u16 l1 = bf16_rne(v[2 * j + 1] - bf16_f(h1));
            hp[j] = (unsigned int)h0 | ((unsigned int)h1 << 16);
            lp[j] = (unsigned int)l0 | ((unsigned int)l1 << 16);
        }
        *(uint4*)(xhi + i) = make_uint4(hp[0], hp[1], hp[2], hp[3]);
        *(uint4*)(xlo + i) = make_uint4(lp[0], lp[1], lp[2], lp[3]);
    } else if (blockIdx.x < NSPLIT + NCNT) {
        int e = (blockIdx.x - NSPLIT) * 256 + threadIdx.x;
        if (e < NE) atomicAdd(&cnt[edge[e]], 1);
    } else {
        int b = blockIdx.x - NSPLIT - NCNT;   // 0..575
        if (b < 512) {
            int kf = b >> 7, n = b & 127;
            for (int f = threadIdx.x; f < NF; f += 256) {
                float v = Wks[(size_t)kf * (NF * NH) + (size_t)f * NH + n];
                u16 hb = bf16_rne(v);
                u16 lb = bf16_rne(v - bf16_f(hb));
                wthi[(size_t)b * NF + f] = hb;
                wtlo[(size_t)b * NF + f] = lb;
            }
        } else {
            int n = b - 512;   // 0..63
            for (int f = threadIdx.x; f < NF; f += 256) {
                float v = Wo[(size_t)f * NC + n];
                u16 hb = bf16_rne(v);
                u16 lb = bf16_rne(v - bf16_f(hb));
                wohi[(size_t)n * NF + f] = hb;
                wolo[(size_t)n * NF + f] = lb;
            }
        }
    }
}

// ---------------------------------------------------------------------------
// K1: h = x @ Wcat via 3-term split-bf16 MFMA, gload_lds staging, XCD-chunked
// bijective block swizzle.
__global__ __launch_bounds__(256) void gemm_h_mfma(
        const u16* __restrict__ xhi, const u16* __restrict__ xlo,
        const u16* __restrict__ wthi, const u16* __restrict__ wtlo,
        float* __restrict__ h) {
    __shared__ u16 Ah[128 * 32], Al[128 * 32], Bh[128 * 32], Bl[128 * 32];
    const int nwg = 4 * ((NN + 127) / 128);
    const int q = nwg / 8, r = nwg % 8;
    int o = blockIdx.x;
    int xcd = o & 7, pos = o >> 3;
    int wg = (xcd < r ? xcd * (q + 1) : r * (q + 1) + (xcd - r) * q) + pos;
    int m0 = (wg >> 2) * 128, n0 = (wg & 3) * 128;

    int tid = threadIdx.x;
    int lane = tid & 63;
    int wave = tid >> 6, wm = wave >> 1, wn = wave & 1;
    f32x4 acc[4][4];
#pragma unroll
    for (int i = 0; i < 4; ++i)
#pragma unroll
        for (int j = 0; j < 4; ++j) acc[i][j] = (f32x4)(0.f);

    u16* sbuf = (wave == 0) ? Ah : (wave == 1) ? Al : (wave == 2) ? Bh : Bl;
    const u16* gbase = (wave == 0) ? xhi : (wave == 1) ? xlo
                     : (wave == 2) ? wthi : wtlo;
    int rowbase = (wave < 2) ? m0 : n0;
    int c16s = (lane & 3) ^ ((lane >> 2) & 3) ^ (lane >> 4);
    const u16* gsrc[8];
#pragma unroll
    for (int i = 0; i < 8; ++i) {
        int rowg = rowbase + 16 * i + (lane >> 2);
        if (wave < 2 && rowg >= NN) rowg = NN - 1;
        gsrc[i] = gbase + (size_t)rowg * NF + c16s * 8;
    }

    const int arow = wm * 64 + (lane & 15);
    const int brow = wn * 64 + (lane & 15);
    const int rc16 = (lane >> 4) ^ ((lane & 3) ^ ((lane >> 2) & 3));
    const int fragoff = rc16 * 8;

    for (int k0 = 0; k0 < NF; k0 += 32) {
        __syncthreads();
#pragma unroll
        for (int i = 0; i < 8; ++i)
            gload_lds16(gsrc[i] + k0, sbuf + i * 512);
        __syncthreads();
        bf16x8 ah[4], al[4], bh[4], bl[4];
#pragma unroll
        for (int mi = 0; mi < 4; ++mi) {
            ah[mi] = *(const bf16x8*)(Ah + (arow + mi * 16) * 32 + fragoff);
            al[mi] = *(const bf16x8*)(Al + (arow + mi * 16) * 32 + fragoff);
        }
#pragma unroll
        for (int ni = 0; ni < 4; ++ni) {
            bh[ni] = *(const bf16x8*)(Bh + (brow + ni * 16) * 32 + fragoff);
            bl[ni] = *(const bf16x8*)(Bl + (brow + ni * 16) * 32 + fragoff);
        }
#pragma unroll
        for (int mi = 0; mi < 4; ++mi)
#pragma unroll
            for (int ni = 0; ni < 4; ++ni) {
                acc[mi][ni] = __builtin_amdgcn_mfma_f32_16x16x32_bf16(
                    ah[mi], bh[ni], acc[mi][ni], 0, 0, 0);
                acc[mi][ni] = __builtin_amdgcn_mfma_f32_16x16x32_bf16(
                    ah[mi], bl[ni], acc[mi][ni], 0, 0, 0);
                acc[mi][ni] = __builtin_amdgcn_mfma_f32_16x16x32_bf16(
                    al[mi], bh[ni], acc[mi][ni], 0, 0, 0);
            }
    }
#pragma unroll
    for (int mi = 0; mi < 4; ++mi) {
        int mbase = m0 + wm * 64 + mi * 16 + (lane >> 4) * 4;
#pragma unroll
        for (int ni = 0; ni < 4; ++ni) {
            int n = n0 + wn * 64 + ni * 16 + (lane & 15);
#pragma unroll
            for (int r2 = 0; r2 < 4; ++r2) {
                int m = mbase + r2;
                if (m < NN) h[(size_t)m * NF + n] = acc[mi][ni][r2];
            }
        }
    }
}

// ---------------------------------------------------------------------------
// K2: routing/attention scalars from h, packed per node. 2048 blocks so each
// SIMD carries ~8 waves (R12's 256-block version had 1 wave/SIMD -> latency-
// starved).
__global__ __launch_bounds__(256) void compute_svals_h(
        const float* __restrict__ h, const float* __restrict__ a_k,
        const float* __restrict__ a_att,
        float* __restrict__ sv1, float* __restrict__ sv2) {
    __shared__ float Ak[4][1024];
    __shared__ float Aa[4][256];
    for (int i = threadIdx.x; i < 4096; i += 256) Ak[i >> 10][i & 1023] = a_k[i];
    for (int i = threadIdx.x; i < 1024; i += 256) Aa[i >> 8][i & 255] = a_att[i];
    __syncthreads();
    int w = threadIdx.x >> 6, lane = threadIdx.x & 63;
    for (int n = blockIdx.x * 4 + w; n < NN; n += gridDim.x * 4) {
        const float* hr = h + (size_t)n * NF;
        float accS[4] = {0, 0, 0, 0}, accD[4] = {0, 0, 0, 0};
        float accQ1[4] = {0, 0, 0, 0}, accQ2[4] = {0, 0, 0, 0};
#pragma unroll
        for (int i = 0; i < 8; ++i) {
            int f = i * 64 + lane;
            float hv = hr[f];
#pragma unroll
            for (int k = 0; k < 4; ++k) {
                accS[k] = fmaf(hv, Ak[k][f], accS[k]);
                accD[k] = fmaf(hv, Ak[k][512 + f], accD[k]);
            }
            accQ1[i >> 1] = fmaf(hv, Aa[i >> 1][f & 127], accQ1[i >> 1]);
            accQ2[i >> 1] = fmaf(hv, Aa[i >> 1][128 + (f & 127)], accQ2[i >> 1]);
        }
#pragma unroll
        for (int off = 32; off >= 1; off >>= 1) {
#pragma unroll
            for (int k = 0; k < 4; ++k) {
                accS[k] += __shfl_xor(accS[k], off);
                accD[k] += __shfl_xor(accD[k], off);
                accQ1[k] += __shfl_xor(accQ1[k], off);
                accQ2[k] += __shfl_xor(accQ2[k], off);
            }
        }
        if (lane == 0) {
#pragma unroll
            for (int k = 0; k < 4; ++k) {
                sv1[(size_t)n * 8 + k]     = accS[k];
                sv1[(size_t)n * 8 + 4 + k] = accQ1[k];
                sv2[(size_t)n * 8 + k]     = accD[k];
                sv2[(size_t)n * 8 + 4 + k] = accQ2[k];
            }
        }
    }
}

// ---------------------------------------------------------------------------
__global__ __launch_bounds__(1024) void csr_scan(const int* __restrict__ cnt,
                                                 int* __restrict__ start) {
    __shared__ int part[1024];
    int t = threadIdx.x;
    const int CH = (NN + 1023) / 1024;  // 49
    int base = t * CH;
    int s = 0;
    for (int i = 0; i < CH; ++i) {
        int idx = base + i;
        if (idx < NN) s += cnt[idx];
    }
    part[t] = s;
    __syncthreads();
    for (int off = 1; off < 1024; off <<= 1) {
        int v = (t >= off) ? part[t - off] : 0;
        __syncthreads();
        part[t] += v;
        __syncthreads();
    }
    int run = (t == 0) ? 0 : part[t - 1];
    for (int i = 0; i < CH; ++i) {
        int idx = base + i;
        if (idx < NN) { start[idx] = run; run += cnt[idx]; }
    }
    if (t == 1023) start[NN] = run;
}

// ---------------------------------------------------------------------------
// K3: edge-parallel scalar precompute + CSR fill. One thread per edge.
__global__ __launch_bounds__(256) void edge_pre1(
        const int* __restrict__ edge, const int* __restrict__ start,
        int* __restrict__ cursor,
        const float* __restrict__ sv1, const float* __restrict__ sv2,
        int4* __restrict__ rec, double* __restrict__ att_acc) {
    __shared__ float blk[4];
    int tid = threadIdx.x;
    int e = blockIdx.x * 256 + tid;
    float t2 = 0.f;
    if (e < NE) {
        int src = edge[e];
        int dst = edge[NE + e];
        const float* p1 = sv1 + (size_t)src * 8;
        const float* p2 = sv2 + (size_t)dst * 8;
        float4 ss = *(const float4*)(p1);
        float4 q1 = *(const float4*)(p1 + 4);
        float4 sd = *(const float4*)(p2);
        float4 q2 = *(const float4*)(p2 + 4);
        float l0 = ss.x + sd.x, l1 = ss.y + sd.y, l2 = ss.z + sd.z, l3 = ss.w + sd.w;
        int i1 = 0; float v1 = l0;
        if (l1 > v1) { v1 = l1; i1 = 1; }
        if (l2 > v1) { v1 = l2; i1 = 2; }
        if (l3 > v1) { v1 = l3; i1 = 3; }
        int i2 = 0; float v2 = -3.4e38f;
        if (i1 != 0)            { v2 = l0; i2 = 0; }
        if (i1 != 1 && l1 > v2) { v2 = l1; i2 = 1; }
        if (i1 != 2 && l2 > v2) { v2 = l2; i2 = 2; }
        if (i1 != 3 && l3 > v2) { v2 = l3; i2 = 3; }
        float esum = expf(l0 - v1) + expf(l1 - v1) + expf(l2 - v1) + expf(l3 - v1);
        t2 = (1.f + expf(v2 - v1)) / esum;
        float q1v1 = i1 == 0 ? q1.x : i1 == 1 ? q1.y : i1 == 2 ? q1.z : q1.w;
        float q2v1 = i1 == 0 ? q2.x : i1 == 1 ? q2.y : i1 == 2 ? q2.z : q2.w;
        float q1v2 = i2 == 0 ? q1.x : i2 == 1 ? q1.y : i2 == 2 ? q1.z : q1.w;
        float q2v2 = i2 == 0 ? q2.x : i2 == 1 ? q2.y : i2 == 2 ? q2.z : q2.w;
        float sv1v = q1v1 + q2v1, sv2v = q1v2 + q2v2;
        float ee1 = expf(-(sv1v >= 0.f ? sv1v : LRELU_ALPHA * sv1v));
        float ee2 = expf(-(sv2v >= 0.f ? sv2v : LRELU_ALPHA * sv2v));
        int p = start[src] + atomicAdd(&cursor[src], 1);
        rec[p] = make_int4(dst, src | (i1 << 16) | (i2 << 18),
                           __float_as_int(ee1), __float_as_int(ee2));
    }
#pragma unroll
    for (int off = 32; off >= 1; off >>= 1) t2 += __shfl_xor(t2, off);
    if ((tid & 63) == 0) blk[tid >> 6] = t2;
    __syncthreads();
    if (tid == 0)
        atomicAdd(att_acc, (double)(blk[0] + blk[1] + blk[2] + blk[3]));
}

// ---------------------------------------------------------------------------
// K4: layer-1 gather, unrolled x4 (load-phase / accumulate-phase split so up
// to 4 rec + 16 row loads are in flight). Per-wave accumulation order is by
// increasing j, identical to the rolled loop -> bit-identical results.
#define G1_LOAD(RR, T)                                                          \
    int i1##T = __builtin_amdgcn_readfirstlane(((RR).y >> 16) & 3);             \
    int i2##T = __builtin_amdgcn_readfirstlane(((RR).y >> 18) & 3);             \
    int dd##T = __builtin_amdgcn_readfirstlane((RR).x);                         \
    float w1##T = __uint_as_float(__builtin_amdgcn_readfirstlane((RR).z));      \
    float w2##T = __uint_as_float(__builtin_amdgcn_readfirstlane((RR).w));      \
    const float* hr##T = h + (size_t)dd##T * NF + lane;                         \
    float v1a##T = hr##T[i1##T * 128];                                          \
    float v1b##T = hr##T[i1##T * 128 + 64];                                     \
    float v2a##T = hr##T[i2##T * 128];                                          \
    float v2b##T = hr##T[i2##T * 128 + 64];

#define G1_ACC(T)                                                               \
    switch (i1##T) {                                                            \
        case 0: a00 = fmaf(w1##T, v1a##T, a00); a01 = fmaf(w1##T, v1b##T, a01); rs0 += w1##T; break; \
        case 1: a10 = fmaf(w1##T, v1a##T, a10); a11 = fmaf(w1##T, v1b##T, a11); rs1 += w1##T; break; \
        case 2: a20 = fmaf(w1##T, v1a##T, a20); a21 = fmaf(w1##T, v1b##T, a21); rs2 += w1##T; break; \
        default:a30 = fmaf(w1##T, v1a##T, a30); a31 = fmaf(w1##T, v1b##T, a31); rs3 += w1##T; break; \
    }                                                                           \
    switch (i2##T) {                                                            \
        case 0: a00 = fmaf(w2##T, v2a##T, a00); a01 = fmaf(w2##T, v2b##T, a01); rs0 += w2##T; break; \
        case 1: a10 = fmaf(w2##T, v2a##T, a10); a11 = fmaf(w2##T, v2b##T, a11); rs1 += w2##T; break; \
        case 2: a20 = fmaf(w2##T, v2a##T, a20); a21 = fmaf(w2##T, v2b##T, a21); rs2 += w2##T; break; \
        default:a30 = fmaf(w2##T, v2a##T, a30); a31 = fmaf(w2##T, v2b##T, a31); rs3 += w2##T; break; \
    }

__global__ __launch_bounds__(256) void node_gather1(
        const int* __restrict__ start, const int4* __restrict__ rec,
        const float* __restrict__ h,
        u16* __restrict__ ahi, u16* __restrict__ alo) {
    __shared__ float red[4][512];
    __shared__ float rsred[4][4];
    int n = blockIdx.x;
    int w = threadIdx.x >> 6, lane = threadIdx.x & 63;
    int j0 = __builtin_amdgcn_readfirstlane(start[n]);
    int j1 = __builtin_amdgcn_readfirstlane(start[n + 1]);
    float a00 = 0.f, a01 = 0.f, a10 = 0.f, a11 = 0.f;
    float a20 = 0.f, a21 = 0.f, a30 = 0.f, a31 = 0.f;
    float rs0 = 0.f, rs1 = 0.f, rs2 = 0.f, rs3 = 0.f;
    int j = j0 + w;
    for (; j + 12 < j1; j += 16) {      // 4 records in flight
        int4 r0 = rec[j];
        int4 r1 = rec[j + 4];
        int4 r2 = rec[j + 8];
        int4 r3 = rec[j + 12];
        G1_LOAD(r0, A) G1_LOAD(r1, B) G1_LOAD(r2, C) G1_LOAD(r3, D)
        G1_ACC(A) G1_ACC(B) G1_ACC(C) G1_ACC(D)
    }
    for (; j < j1; j += 4) {
        int4 r0 = rec[j];
        G1_LOAD(r0, A)
        G1_ACC(A)
    }
    red[w][lane]       = a00; red[w][64 + lane]  = a01;
    red[w][128 + lane] = a10; red[w][192 + lane] = a11;
    red[w][256 + lane] = a20; red[w][320 + lane] = a21;
    red[w][384 + lane] = a30; red[w][448 + lane] = a31;
    if (lane == 0) {
        rsred[w][0] = rs0; rsred[w][1] = rs1; rsred[w][2] = rs2; rsred[w][3] = rs3;
    }
    __syncthreads();
    int t = threadIdx.x;
    float s0 = (red[0][t] + red[1][t]) + (red[2][t] + red[3][t]);
    float s1 = (red[0][256 + t] + red[1][256 + t]) + (red[2][256 + t] + red[3][256 + t]);
    int f0 = t >> 7, f1 = 2 + (t >> 7);
    float rsa = (rsred[0][f0] + rsred[1][f0]) + (rsred[2][f0] + rsred[3][f0]) + EPSF;
    float rsb = (rsred[0][f1] + rsred[1][f1]) + (rsred[2][f1] + rsred[3][f1]) + EPSF;
    float e0 = s0 / rsa; e0 = e0 > 0.f ? e0 : expm1f(e0);
    float e1 = s1 / rsb; e1 = e1 > 0.f ? e1 : expm1f(e1);
    u16 h0 = bf16_rne(e0), l0 = bf16_rne(e0 - bf16_f(h0));
    u16 h1 = bf16_rne(e1), l1 = bf16_rne(e1 - bf16_f(h1));
    u16* ah = ahi + (size_t)n * NF;
    u16* al = alo + (size_t)n * NF;
    ah[t] = h0; ah[256 + t] = h1;
    al[t] = l0; al[256 + t] = l1;
}

// ---------------------------------------------------------------------------
// K5: xo0 = elu_cat @ W_o via 3-term split-bf16 MFMA + fused s1o/s2o dots.
__global__ __launch_bounds__(256) void node_pass_mfma(
        const u16* __restrict__ ahi, const u16* __restrict__ alo,
        const u16* __restrict__ wohi, const u16* __restrict__ wolo,
        const float* __restrict__ a_out,
        float* __restrict__ xo0, float* __restrict__ s1o, float* __restrict__ s2o) {
    __shared__ u16 Ah[128 * 32], Al[128 * 32], Bh[64 * 32], Bl[64 * 32];
    __shared__ float part1[2][64][2];
    __shared__ float part2[2][64][2];
    int m0 = blockIdx.x * 128;
    int tid = threadIdx.x;
    int lane = tid & 63;
    int wave = tid >> 6, wm = wave >> 1, wn = wave & 1;
    f32x4 acc[4][2];
#pragma unroll
    for (int i = 0; i < 4; ++i)
#pragma unroll
        for (int j = 0; j < 2; ++j) acc[i][j] = (f32x4)(0.f);

    u16* sbuf = (wave == 0) ? Ah : (wave == 1) ? Al : (wave == 2) ? Bh : Bl;
    const u16* gbase = (wave == 0) ? ahi : (wave == 1) ? alo
                     : (wave == 2) ? wohi : wolo;
    int nld = (wave < 2) ? 8 : 4;
    int c16s = (lane & 3) ^ ((lane >> 2) & 3) ^ (lane >> 4);
    const u16* gsrc[8];
#pragma unroll
    for (int i = 0; i < 8; ++i) {
        int rowg = ((wave < 2) ? m0 : 0) + 16 * i + (lane >> 2);
        if (wave < 2 && rowg >= NN) rowg = NN - 1;
        gsrc[i] = gbase + (size_t)rowg * NF + c16s * 8;
    }

    const int arow = wm * 64 + (lane & 15);
    const int brow = wn * 32 + (lane & 15);
    const int rc16 = (lane >> 4) ^ ((lane & 3) ^ ((lane >> 2) & 3));
    const int fragoff = rc16 * 8;

    for (int k0 = 0; k0 < NF; k0 += 32) {
        __syncthreads();
        for (int i = 0; i < nld; ++i)
            gload_lds16(gsrc[i] + k0, sbuf + i * 512);
        __syncthreads();
        bf16x8 ah[4], al[4], bh[2], bl[2];
#pragma unroll
        for (int mi = 0; mi < 4; ++mi) {
            ah[mi] = *(const bf16x8*)(Ah + (arow + mi * 16) * 32 + fragoff);
            al[mi] = *(const bf16x8*)(Al + (arow + mi * 16) * 32 + fragoff);
        }
#pragma unroll
        for (int ni = 0; ni < 2; ++ni) {
            bh[ni] = *(const bf16x8*)(Bh + (brow + ni * 16) * 32 + fragoff);
            bl[ni] = *(const bf16x8*)(Bl + (brow + ni * 16) * 32 + fragoff);
        }
#pragma unroll
        for (int mi = 0; mi < 4; ++mi)
#pragma unroll
            for (int ni = 0; ni < 2; ++ni) {
                acc[mi][ni] = __builtin_amdgcn_mfma_f32_16x16x32_bf16(
                    ah[mi], bh[ni], acc[mi][ni], 0, 0, 0);
                acc[mi][ni] = __builtin_amdgcn_mfma_f32_16x16x32_bf16(
                    ah[mi], bl[ni], acc[mi][ni], 0, 0, 0);
                acc[mi][ni] = __builtin_amdgcn_mfma_f32_16x16x32_bf16(
                    al[mi], bh[ni], acc[mi][ni], 0, 0, 0);
            }
    }
    // xo0 store
#pragma unroll
    for (int mi = 0; mi < 4; ++mi) {
        int mbase = m0 + wm * 64 + mi * 16 + (lane >> 4) * 4;
#pragma unroll
        for (int ni = 0; ni < 2; ++ni) {
            int n = wn * 32 + ni * 16 + (lane & 15);
#pragma unroll
            for (int r2 = 0; r2 < 4; ++r2) {
                int m = mbase + r2;
                if (m < NN) xo0[(size_t)m * NC + n] = acc[mi][ni][r2];
            }
        }
    }
    // fused dots
    float ao1[2], ao2[2];
#pragma unroll
    for (int ni = 0; ni < 2; ++ni) {
        int c = wn * 32 + ni * 16 + (lane & 15);
        ao1[ni] = a_out[c];
        ao2[ni] = a_out[64 + c];
    }
#pragma unroll
    for (int mi = 0; mi < 4; ++mi)
#pragma unroll
        for (int r2 = 0; r2 < 4; ++r2) {
            float p1 = acc[mi][0][r2] * ao1[0] + acc[mi][1][r2] * ao1[1];
            float p2 = acc[mi][0][r2] * ao2[0] + acc[mi][1][r2] * ao2[1];
#pragma unroll
            for (int off = 8; off >= 1; off >>= 1) {
                p1 += __shfl_xor(p1, off);
                p2 += __shfl_xor(p2, off);
            }
            if ((lane & 15) == 0) {
                int rl = mi * 16 + (lane >> 4) * 4 + r2;
                part1[wm][rl][wn] = p1;
                part2[wm][rl][wn] = p2;
            }
        }
    __syncthreads();
    if (tid < 128) {
        int m = m0 + tid;
        if (m < NN) {
            s1o[m] = part1[tid >> 6][tid & 63][0] + part1[tid >> 6][tid & 63][1];
            s2o[m] = part2[tid >> 6][tid & 63][0] + part2[tid >> 6][tid & 63][1];
        }
    }
}

// ---------------------------------------------------------------------------
// K6: output attention gather, unrolled x4 (4 dependent chains in flight),
// fused elu + log-softmax; block 0 finalizes att_loss. Accumulation order per
// wave unchanged -> bit-identical.
__global__ __launch_bounds__(256) void node_gather2(
        const int* __restrict__ start, const int4* __restrict__ rec,
        const float* __restrict__ s1o, const float* __restrict__ s2o,
        const float* __restrict__ xo0, const double* __restrict__ att_acc,
        float* __restrict__ out) {
    __shared__ float red[4][64];
    __shared__ float rsl[4];
    if (blockIdx.x == 0 && threadIdx.x == 0)
        out[(size_t)NN * NC] = 1.f - (float)(att_acc[0] / (double)NE);
    int n = blockIdx.x;
    int w = threadIdx.x >> 6, lane = threadIdx.x & 63;
    int j0 = __builtin_amdgcn_readfirstlane(start[n]);
    int j1 = __builtin_amdgcn_readfirstlane(start[n + 1]);
    float s1n = s1o[n];
    float acc = 0.f, rsum = 0.f;
    int j = j0 + w;
    for (; j + 12 < j1; j += 16) {
        int d0 = __builtin_amdgcn_readfirstlane(rec[j].x);
        int d1 = __builtin_amdgcn_readfirstlane(rec[j + 4].x);
        int d2 = __builtin_amdgcn_readfirstlane(rec[j + 8].x);
        int d3 = __builtin_amdgcn_readfirstlane(rec[j + 12].x);
        float t0 = s1n + s2o[d0];
        float t1 = s1n + s2o[d1];
        float t2 = s1n + s2o[d2];
        float t3 = s1n + s2o[d3];
        float x0 = xo0[(size_t)d0 * NC + lane];
        float x1 = xo0[(size_t)d1 * NC + lane];
        float x2 = xo0[(size_t)d2 * NC + lane];
        float x3 = xo0[(size_t)d3 * NC + lane];
        float e0 = expf(-(t0 >= 0.f ? t0 : LRELU_ALPHA * t0));
        float e1 = expf(-(t1 >= 0.f ? t1 : LRELU_ALPHA * t1));
        float e2 = expf(-(t2 >= 0.f ? t2 : LRELU_ALPHA * t2));
        float e3 = expf(-(t3 >= 0.f ? t3 : LRELU_ALPHA * t3));
        acc = fmaf(e0, x0, acc); rsum += e0;
        acc = fmaf(e1, x1, acc); rsum += e1;
        acc = fmaf(e2, x2, acc); rsum += e2;
        acc = fmaf(e3, x3, acc); rsum += e3;
    }
    for (; j < j1; j += 4) {
        int d = __builtin_amdgcn_readfirstlane(rec[j].x);
        float sv = s1n + s2o[d];
        float e = expf(-(sv >= 0.f ? sv : LRELU_ALPHA * sv));
        acc = fmaf(e, xo0[(size_t)d * NC + lane], acc);
        rsum += e;
    }
    red[w][lane] = acc;
    if (lane == 0) rsl[w] = rsum;
    __syncthreads();
    if (w == 0) {
        float a = (red[0][lane] + red[1][lane]) + (red[2][lane] + red[3][lane]);
        float r = (rsl[0] + rsl[1]) + (rsl[2] + rsl[3]);
        float t = a / (r + EPSF);
        float v = t > 0.f ? t : expm1f(t);
        float m = v;
#pragma unroll
        for (int off = 32; off >= 1; off >>= 1) m = fmaxf(m, __shfl_xor(m, off));
        float p = expf(v - m);
#pragma unroll
        for (int off = 32; off >= 1; off >>= 1) p += __shfl_xor(p, off);
        out[(size_t)n * NC + lane] = v - m - logf(p);
    }
}

// ---------------------------------------------------------------------------
extern "C" void kernel_launch(void* const* d_in, const int* in_sizes, int n_in,
                              void* d_out, int out_size, void* d_ws, size_t ws_size,
                              hipStream_t stream) {
    const float* x     = (const float*)d_in[0];
    const int*   edge  = (const int*)d_in[1];
    const float* Wks   = (const float*)d_in[2];
    const float* a_k   = (const float*)d_in[3];
    const float* Wo    = (const float*)d_in[4];
    const float* a_att = (const float*)d_in[5];
    const float* a_out = (const float*)d_in[6];
    float* out = (float*)d_out;

    float* wsf = (float*)d_ws;
    float* h      = wsf + OFF_H;
    int4*  rec    = (int4*)(wsf + OFF_REC);
    float* xo0    = wsf + OFF_XO0;
    float* sv1    = wsf + OFF_SV1;
    float* sv2    = wsf + OFF_SV2;
    float* s1o    = wsf + OFF_S1O;
    float* s2o    = wsf + OFF_S2O;
    int*   startp = (int*)(wsf + OFF_START);
    int*   cnt    = (int*)(wsf + OFF_CNT);
    int*   cursor = (int*)(wsf + OFF_CURSOR);
    double* att   = (double*)(wsf + OFF_ATT);

    u16* xhi  = (u16*)(wsf + OFF_HP);
    u16* xlo  = xhi + (size_t)NN * NF;
    u16* ahi  = xhi;
    u16* alo  = xlo;
    u16* wthi = (u16*)(wsf + OFF_REC);
    u16* wtlo = wthi + (size_t)KF * NH * NF;
    u16* wohi = (u16*)(wsf + OFF_WOT);
    u16* wolo = wohi + (size_t)NC * NF;

    size_t zero_bytes = (size_t)(WS_FLOATS - OFF_CNT) * sizeof(float);
    hipMemsetAsync((char*)d_ws + (size_t)OFF_CNT * sizeof(float), 0, zero_bytes, stream);

    split_all<<<NSPLIT + NCNT + 576, 256, 0, stream>>>(
        x, xhi, xlo, edge, cnt, Wks, Wo, wthi, wtlo, wohi, wolo);
    csr_scan<<<1, 1024, 0, stream>>>(cnt, startp);
    gemm_h_mfma<<<4 * ((NN + 127) / 128), 256, 0, stream>>>(xhi, xlo, wthi, wtlo, h);
    compute_svals_h<<<2048, 256, 0, stream>>>(h, a_k, a_att, sv1, sv2);
    edge_pre1<<<(NE + 255) / 256, 256, 0, stream>>>(edge, startp, cursor,
                                                    sv1, sv2, rec, att);
    node_gather1<<<NN, 256, 0, stream>>>(startp, rec, h, ahi, alo);
    node_pass_mfma<<<(NN + 127) / 128, 256, 0, stream>>>(ahi, alo, wohi, wolo,
                                                         a_out, xo0, s1o, s2o);
    node_gather2<<<NN, 256, 0, stream>>>(startp, rec, s1o, s2o, xo0, att, out);
}